// Round 13
// baseline (446.058 us; speedup 1.0000x reference)
//
#include <hip/hip_runtime.h>
#include <hip/hip_bf16.h>

// GCN link prediction. Inputs fp32+int32; OUTPUT fp32 (scores[1M] ++ embed[n*64]).
// CSR gather + bf16 feature tables (fp32 math), register-tiled 4x4 GEMMs,
// device-wide scan, radix-partitioned CSR build, 8-edge/wave uint4 score,
// 32-lane-group gathers: 2 edges per load instruction (issue-bound fix).

#define ECH 4096      // edges per partition chunk
#define SHIFT 8       // dsts per bucket = 256
#define MAXNB 512     // max buckets (n <= 131072)

__device__ __forceinline__ float lo16f(uint32_t u) { uint32_t x = u << 16; float f; __builtin_memcpy(&f, &x, 4); return f; }
__device__ __forceinline__ float hi16f(uint32_t u) { uint32_t x = u & 0xffff0000u; float f; __builtin_memcpy(&f, &x, 4); return f; }
__device__ __forceinline__ float u16f(unsigned short u) { uint32_t x = (uint32_t)u << 16; float f; __builtin_memcpy(&f, &x, 4); return f; }
__device__ __forceinline__ uint32_t pk2(float a, float b) {
    union { __hip_bfloat162 h; uint32_t u; } cv;
    cv.h = __hip_bfloat162(__float2bfloat16(a), __float2bfloat16(b));
    return cv.u;
}

// ---------------- degree count + row_ptr scan ----------------
__global__ void count_kernel(const int* __restrict__ dst, int E, int* __restrict__ count) {
    int e = blockIdx.x * blockDim.x + threadIdx.x;
    if (e < E) atomicAdd(&count[dst[e]], 1);
}

__global__ __launch_bounds__(256) void scan_partial_kernel(const int* __restrict__ count, int n,
                                                           int* __restrict__ partial) {
    __shared__ int red[256];
    int t = threadIdx.x;
    int base = blockIdx.x * 1024 + t * 4;
    int s = 0;
#pragma unroll
    for (int i = 0; i < 4; ++i) {
        int idx = base + i;
        if (idx < n) s += count[idx];
    }
    red[t] = s;
    __syncthreads();
    for (int o = 128; o > 0; o >>= 1) {
        if (t < o) red[t] += red[t + o];
        __syncthreads();
    }
    if (t == 0) partial[blockIdx.x] = red[0];
}

__global__ __launch_bounds__(256) void scan_offsets_kernel(int* __restrict__ partial, int nb,
                                                           int* __restrict__ row_ptr, int n) {
    __shared__ int sc[256];
    int t = threadIdx.x;
    sc[t] = (t < nb) ? partial[t] : 0;
    __syncthreads();
    for (int o = 1; o < 256; o <<= 1) {
        int v = sc[t];
        int u = (t >= o) ? sc[t - o] : 0;
        __syncthreads();
        sc[t] = v + u;
        __syncthreads();
    }
    if (t < nb) partial[t] = (t > 0) ? sc[t - 1] : 0;  // exclusive
    if (t == 0) row_ptr[n] = sc[255];
}

__global__ __launch_bounds__(256) void scan_write_kernel(const int* __restrict__ count, int n,
                                                         const int* __restrict__ partial,
                                                         int* __restrict__ row_ptr,
                                                         float* __restrict__ dinv) {
    __shared__ int sc[256];
    int t = threadIdx.x;
    int base = blockIdx.x * 1024 + t * 4;
    int c[4];
    int s = 0;
#pragma unroll
    for (int i = 0; i < 4; ++i) {
        int idx = base + i;
        c[i] = (idx < n) ? count[idx] : 0;
        s += c[i];
    }
    sc[t] = s;
    __syncthreads();
    for (int o = 1; o < 256; o <<= 1) {
        int v = sc[t];
        int u = (t >= o) ? sc[t - o] : 0;
        __syncthreads();
        sc[t] = v + u;
        __syncthreads();
    }
    int run = partial[blockIdx.x] + ((t > 0) ? sc[t - 1] : 0);
#pragma unroll
    for (int i = 0; i < 4; ++i) {
        int idx = base + i;
        if (idx < n) {
            row_ptr[idx] = run;
            dinv[idx] = rsqrtf((float)c[i] + 1.0f);
            run += c[i];
        }
    }
}

// ---------------- radix partition: edges -> buckets -> CSR ----------------
__global__ __launch_bounds__(256) void part_hist_kernel(const int* __restrict__ dst, int E,
                                                        int B, int NB, int* __restrict__ histG) {
    __shared__ int h[MAXNB];
    int t = threadIdx.x, blk = blockIdx.x;
    for (int i = t; i < NB; i += 256) h[i] = 0;
    __syncthreads();
    int lo = blk * ECH, hi = min(lo + ECH, E);
    for (int i = lo + t; i < hi; i += 256) atomicAdd(&h[dst[i] >> SHIFT], 1);
    __syncthreads();
    for (int k = t; k < NB; k += 256) histG[(size_t)k * B + blk] = h[k];
}

__global__ __launch_bounds__(256) void part_scan_kernel(int* __restrict__ histG, int B,
                                                        int* __restrict__ bucketTotal) {
    __shared__ int sc[1024];   // supports B <= 1024
    int k = blockIdx.x, t = threadIdx.x;
    for (int i = t; i < 1024; i += 256) sc[i] = (i < B) ? histG[(size_t)k * B + i] : 0;
    __syncthreads();
    for (int o = 1; o < 1024; o <<= 1) {
        int v[4];
#pragma unroll
        for (int j = 0; j < 4; ++j) { int i = t + j * 256; v[j] = (i >= o) ? sc[i - o] : 0; }
        __syncthreads();
#pragma unroll
        for (int j = 0; j < 4; ++j) sc[t + j * 256] += v[j];
        __syncthreads();
    }
    for (int i = t; i < B; i += 256) histG[(size_t)k * B + i] = (i > 0) ? sc[i - 1] : 0;
    if (t == 0) bucketTotal[k] = sc[B - 1];
}

__global__ __launch_bounds__(256) void bucket_base_kernel(const int* __restrict__ bucketTotal,
                                                          int NB, int* __restrict__ bucketBase) {
    __shared__ int sc[MAXNB];
    int t = threadIdx.x;
    for (int i = t; i < MAXNB; i += 256) sc[i] = (i < NB) ? bucketTotal[i] : 0;
    __syncthreads();
    for (int o = 1; o < MAXNB; o <<= 1) {
        int v[MAXNB / 256];
#pragma unroll
        for (int j = 0; j < MAXNB / 256; ++j) { int i = t + j * 256; v[j] = (i >= o) ? sc[i - o] : 0; }
        __syncthreads();
#pragma unroll
        for (int j = 0; j < MAXNB / 256; ++j) sc[t + j * 256] += v[j];
        __syncthreads();
    }
    for (int i = t; i < NB; i += 256) bucketBase[i] = (i > 0) ? sc[i - 1] : 0;
}

__global__ __launch_bounds__(256) void part_scatter_kernel(
    const int* __restrict__ src, const int* __restrict__ dst, int E, int B, int NB,
    const int* __restrict__ histG, const int* __restrict__ bucketBase,
    int2* __restrict__ bedges) {
    __shared__ int cur[MAXNB];
    int t = threadIdx.x, blk = blockIdx.x;
    for (int k = t; k < NB; k += 256) cur[k] = bucketBase[k] + histG[(size_t)k * B + blk];
    __syncthreads();
    int lo = blk * ECH, hi = min(lo + ECH, E);
    for (int i = lo + t; i < hi; i += 256) {
        int s = src[i], d = dst[i];
        int p = atomicAdd(&cur[d >> SHIFT], 1);
        bedges[p] = make_int2(s, d);
    }
}

__global__ __launch_bounds__(256) void csr_fill_kernel(
    const int2* __restrict__ bedges, const int* __restrict__ bucketBase,
    const int* __restrict__ bucketTotal, const int* __restrict__ row_ptr,
    const float* __restrict__ dinv, int n, int2* __restrict__ colw) {
    __shared__ int cur[1 << SHIFT];
    int k = blockIdx.x, t = threadIdx.x;
    int d0 = k << SHIFT;
    for (int i = t; i < (1 << SHIFT); i += 256) {
        int d = d0 + i;
        cur[i] = (d < n) ? row_ptr[d] : 0;
    }
    __syncthreads();
    int base = bucketBase[k], cnt = bucketTotal[k];
    for (int i = t; i < cnt; i += 256) {
        int2 e = bedges[base + i];
        float w = dinv[e.x];
        int p = atomicAdd(&cur[e.y - d0], 1);
        colw[p] = make_int2(e.x, __float_as_int(w));
    }
}

// ---------------- GEMMs (4x4 register tile, K-chunked LDS) ----------------
#define FMA16(a, b, acc)                                                     \
    acc[0][0] = fmaf(a.x, b.x, acc[0][0]); acc[0][1] = fmaf(a.x, b.y, acc[0][1]); \
    acc[0][2] = fmaf(a.x, b.z, acc[0][2]); acc[0][3] = fmaf(a.x, b.w, acc[0][3]); \
    acc[1][0] = fmaf(a.y, b.x, acc[1][0]); acc[1][1] = fmaf(a.y, b.y, acc[1][1]); \
    acc[1][2] = fmaf(a.y, b.z, acc[1][2]); acc[1][3] = fmaf(a.y, b.w, acc[1][3]); \
    acc[2][0] = fmaf(a.z, b.x, acc[2][0]); acc[2][1] = fmaf(a.z, b.y, acc[2][1]); \
    acc[2][2] = fmaf(a.z, b.z, acc[2][2]); acc[2][3] = fmaf(a.z, b.w, acc[2][3]); \
    acc[3][0] = fmaf(a.w, b.x, acc[3][0]); acc[3][1] = fmaf(a.w, b.y, acc[3][1]); \
    acc[3][2] = fmaf(a.w, b.z, acc[3][2]); acc[3][3] = fmaf(a.w, b.w, acc[3][3]);

__global__ __launch_bounds__(256) void gemm1_kernel(const float* __restrict__ In,
                                                    const float* __restrict__ W,
                                                    __hip_bfloat16* __restrict__ Out, int n) {
    __shared__ float sInT[32][32];   // [k][row]
    __shared__ float sW[32][128];
    int t = threadIdx.x;
    int tr = t >> 5, tc = t & 31;
    int rbase = blockIdx.x * 32;
    float acc[4][4] = {};
    for (int kt = 0; kt < 128; kt += 32) {
        {
            int r = t >> 3, k4 = (t & 7) << 2;
            int gr = rbase + r;
            float4 v = make_float4(0.f, 0.f, 0.f, 0.f);
            if (gr < n) v = *(const float4*)&In[(size_t)gr * 128 + kt + k4];
            sInT[k4 + 0][r] = v.x; sInT[k4 + 1][r] = v.y;
            sInT[k4 + 2][r] = v.z; sInT[k4 + 3][r] = v.w;
        }
        {
            const float4* Wv = (const float4*)&W[(size_t)kt * 128];
            float4* sWv = (float4*)&sW[0][0];
            for (int i = t; i < 1024; i += 256) sWv[i] = Wv[i];
        }
        __syncthreads();
#pragma unroll
        for (int k = 0; k < 32; ++k) {
            float4 a = *(const float4*)&sInT[k][tr << 2];
            float4 b = *(const float4*)&sW[k][tc << 2];
            FMA16(a, b, acc)
        }
        __syncthreads();
    }
#pragma unroll
    for (int i = 0; i < 4; ++i) {
        int gr = rbase + (tr << 2) + i;
        if (gr < n) {
            uint2 pk;
            pk.x = pk2(acc[i][0], acc[i][1]);
            pk.y = pk2(acc[i][2], acc[i][3]);
            *(uint2*)((uint32_t*)Out + (size_t)gr * 64 + (tc << 1)) = pk;
        }
    }
}

__global__ __launch_bounds__(256) void gemmA_kernel(const __hip_bfloat16* __restrict__ In,
                                                    const float* __restrict__ W,
                                                    __hip_bfloat16* __restrict__ Out, int n) {
    __shared__ float sInT[32][64];
    __shared__ float sW[32][64];
    int t = threadIdx.x;
    int tr = t >> 4, tc = t & 15;
    int rbase = blockIdx.x * 64;
    float acc[4][4] = {};
    const uint32_t* Inu = (const uint32_t*)In;
    for (int kt = 0; kt < 128; kt += 32) {
        for (int i = t; i < 1024; i += 256) {
            int r = i >> 4, ku = i & 15;
            int gr = rbase + r;
            uint32_t u = (gr < n) ? Inu[(size_t)gr * 64 + (kt >> 1) + ku] : 0u;
            sInT[2 * ku][r] = lo16f(u);
            sInT[2 * ku + 1][r] = hi16f(u);
        }
        {
            const float4* Wv = (const float4*)&W[(size_t)kt * 64];
            float4* sWv = (float4*)&sW[0][0];
            for (int i = t; i < 512; i += 256) sWv[i] = Wv[i];
        }
        __syncthreads();
#pragma unroll
        for (int k = 0; k < 32; ++k) {
            float4 a = *(const float4*)&sInT[k][tr << 2];
            float4 b = *(const float4*)&sW[k][tc << 2];
            FMA16(a, b, acc)
        }
        __syncthreads();
    }
#pragma unroll
    for (int i = 0; i < 4; ++i) {
        int gr = rbase + (tr << 2) + i;
        if (gr < n) {
            uint2 pk;
            pk.x = pk2(acc[i][0], acc[i][1]);
            pk.y = pk2(acc[i][2], acc[i][3]);
            *(uint2*)((uint32_t*)Out + (size_t)gr * 32 + (tc << 1)) = pk;
        }
    }
}

__global__ __launch_bounds__(256) void gemmB_kernel(const float* __restrict__ In,
                                                    const float* __restrict__ W,
                                                    __hip_bfloat16* __restrict__ Out, int n) {
    __shared__ float sInT[32][64];
    __shared__ float sW[32][64];
    int t = threadIdx.x;
    int tr = t >> 4, tc = t & 15;
    int rbase = blockIdx.x * 64;
    float acc[4][4] = {};
    for (int kt = 0; kt < 64; kt += 32) {
        for (int i = t; i < 512; i += 256) {
            int r = i >> 3, k4 = (i & 7) << 2;
            int gr = rbase + r;
            float4 v = make_float4(0.f, 0.f, 0.f, 0.f);
            if (gr < n) v = *(const float4*)&In[(size_t)gr * 64 + kt + k4];
            sInT[k4 + 0][r] = v.x; sInT[k4 + 1][r] = v.y;
            sInT[k4 + 2][r] = v.z; sInT[k4 + 3][r] = v.w;
        }
        {
            const float4* Wv = (const float4*)&W[(size_t)kt * 64];
            float4* sWv = (float4*)&sW[0][0];
            for (int i = t; i < 512; i += 256) sWv[i] = Wv[i];
        }
        __syncthreads();
#pragma unroll
        for (int k = 0; k < 32; ++k) {
            float4 a = *(const float4*)&sInT[k][tr << 2];
            float4 b = *(const float4*)&sW[k][tc << 2];
            FMA16(a, b, acc)
        }
        __syncthreads();
    }
#pragma unroll
    for (int i = 0; i < 4; ++i) {
        int gr = rbase + (tr << 2) + i;
        if (gr < n) {
            uint2 pk;
            pk.x = pk2(acc[i][0], acc[i][1]);
            pk.y = pk2(acc[i][2], acc[i][3]);
            *(uint2*)((uint32_t*)Out + (size_t)gr * 32 + (tc << 1)) = pk;
        }
    }
}

// ------- Gathers: 32-lane groups, 2 edges per load instruction, unroll-8 -------
// Row d per wave; group g in {0,1} handles edges e+g. Lane sl in [0,32).
// gather128: lane sl covers feats [4sl, 4sl+4) via uint2 row loads.
__global__ __launch_bounds__(256) void gather128_kernel(
    const __hip_bfloat16* __restrict__ xw, const int* __restrict__ row_ptr,
    const int2* __restrict__ colw, const float* __restrict__ dinv,
    const float* __restrict__ b1, __hip_bfloat16* __restrict__ h1, int n) {
    int w = threadIdx.x >> 6, lane = threadIdx.x & 63;
    int g = lane >> 5, sl = lane & 31;
    int d = blockIdx.x * 4 + w;
    if (d >= n) return;
    float dd = dinv[d];
    int p0 = row_ptr[d], p1 = row_ptr[d + 1];
    const uint2* X2 = (const uint2*)xw;   // 32 uint2 per 128-feat row
    float a0 = 0.f, a1 = 0.f, a2 = 0.f, a3 = 0.f;
    float c0 = 0.f, c1 = 0.f, c2 = 0.f, c3 = 0.f;
    if (g == 0) {   // self-loop term counted once
        uint2 v = X2[(size_t)d * 32 + sl];
        a0 = dd * lo16f(v.x); a1 = dd * hi16f(v.x);
        a2 = dd * lo16f(v.y); a3 = dd * hi16f(v.y);
    }
    int e = p0;
    for (; e + 8 <= p1; e += 8) {    // 4 pairs; my edges e+g, e+2+g, e+4+g, e+6+g
        int2 q0 = colw[e + g], q1 = colw[e + 2 + g], q2 = colw[e + 4 + g], q3 = colw[e + 6 + g];
        uint2 v0 = X2[(size_t)q0.x * 32 + sl];
        uint2 v1 = X2[(size_t)q1.x * 32 + sl];
        uint2 v2 = X2[(size_t)q2.x * 32 + sl];
        uint2 v3 = X2[(size_t)q3.x * 32 + sl];
        float w0 = __int_as_float(q0.y), w1 = __int_as_float(q1.y);
        float w2 = __int_as_float(q2.y), w3 = __int_as_float(q3.y);
        a0 = fmaf(w0, lo16f(v0.x), a0); a1 = fmaf(w0, hi16f(v0.x), a1);
        a2 = fmaf(w0, lo16f(v0.y), a2); a3 = fmaf(w0, hi16f(v0.y), a3);
        c0 = fmaf(w1, lo16f(v1.x), c0); c1 = fmaf(w1, hi16f(v1.x), c1);
        c2 = fmaf(w1, lo16f(v1.y), c2); c3 = fmaf(w1, hi16f(v1.y), c3);
        a0 = fmaf(w2, lo16f(v2.x), a0); a1 = fmaf(w2, hi16f(v2.x), a1);
        a2 = fmaf(w2, lo16f(v2.y), a2); a3 = fmaf(w2, hi16f(v2.y), a3);
        c0 = fmaf(w3, lo16f(v3.x), c0); c1 = fmaf(w3, hi16f(v3.x), c1);
        c2 = fmaf(w3, lo16f(v3.y), c2); c3 = fmaf(w3, hi16f(v3.y), c3);
    }
    for (; e + 2 <= p1; e += 2) {    // single pair
        int2 q = colw[e + g];
        uint2 v = X2[(size_t)q.x * 32 + sl];
        float ww = __int_as_float(q.y);
        a0 = fmaf(ww, lo16f(v.x), a0); a1 = fmaf(ww, hi16f(v.x), a1);
        a2 = fmaf(ww, lo16f(v.y), a2); a3 = fmaf(ww, hi16f(v.y), a3);
    }
    if (e + g < p1) {                // 0 or 1 leftover (group 0 takes it)
        int2 q = colw[e + g];
        uint2 v = X2[(size_t)q.x * 32 + sl];
        float ww = __int_as_float(q.y);
        a0 = fmaf(ww, lo16f(v.x), a0); a1 = fmaf(ww, hi16f(v.x), a1);
        a2 = fmaf(ww, lo16f(v.y), a2); a3 = fmaf(ww, hi16f(v.y), a3);
    }
    a0 += c0; a1 += c1; a2 += c2; a3 += c3;
    a0 += __shfl_xor(a0, 32); a1 += __shfl_xor(a1, 32);
    a2 += __shfl_xor(a2, 32); a3 += __shfl_xor(a3, 32);
    if (g == 0) {
        float4 bb = ((const float4*)b1)[sl];
        a0 = fmaxf(fmaf(dd, a0, bb.x), 0.0f);
        a1 = fmaxf(fmaf(dd, a1, bb.y), 0.0f);
        a2 = fmaxf(fmaf(dd, a2, bb.z), 0.0f);
        a3 = fmaxf(fmaf(dd, a3, bb.w), 0.0f);
        uint2 pk;
        pk.x = pk2(a0, a1); pk.y = pk2(a2, a3);
        ((uint2*)h1)[(size_t)d * 32 + sl] = pk;
    }
}

// gather64: lane sl covers feats {2sl, 2sl+1} via uint32 row loads.
// OUT=0: fp32 out; OUT=1: bf16 out.
template<bool RELU, int OUT>
__global__ __launch_bounds__(256) void gather64b_kernel(
    const __hip_bfloat16* __restrict__ xw, const int* __restrict__ row_ptr,
    const int2* __restrict__ colw, const float* __restrict__ dinv,
    const float* __restrict__ b, void* __restrict__ out, int n) {
    int w = threadIdx.x >> 6, lane = threadIdx.x & 63;
    int g = lane >> 5, sl = lane & 31;
    int d = blockIdx.x * 4 + w;
    if (d >= n) return;
    float dd = dinv[d];
    int p0 = row_ptr[d], p1 = row_ptr[d + 1];
    const uint32_t* X = (const uint32_t*)xw;   // 32 u32 per 64-feat row
    float a0 = 0.f, a1 = 0.f, c0 = 0.f, c1 = 0.f;
    if (g == 0) {
        uint32_t v = X[(size_t)d * 32 + sl];
        a0 = dd * lo16f(v); a1 = dd * hi16f(v);
    }
    int e = p0;
    for (; e + 8 <= p1; e += 8) {
        int2 q0 = colw[e + g], q1 = colw[e + 2 + g], q2 = colw[e + 4 + g], q3 = colw[e + 6 + g];
        uint32_t v0 = X[(size_t)q0.x * 32 + sl];
        uint32_t v1 = X[(size_t)q1.x * 32 + sl];
        uint32_t v2 = X[(size_t)q2.x * 32 + sl];
        uint32_t v3 = X[(size_t)q3.x * 32 + sl];
        float w0 = __int_as_float(q0.y), w1 = __int_as_float(q1.y);
        float w2 = __int_as_float(q2.y), w3 = __int_as_float(q3.y);
        a0 = fmaf(w0, lo16f(v0), a0); a1 = fmaf(w0, hi16f(v0), a1);
        c0 = fmaf(w1, lo16f(v1), c0); c1 = fmaf(w1, hi16f(v1), c1);
        a0 = fmaf(w2, lo16f(v2), a0); a1 = fmaf(w2, hi16f(v2), a1);
        c0 = fmaf(w3, lo16f(v3), c0); c1 = fmaf(w3, hi16f(v3), c1);
    }
    for (; e + 2 <= p1; e += 2) {
        int2 q = colw[e + g];
        uint32_t v = X[(size_t)q.x * 32 + sl];
        float ww = __int_as_float(q.y);
        a0 = fmaf(ww, lo16f(v), a0); a1 = fmaf(ww, hi16f(v), a1);
    }
    if (e + g < p1) {
        int2 q = colw[e + g];
        uint32_t v = X[(size_t)q.x * 32 + sl];
        float ww = __int_as_float(q.y);
        a0 = fmaf(ww, lo16f(v), a0); a1 = fmaf(ww, hi16f(v), a1);
    }
    a0 += c0; a1 += c1;
    a0 += __shfl_xor(a0, 32);
    a1 += __shfl_xor(a1, 32);
    if (g == 0) {
        float2 bb = ((const float2*)b)[sl];
        float r0 = fmaf(dd, a0, bb.x);
        float r1 = fmaf(dd, a1, bb.y);
        if (RELU) { r0 = fmaxf(r0, 0.0f); r1 = fmaxf(r1, 0.0f); }
        if (OUT == 0) {
            ((float2*)out)[(size_t)d * 32 + sl] = make_float2(r0, r1);
        } else {
            ((uint32_t*)out)[(size_t)d * 32 + sl] = pk2(r0, r1);
        }
    }
}

// ---------------- Score: 8 edges per wave, 8-lane groups, uint4 row loads ----------
__global__ void score_kernel(const __hip_bfloat16* __restrict__ h, const int* __restrict__ pos,
                             const int* __restrict__ neg, int Ep, int En,
                             float* __restrict__ out) {
    int wid = (int)(((size_t)blockIdx.x * blockDim.x + threadIdx.x) >> 6);
    int lane = threadIdx.x & 63;
    int g = lane >> 3, sl = lane & 7;
    int ed = wid * 8 + g;
    int tot = Ep + En;
    if (ed >= tot) return;
    int j, i;
    if (ed < Ep) { j = pos[ed]; i = pos[Ep + ed]; }
    else { int e = ed - Ep; j = neg[e]; i = neg[En + e]; }
    const uint4* X = (const uint4*)h;  // 8 uint4 per 64-feat bf16 row
    uint4 vi = X[(size_t)i * 8 + sl];
    uint4 vj = X[(size_t)j * 8 + sl];
    float v;
    v = lo16f(vi.x) * lo16f(vj.x);
    v = fmaf(hi16f(vi.x), hi16f(vj.x), v);
    v = fmaf(lo16f(vi.y), lo16f(vj.y), v);
    v = fmaf(hi16f(vi.y), hi16f(vj.y), v);
    v = fmaf(lo16f(vi.z), lo16f(vj.z), v);
    v = fmaf(hi16f(vi.z), hi16f(vj.z), v);
    v = fmaf(lo16f(vi.w), lo16f(vj.w), v);
    v = fmaf(hi16f(vi.w), hi16f(vj.w), v);
#pragma unroll
    for (int o = 4; o > 0; o >>= 1) v += __shfl_xor(v, o);
    if (sl == 0) out[ed] = v;
}

extern "C" void kernel_launch(void* const* d_in, const int* in_sizes, int n_in,
                              void* d_out, int out_size, void* d_ws, size_t ws_size,
                              hipStream_t stream) {
    const float* x   = (const float*)d_in[0];
    const int* train = (const int*)d_in[1];
    const int* pos   = (const int*)d_in[2];
    const int* neg   = (const int*)d_in[3];
    const float* W1  = (const float*)d_in[4];
    const float* b1  = (const float*)d_in[5];
    const float* W2  = (const float*)d_in[6];
    const float* b2  = (const float*)d_in[7];
    const float* W3  = (const float*)d_in[8];
    const float* b3  = (const float*)d_in[9];

    const int n  = in_sizes[0] / 128;
    const int E  = in_sizes[1] / 2;
    const int Ep = in_sizes[2] / 2;
    const int En = in_sizes[3] / 2;

    const int B  = (E + ECH - 1) / ECH;         // partition chunks (391 for E=1.6M)
    const int NB = ((n - 1) >> SHIFT) + 1;      // buckets (391 for n=100K)

    // Workspace (~78 MB)
    char* wp = (char*)d_ws;
    auto alloc = [&](size_t bytes) { char* r = wp; wp += (bytes + 255) & ~(size_t)255; return r; };
    int*   count    = (int*)alloc((size_t)n * 4);
    int*   row_ptr  = (int*)alloc(((size_t)n + 1) * 4);
    int*   partial  = (int*)alloc(256 * 4);
    int*   bucketTotal = (int*)alloc(MAXNB * 4);
    int*   bucketBase  = (int*)alloc(MAXNB * 4);
    int2*  colw     = (int2*)alloc((size_t)E * 8);
    float* dinv     = (float*)alloc((size_t)n * 4);
    __hip_bfloat16* xw1 = (__hip_bfloat16*)alloc((size_t)n * 128 * 2);  // reused as h3(bf16 n*64)
    __hip_bfloat16* h1  = (__hip_bfloat16*)alloc((size_t)n * 128 * 2);
    __hip_bfloat16* P   = (__hip_bfloat16*)alloc((size_t)n * 64 * 2);   // xw2, later xw3
    __hip_bfloat16* h3  = xw1;
    __hip_bfloat16* xw3 = P;
    int2* bedges = (int2*)h1;       // alias: consumed before h1 is written
    int*  histG  = (int*)P;         // alias: NB*B*4 ~ 612KB, consumed before P is written

    float* out_scores = (float*)d_out;
    float* out_embed  = out_scores + (Ep + En);  // h2 lives here directly

    const int eb256 = (E + 255) / 256;
    const int nbs = (n + 1023) / 1024;

    // degrees -> row_ptr, dinv
    hipMemsetAsync(count, 0, (size_t)n * sizeof(int), stream);
    count_kernel<<<eb256, 256, 0, stream>>>(train + E, E, count);
    scan_partial_kernel<<<nbs, 256, 0, stream>>>(count, n, partial);
    scan_offsets_kernel<<<1, 256, 0, stream>>>(partial, nbs, row_ptr, n);
    scan_write_kernel<<<nbs, 256, 0, stream>>>(count, n, partial, row_ptr, dinv);

    // radix-partitioned CSR build (no global atomics, block-local writes)
    part_hist_kernel<<<B, 256, 0, stream>>>(train + E, E, B, NB, histG);
    part_scan_kernel<<<NB, 256, 0, stream>>>(histG, B, bucketTotal);
    bucket_base_kernel<<<1, 256, 0, stream>>>(bucketTotal, NB, bucketBase);
    part_scatter_kernel<<<B, 256, 0, stream>>>(train, train + E, E, B, NB, histG, bucketBase, bedges);
    csr_fill_kernel<<<NB, 256, 0, stream>>>(bedges, bucketBase, bucketTotal, row_ptr, dinv, n, colw);

    // Layer 1
    gemm1_kernel<<<(n + 31) / 32, 256, 0, stream>>>(x, W1, xw1, n);
    gather128_kernel<<<(n + 3) / 4, 256, 0, stream>>>(xw1, row_ptr, colw, dinv, b1, h1, n);
    gemmA_kernel<<<(n + 63) / 64, 256, 0, stream>>>(h1, W2, P, n);

    // Layer 2 (h2 written straight into out_embed, fp32)
    gather64b_kernel<true, 0><<<(n + 3) / 4, 256, 0, stream>>>(
        P, row_ptr, colw, dinv, b2, out_embed, n);

    // Layer 3 (h3 emitted bf16 for the score stage)
    gemmB_kernel<<<(n + 63) / 64, 256, 0, stream>>>(out_embed, W3, xw3, n);
    gather64b_kernel<false, 1><<<(n + 3) / 4, 256, 0, stream>>>(
        xw3, row_ptr, colw, dinv, b3, h3, n);

    // Scores: 8 edges per wave
    {
        int waves = (Ep + En + 7) / 8;
        score_kernel<<<(int)(((size_t)waves * 64 + 255) / 256), 256, 0, stream>>>(
            h3, pos, neg, Ep, En, out_scores);
    }
}

// Round 14
// 430.208 us; speedup vs baseline: 1.0368x; 1.0368x over previous
//
#include <hip/hip_runtime.h>
#include <hip/hip_bf16.h>

// GCN link prediction. Inputs fp32+int32; OUTPUT fp32 (scores[1M] ++ embed[n*64]).
// CSR gather + bf16 feature tables (fp32 math), register-tiled 4x4 GEMMs,
// device-wide scan, radix-partitioned CSR build, 8-edge/wave uint4 score,
// rows PADDED to multiple of 8 with (d, w=0) -> branch-free unroll-8 gathers.

#define ECH 4096      // edges per partition chunk
#define SHIFT 8       // dsts per bucket = 256
#define MAXNB 512     // max buckets (n <= 131072)

__device__ __forceinline__ float lo16f(uint32_t u) { uint32_t x = u << 16; float f; __builtin_memcpy(&f, &x, 4); return f; }
__device__ __forceinline__ float hi16f(uint32_t u) { uint32_t x = u & 0xffff0000u; float f; __builtin_memcpy(&f, &x, 4); return f; }
__device__ __forceinline__ float u16f(unsigned short u) { uint32_t x = (uint32_t)u << 16; float f; __builtin_memcpy(&f, &x, 4); return f; }
__device__ __forceinline__ uint32_t pk2(float a, float b) {
    union { __hip_bfloat162 h; uint32_t u; } cv;
    cv.h = __hip_bfloat162(__float2bfloat16(a), __float2bfloat16(b));
    return cv.u;
}
__device__ __forceinline__ unsigned short bf16bits(float a) {
    union { __hip_bfloat16 b; unsigned short u; } cv;
    cv.b = __float2bfloat16(a);
    return cv.u;
}
__device__ __forceinline__ int pad8(int c) { return (c + 7) & ~7; }

// ---------------- degree count + (padded) row_ptr scan ----------------
__global__ void count_kernel(const int* __restrict__ dst, int E, int* __restrict__ count) {
    int e = blockIdx.x * blockDim.x + threadIdx.x;
    if (e < E) atomicAdd(&count[dst[e]], 1);
}

__global__ __launch_bounds__(256) void scan_partial_kernel(const int* __restrict__ count, int n,
                                                           int* __restrict__ partial) {
    __shared__ int red[256];
    int t = threadIdx.x;
    int base = blockIdx.x * 1024 + t * 4;
    int s = 0;
#pragma unroll
    for (int i = 0; i < 4; ++i) {
        int idx = base + i;
        if (idx < n) s += pad8(count[idx]);
    }
    red[t] = s;
    __syncthreads();
    for (int o = 128; o > 0; o >>= 1) {
        if (t < o) red[t] += red[t + o];
        __syncthreads();
    }
    if (t == 0) partial[blockIdx.x] = red[0];
}

__global__ __launch_bounds__(256) void scan_offsets_kernel(int* __restrict__ partial, int nb,
                                                           int* __restrict__ row_ptr, int n) {
    __shared__ int sc[256];
    int t = threadIdx.x;
    sc[t] = (t < nb) ? partial[t] : 0;
    __syncthreads();
    for (int o = 1; o < 256; o <<= 1) {
        int v = sc[t];
        int u = (t >= o) ? sc[t - o] : 0;
        __syncthreads();
        sc[t] = v + u;
        __syncthreads();
    }
    if (t < nb) partial[t] = (t > 0) ? sc[t - 1] : 0;  // exclusive
    if (t == 0) row_ptr[n] = sc[255];
}

__global__ __launch_bounds__(256) void scan_write_kernel(const int* __restrict__ count, int n,
                                                         const int* __restrict__ partial,
                                                         int* __restrict__ row_ptr,
                                                         float* __restrict__ dinv) {
    __shared__ int sc[256];
    int t = threadIdx.x;
    int base = blockIdx.x * 1024 + t * 4;
    int c[4];
    int s = 0;
#pragma unroll
    for (int i = 0; i < 4; ++i) {
        int idx = base + i;
        c[i] = (idx < n) ? count[idx] : 0;
        s += pad8(c[i]);
    }
    sc[t] = s;
    __syncthreads();
    for (int o = 1; o < 256; o <<= 1) {
        int v = sc[t];
        int u = (t >= o) ? sc[t - o] : 0;
        __syncthreads();
        sc[t] = v + u;
        __syncthreads();
    }
    int run = partial[blockIdx.x] + ((t > 0) ? sc[t - 1] : 0);
#pragma unroll
    for (int i = 0; i < 4; ++i) {
        int idx = base + i;
        if (idx < n) {
            row_ptr[idx] = run;
            dinv[idx] = rsqrtf((float)c[i] + 1.0f);
            run += pad8(c[i]);
        }
    }
}

// ---------------- radix partition: edges -> buckets -> CSR ----------------
__global__ __launch_bounds__(256) void part_hist_kernel(const int* __restrict__ dst, int E,
                                                        int B, int NB, int* __restrict__ histG) {
    __shared__ int h[MAXNB];
    int t = threadIdx.x, blk = blockIdx.x;
    for (int i = t; i < NB; i += 256) h[i] = 0;
    __syncthreads();
    int lo = blk * ECH, hi = min(lo + ECH, E);
    for (int i = lo + t; i < hi; i += 256) atomicAdd(&h[dst[i] >> SHIFT], 1);
    __syncthreads();
    for (int k = t; k < NB; k += 256) histG[(size_t)k * B + blk] = h[k];
}

__global__ __launch_bounds__(256) void part_scan_kernel(int* __restrict__ histG, int B,
                                                        int* __restrict__ bucketTotal) {
    __shared__ int sc[1024];   // supports B <= 1024
    int k = blockIdx.x, t = threadIdx.x;
    for (int i = t; i < 1024; i += 256) sc[i] = (i < B) ? histG[(size_t)k * B + i] : 0;
    __syncthreads();
    for (int o = 1; o < 1024; o <<= 1) {
        int v[4];
#pragma unroll
        for (int j = 0; j < 4; ++j) { int i = t + j * 256; v[j] = (i >= o) ? sc[i - o] : 0; }
        __syncthreads();
#pragma unroll
        for (int j = 0; j < 4; ++j) sc[t + j * 256] += v[j];
        __syncthreads();
    }
    for (int i = t; i < B; i += 256) histG[(size_t)k * B + i] = (i > 0) ? sc[i - 1] : 0;
    if (t == 0) bucketTotal[k] = sc[B - 1];
}

__global__ __launch_bounds__(256) void bucket_base_kernel(const int* __restrict__ bucketTotal,
                                                          int NB, int* __restrict__ bucketBase) {
    __shared__ int sc[MAXNB];
    int t = threadIdx.x;
    for (int i = t; i < MAXNB; i += 256) sc[i] = (i < NB) ? bucketTotal[i] : 0;
    __syncthreads();
    for (int o = 1; o < MAXNB; o <<= 1) {
        int v[MAXNB / 256];
#pragma unroll
        for (int j = 0; j < MAXNB / 256; ++j) { int i = t + j * 256; v[j] = (i >= o) ? sc[i - o] : 0; }
        __syncthreads();
#pragma unroll
        for (int j = 0; j < MAXNB / 256; ++j) sc[t + j * 256] += v[j];
        __syncthreads();
    }
    for (int i = t; i < NB; i += 256) bucketBase[i] = (i > 0) ? sc[i - 1] : 0;
}

__global__ __launch_bounds__(256) void part_scatter_kernel(
    const int* __restrict__ src, const int* __restrict__ dst, int E, int B, int NB,
    const int* __restrict__ histG, const int* __restrict__ bucketBase,
    int2* __restrict__ bedges) {
    __shared__ int cur[MAXNB];
    int t = threadIdx.x, blk = blockIdx.x;
    for (int k = t; k < NB; k += 256) cur[k] = bucketBase[k] + histG[(size_t)k * B + blk];
    __syncthreads();
    int lo = blk * ECH, hi = min(lo + ECH, E);
    for (int i = lo + t; i < hi; i += 256) {
        int s = src[i], d = dst[i];
        int p = atomicAdd(&cur[d >> SHIFT], 1);
        bedges[p] = make_int2(s, d);
    }
}

// Fill CSR (padded layout): real edges via LDS cursors, then pad each dst's
// tail [cur, row_ptr[d+1]) with (d, w=0) no-op entries.
__global__ __launch_bounds__(256) void csr_fill_kernel(
    const int2* __restrict__ bedges, const int* __restrict__ bucketBase,
    const int* __restrict__ bucketTotal, const int* __restrict__ row_ptr,
    const float* __restrict__ dinv, int n, int2* __restrict__ colw) {
    __shared__ int cur[1 << SHIFT];
    int k = blockIdx.x, t = threadIdx.x;
    int d0 = k << SHIFT;
    for (int i = t; i < (1 << SHIFT); i += 256) {
        int d = d0 + i;
        cur[i] = (d < n) ? row_ptr[d] : 0;
    }
    __syncthreads();
    int base = bucketBase[k], cnt = bucketTotal[k];
    for (int i = t; i < cnt; i += 256) {
        int2 e = bedges[base + i];
        float w = dinv[e.x];
        int p = atomicAdd(&cur[e.y - d0], 1);
        colw[p] = make_int2(e.x, __float_as_int(w));
    }
    __syncthreads();
    for (int i = t; i < (1 << SHIFT); i += 256) {
        int d = d0 + i;
        if (d < n) {
            int pend = row_ptr[d + 1];
            for (int p = cur[i]; p < pend; ++p) colw[p] = make_int2(d, 0);
        }
    }
}

// ---------------- GEMMs (4x4 register tile, K-chunked LDS) ----------------
#define FMA16(a, b, acc)                                                     \
    acc[0][0] = fmaf(a.x, b.x, acc[0][0]); acc[0][1] = fmaf(a.x, b.y, acc[0][1]); \
    acc[0][2] = fmaf(a.x, b.z, acc[0][2]); acc[0][3] = fmaf(a.x, b.w, acc[0][3]); \
    acc[1][0] = fmaf(a.y, b.x, acc[1][0]); acc[1][1] = fmaf(a.y, b.y, acc[1][1]); \
    acc[1][2] = fmaf(a.y, b.z, acc[1][2]); acc[1][3] = fmaf(a.y, b.w, acc[1][3]); \
    acc[2][0] = fmaf(a.z, b.x, acc[2][0]); acc[2][1] = fmaf(a.z, b.y, acc[2][1]); \
    acc[2][2] = fmaf(a.z, b.z, acc[2][2]); acc[2][3] = fmaf(a.z, b.w, acc[2][3]); \
    acc[3][0] = fmaf(a.w, b.x, acc[3][0]); acc[3][1] = fmaf(a.w, b.y, acc[3][1]); \
    acc[3][2] = fmaf(a.w, b.z, acc[3][2]); acc[3][3] = fmaf(a.w, b.w, acc[3][3]);

__global__ __launch_bounds__(256) void gemm1_kernel(const float* __restrict__ In,
                                                    const float* __restrict__ W,
                                                    __hip_bfloat16* __restrict__ Out, int n) {
    __shared__ float sInT[32][32];   // [k][row]
    __shared__ float sW[32][128];
    int t = threadIdx.x;
    int tr = t >> 5, tc = t & 31;
    int rbase = blockIdx.x * 32;
    float acc[4][4] = {};
    for (int kt = 0; kt < 128; kt += 32) {
        {
            int r = t >> 3, k4 = (t & 7) << 2;
            int gr = rbase + r;
            float4 v = make_float4(0.f, 0.f, 0.f, 0.f);
            if (gr < n) v = *(const float4*)&In[(size_t)gr * 128 + kt + k4];
            sInT[k4 + 0][r] = v.x; sInT[k4 + 1][r] = v.y;
            sInT[k4 + 2][r] = v.z; sInT[k4 + 3][r] = v.w;
        }
        {
            const float4* Wv = (const float4*)&W[(size_t)kt * 128];
            float4* sWv = (float4*)&sW[0][0];
            for (int i = t; i < 1024; i += 256) sWv[i] = Wv[i];
        }
        __syncthreads();
#pragma unroll
        for (int k = 0; k < 32; ++k) {
            float4 a = *(const float4*)&sInT[k][tr << 2];
            float4 b = *(const float4*)&sW[k][tc << 2];
            FMA16(a, b, acc)
        }
        __syncthreads();
    }
#pragma unroll
    for (int i = 0; i < 4; ++i) {
        int gr = rbase + (tr << 2) + i;
        if (gr < n) {
            uint2 pk;
            pk.x = pk2(acc[i][0], acc[i][1]);
            pk.y = pk2(acc[i][2], acc[i][3]);
            *(uint2*)((uint32_t*)Out + (size_t)gr * 64 + (tc << 1)) = pk;
        }
    }
}

__global__ __launch_bounds__(256) void gemmA_kernel(const __hip_bfloat16* __restrict__ In,
                                                    const float* __restrict__ W,
                                                    __hip_bfloat16* __restrict__ Out, int n) {
    __shared__ float sInT[32][64];
    __shared__ float sW[32][64];
    int t = threadIdx.x;
    int tr = t >> 4, tc = t & 15;
    int rbase = blockIdx.x * 64;
    float acc[4][4] = {};
    const uint32_t* Inu = (const uint32_t*)In;
    for (int kt = 0; kt < 128; kt += 32) {
        for (int i = t; i < 1024; i += 256) {
            int r = i >> 4, ku = i & 15;
            int gr = rbase + r;
            uint32_t u = (gr < n) ? Inu[(size_t)gr * 64 + (kt >> 1) + ku] : 0u;
            sInT[2 * ku][r] = lo16f(u);
            sInT[2 * ku + 1][r] = hi16f(u);
        }
        {
            const float4* Wv = (const float4*)&W[(size_t)kt * 64];
            float4* sWv = (float4*)&sW[0][0];
            for (int i = t; i < 512; i += 256) sWv[i] = Wv[i];
        }
        __syncthreads();
#pragma unroll
        for (int k = 0; k < 32; ++k) {
            float4 a = *(const float4*)&sInT[k][tr << 2];
            float4 b = *(const float4*)&sW[k][tc << 2];
            FMA16(a, b, acc)
        }
        __syncthreads();
    }
#pragma unroll
    for (int i = 0; i < 4; ++i) {
        int gr = rbase + (tr << 2) + i;
        if (gr < n) {
            uint2 pk;
            pk.x = pk2(acc[i][0], acc[i][1]);
            pk.y = pk2(acc[i][2], acc[i][3]);
            *(uint2*)((uint32_t*)Out + (size_t)gr * 32 + (tc << 1)) = pk;
        }
    }
}

__global__ __launch_bounds__(256) void gemmB_kernel(const float* __restrict__ In,
                                                    const float* __restrict__ W,
                                                    __hip_bfloat16* __restrict__ Out, int n) {
    __shared__ float sInT[32][64];
    __shared__ float sW[32][64];
    int t = threadIdx.x;
    int tr = t >> 4, tc = t & 15;
    int rbase = blockIdx.x * 64;
    float acc[4][4] = {};
    for (int kt = 0; kt < 64; kt += 32) {
        for (int i = t; i < 512; i += 256) {
            int r = i >> 3, k4 = (i & 7) << 2;
            int gr = rbase + r;
            float4 v = make_float4(0.f, 0.f, 0.f, 0.f);
            if (gr < n) v = *(const float4*)&In[(size_t)gr * 64 + kt + k4];
            sInT[k4 + 0][r] = v.x; sInT[k4 + 1][r] = v.y;
            sInT[k4 + 2][r] = v.z; sInT[k4 + 3][r] = v.w;
        }
        {
            const float4* Wv = (const float4*)&W[(size_t)kt * 64];
            float4* sWv = (float4*)&sW[0][0];
            for (int i = t; i < 512; i += 256) sWv[i] = Wv[i];
        }
        __syncthreads();
#pragma unroll
        for (int k = 0; k < 32; ++k) {
            float4 a = *(const float4*)&sInT[k][tr << 2];
            float4 b = *(const float4*)&sW[k][tc << 2];
            FMA16(a, b, acc)
        }
        __syncthreads();
    }
#pragma unroll
    for (int i = 0; i < 4; ++i) {
        int gr = rbase + (tr << 2) + i;
        if (gr < n) {
            uint2 pk;
            pk.x = pk2(acc[i][0], acc[i][1]);
            pk.y = pk2(acc[i][2], acc[i][3]);
            *(uint2*)((uint32_t*)Out + (size_t)gr * 32 + (tc << 1)) = pk;
        }
    }
}

// ---- Gathers (one wave per dst row, branch-free unroll-8, dual accumulators) ----
// Padded rows: (p1 - p0) % 8 == 0, pads are (d, w=0) no-ops.
__global__ __launch_bounds__(256) void gather128_kernel(
    const __hip_bfloat16* __restrict__ xw, const int* __restrict__ row_ptr,
    const int2* __restrict__ colw, const float* __restrict__ dinv,
    const float* __restrict__ b1, __hip_bfloat16* __restrict__ h1, int n) {
    int w = threadIdx.x >> 6, l = threadIdx.x & 63;
    int d = blockIdx.x * 4 + w;
    if (d >= n) return;
    float dd = dinv[d];
    int p0 = row_ptr[d], p1 = row_ptr[d + 1];
    const uint32_t* X = (const uint32_t*)xw;
    uint32_t v = X[(size_t)d * 64 + l];
    float a0 = dd * lo16f(v), a1 = dd * hi16f(v);
    float c0a = 0.f, c1a = 0.f;   // second accumulator pair (chain break)
    for (int e = p0; e < p1; e += 8) {
        int2 q0 = colw[e], q1 = colw[e + 1], q2 = colw[e + 2], q3 = colw[e + 3];
        int2 q4 = colw[e + 4], q5 = colw[e + 5], q6 = colw[e + 6], q7 = colw[e + 7];
        uint32_t v0 = X[(size_t)q0.x * 64 + l];
        uint32_t v1 = X[(size_t)q1.x * 64 + l];
        uint32_t v2 = X[(size_t)q2.x * 64 + l];
        uint32_t v3 = X[(size_t)q3.x * 64 + l];
        uint32_t v4 = X[(size_t)q4.x * 64 + l];
        uint32_t v5 = X[(size_t)q5.x * 64 + l];
        uint32_t v6 = X[(size_t)q6.x * 64 + l];
        uint32_t v7 = X[(size_t)q7.x * 64 + l];
        float w0 = __int_as_float(q0.y), w1 = __int_as_float(q1.y);
        float w2 = __int_as_float(q2.y), w3 = __int_as_float(q3.y);
        float w4 = __int_as_float(q4.y), w5 = __int_as_float(q5.y);
        float w6 = __int_as_float(q6.y), w7 = __int_as_float(q7.y);
        a0 = fmaf(w0, lo16f(v0), a0);  a1 = fmaf(w0, hi16f(v0), a1);
        c0a = fmaf(w1, lo16f(v1), c0a); c1a = fmaf(w1, hi16f(v1), c1a);
        a0 = fmaf(w2, lo16f(v2), a0);  a1 = fmaf(w2, hi16f(v2), a1);
        c0a = fmaf(w3, lo16f(v3), c0a); c1a = fmaf(w3, hi16f(v3), c1a);
        a0 = fmaf(w4, lo16f(v4), a0);  a1 = fmaf(w4, hi16f(v4), a1);
        c0a = fmaf(w5, lo16f(v5), c0a); c1a = fmaf(w5, hi16f(v5), c1a);
        a0 = fmaf(w6, lo16f(v6), a0);  a1 = fmaf(w6, hi16f(v6), a1);
        c0a = fmaf(w7, lo16f(v7), c0a); c1a = fmaf(w7, hi16f(v7), c1a);
    }
    a0 += c0a; a1 += c1a;
    a0 = fmaxf(fmaf(dd, a0, b1[2 * l]), 0.0f);
    a1 = fmaxf(fmaf(dd, a1, b1[2 * l + 1]), 0.0f);
    ((uint32_t*)h1)[(size_t)d * 64 + l] = pk2(a0, a1);
}

// OUT=0: fp32 out; OUT=1: bf16 out.
template<bool RELU, int OUT>
__global__ __launch_bounds__(256) void gather64b_kernel(
    const __hip_bfloat16* __restrict__ xw, const int* __restrict__ row_ptr,
    const int2* __restrict__ colw, const float* __restrict__ dinv,
    const float* __restrict__ b, void* __restrict__ out, int n) {
    int w = threadIdx.x >> 6, l = threadIdx.x & 63;
    int d = blockIdx.x * 4 + w;
    if (d >= n) return;
    float dd = dinv[d];
    int p0 = row_ptr[d], p1 = row_ptr[d + 1];
    const unsigned short* X = (const unsigned short*)xw;
    float a = dd * u16f(X[(size_t)d * 64 + l]);
    float c = 0.f;   // second accumulator (chain break)
    for (int e = p0; e < p1; e += 8) {
        int2 q0 = colw[e], q1 = colw[e + 1], q2 = colw[e + 2], q3 = colw[e + 3];
        int2 q4 = colw[e + 4], q5 = colw[e + 5], q6 = colw[e + 6], q7 = colw[e + 7];
        unsigned short v0 = X[(size_t)q0.x * 64 + l];
        unsigned short v1 = X[(size_t)q1.x * 64 + l];
        unsigned short v2 = X[(size_t)q2.x * 64 + l];
        unsigned short v3 = X[(size_t)q3.x * 64 + l];
        unsigned short v4 = X[(size_t)q4.x * 64 + l];
        unsigned short v5 = X[(size_t)q5.x * 64 + l];
        unsigned short v6 = X[(size_t)q6.x * 64 + l];
        unsigned short v7 = X[(size_t)q7.x * 64 + l];
        a = fmaf(__int_as_float(q0.y), u16f(v0), a);
        c = fmaf(__int_as_float(q1.y), u16f(v1), c);
        a = fmaf(__int_as_float(q2.y), u16f(v2), a);
        c = fmaf(__int_as_float(q3.y), u16f(v3), c);
        a = fmaf(__int_as_float(q4.y), u16f(v4), a);
        c = fmaf(__int_as_float(q5.y), u16f(v5), c);
        a = fmaf(__int_as_float(q6.y), u16f(v6), a);
        c = fmaf(__int_as_float(q7.y), u16f(v7), c);
    }
    a += c;
    float r = fmaf(dd, a, b[l]);
    if (RELU) r = fmaxf(r, 0.0f);
    if (OUT == 0) ((float*)out)[(size_t)d * 64 + l] = r;
    else ((unsigned short*)out)[(size_t)d * 64 + l] = bf16bits(r);
}

// ---------------- Score: 8 edges per wave, 8-lane groups, uint4 row loads ----------
__global__ void score_kernel(const __hip_bfloat16* __restrict__ h, const int* __restrict__ pos,
                             const int* __restrict__ neg, int Ep, int En,
                             float* __restrict__ out) {
    int wid = (int)(((size_t)blockIdx.x * blockDim.x + threadIdx.x) >> 6);
    int lane = threadIdx.x & 63;
    int g = lane >> 3, sl = lane & 7;
    int ed = wid * 8 + g;
    int tot = Ep + En;
    if (ed >= tot) return;
    int j, i;
    if (ed < Ep) { j = pos[ed]; i = pos[Ep + ed]; }
    else { int e = ed - Ep; j = neg[e]; i = neg[En + e]; }
    const uint4* X = (const uint4*)h;  // 8 uint4 per 64-feat bf16 row
    uint4 vi = X[(size_t)i * 8 + sl];
    uint4 vj = X[(size_t)j * 8 + sl];
    float v;
    v = lo16f(vi.x) * lo16f(vj.x);
    v = fmaf(hi16f(vi.x), hi16f(vj.x), v);
    v = fmaf(lo16f(vi.y), lo16f(vj.y), v);
    v = fmaf(hi16f(vi.y), hi16f(vj.y), v);
    v = fmaf(lo16f(vi.z), lo16f(vj.z), v);
    v = fmaf(hi16f(vi.z), hi16f(vj.z), v);
    v = fmaf(lo16f(vi.w), lo16f(vj.w), v);
    v = fmaf(hi16f(vi.w), hi16f(vj.w), v);
#pragma unroll
    for (int o = 4; o > 0; o >>= 1) v += __shfl_xor(v, o);
    if (sl == 0) out[ed] = v;
}

extern "C" void kernel_launch(void* const* d_in, const int* in_sizes, int n_in,
                              void* d_out, int out_size, void* d_ws, size_t ws_size,
                              hipStream_t stream) {
    const float* x   = (const float*)d_in[0];
    const int* train = (const int*)d_in[1];
    const int* pos   = (const int*)d_in[2];
    const int* neg   = (const int*)d_in[3];
    const float* W1  = (const float*)d_in[4];
    const float* b1  = (const float*)d_in[5];
    const float* W2  = (const float*)d_in[6];
    const float* b2  = (const float*)d_in[7];
    const float* W3  = (const float*)d_in[8];
    const float* b3  = (const float*)d_in[9];

    const int n  = in_sizes[0] / 128;
    const int E  = in_sizes[1] / 2;
    const int Ep = in_sizes[2] / 2;
    const int En = in_sizes[3] / 2;

    const int B  = (E + ECH - 1) / ECH;         // partition chunks (391 for E=1.6M)
    const int NB = ((n - 1) >> SHIFT) + 1;      // buckets (391 for n=100K)

    // Workspace (~85 MB; padded colw needs E + 8n entries)
    char* wp = (char*)d_ws;
    auto alloc = [&](size_t bytes) { char* r = wp; wp += (bytes + 255) & ~(size_t)255; return r; };
    int*   count    = (int*)alloc((size_t)n * 4);
    int*   row_ptr  = (int*)alloc(((size_t)n + 1) * 4);
    int*   partial  = (int*)alloc(256 * 4);
    int*   bucketTotal = (int*)alloc(MAXNB * 4);
    int*   bucketBase  = (int*)alloc(MAXNB * 4);
    int2*  colw     = (int2*)alloc(((size_t)E + 8 * (size_t)n) * 8);
    float* dinv     = (float*)alloc((size_t)n * 4);
    __hip_bfloat16* xw1 = (__hip_bfloat16*)alloc((size_t)n * 128 * 2);  // reused as h3(bf16 n*64)
    __hip_bfloat16* h1  = (__hip_bfloat16*)alloc((size_t)n * 128 * 2);
    __hip_bfloat16* P   = (__hip_bfloat16*)alloc((size_t)n * 64 * 2);   // xw2, later xw3
    __hip_bfloat16* h3  = xw1;
    __hip_bfloat16* xw3 = P;
    int2* bedges = (int2*)h1;       // alias: consumed before h1 is written
    int*  histG  = (int*)P;         // alias: NB*B*4 ~ 612KB, consumed before P is written

    float* out_scores = (float*)d_out;
    float* out_embed  = out_scores + (Ep + En);  // h2 lives here directly

    const int eb256 = (E + 255) / 256;
    const int nbs = (n + 1023) / 1024;

    // degrees -> padded row_ptr, dinv
    hipMemsetAsync(count, 0, (size_t)n * sizeof(int), stream);
    count_kernel<<<eb256, 256, 0, stream>>>(train + E, E, count);
    scan_partial_kernel<<<nbs, 256, 0, stream>>>(count, n, partial);
    scan_offsets_kernel<<<1, 256, 0, stream>>>(partial, nbs, row_ptr, n);
    scan_write_kernel<<<nbs, 256, 0, stream>>>(count, n, partial, row_ptr, dinv);

    // radix-partitioned CSR build (no global atomics, block-local writes)
    part_hist_kernel<<<B, 256, 0, stream>>>(train + E, E, B, NB, histG);
    part_scan_kernel<<<NB, 256, 0, stream>>>(histG, B, bucketTotal);
    bucket_base_kernel<<<1, 256, 0, stream>>>(bucketTotal, NB, bucketBase);
    part_scatter_kernel<<<B, 256, 0, stream>>>(train, train + E, E, B, NB, histG, bucketBase, bedges);
    csr_fill_kernel<<<NB, 256, 0, stream>>>(bedges, bucketBase, bucketTotal, row_ptr, dinv, n, colw);

    // Layer 1
    gemm1_kernel<<<(n + 31) / 32, 256, 0, stream>>>(x, W1, xw1, n);
    gather128_kernel<<<(n + 3) / 4, 256, 0, stream>>>(xw1, row_ptr, colw, dinv, b1, h1, n);
    gemmA_kernel<<<(n + 63) / 64, 256, 0, stream>>>(h1, W2, P, n);

    // Layer 2 (h2 written straight into out_embed, fp32)
    gather64b_kernel<true, 0><<<(n + 3) / 4, 256, 0, stream>>>(
        P, row_ptr, colw, dinv, b2, out_embed, n);

    // Layer 3 (h3 emitted bf16 for the score stage)
    gemmB_kernel<<<(n + 63) / 64, 256, 0, stream>>>(out_embed, W3, xw3, n);
    gather64b_kernel<false, 1><<<(n + 3) / 4, 256, 0, stream>>>(
        xw3, row_ptr, colw, dinv, b3, h3, n);

    // Scores: 8 edges per wave
    {
        int waves = (Ep + En + 7) / 8;
        score_kernel<<<(int)(((size_t)waves * 64 + 255) / 256), 256, 0, stream>>>(
            h3, pos, neg, Ep, En, out_scores);
    }
}

// Round 15
// 409.595 us; speedup vs baseline: 1.0890x; 1.0503x over previous
//
#include <hip/hip_runtime.h>
#include <hip/hip_bf16.h>

// GCN link prediction. Inputs fp32+int32; OUTPUT fp32 (scores[1M] ++ embed[n*64]).
// CSR gather + bf16 feature tables (fp32 math), register-tiled 4x4 GEMMs,
// device-wide scan, radix-partitioned CSR build, 8-edge/wave uint4 score,
// padded unroll-8 gathers + readfirstlane-scalarized edge lists (colw via s_load).

#define ECH 4096      // edges per partition chunk
#define SHIFT 8       // dsts per bucket = 256
#define MAXNB 512     // max buckets (n <= 131072)

__device__ __forceinline__ float lo16f(uint32_t u) { uint32_t x = u << 16; float f; __builtin_memcpy(&f, &x, 4); return f; }
__device__ __forceinline__ float hi16f(uint32_t u) { uint32_t x = u & 0xffff0000u; float f; __builtin_memcpy(&f, &x, 4); return f; }
__device__ __forceinline__ float u16f(unsigned short u) { uint32_t x = (uint32_t)u << 16; float f; __builtin_memcpy(&f, &x, 4); return f; }
__device__ __forceinline__ uint32_t pk2(float a, float b) {
    union { __hip_bfloat162 h; uint32_t u; } cv;
    cv.h = __hip_bfloat162(__float2bfloat16(a), __float2bfloat16(b));
    return cv.u;
}
__device__ __forceinline__ unsigned short bf16bits(float a) {
    union { __hip_bfloat16 b; unsigned short u; } cv;
    cv.b = __float2bfloat16(a);
    return cv.u;
}
__device__ __forceinline__ int pad8(int c) { return (c + 7) & ~7; }

// ---------------- degree count + (padded) row_ptr scan ----------------
__global__ void count_kernel(const int* __restrict__ dst, int E, int* __restrict__ count) {
    int e = blockIdx.x * blockDim.x + threadIdx.x;
    if (e < E) atomicAdd(&count[dst[e]], 1);
}

__global__ __launch_bounds__(256) void scan_partial_kernel(const int* __restrict__ count, int n,
                                                           int* __restrict__ partial) {
    __shared__ int red[256];
    int t = threadIdx.x;
    int base = blockIdx.x * 1024 + t * 4;
    int s = 0;
#pragma unroll
    for (int i = 0; i < 4; ++i) {
        int idx = base + i;
        if (idx < n) s += pad8(count[idx]);
    }
    red[t] = s;
    __syncthreads();
    for (int o = 128; o > 0; o >>= 1) {
        if (t < o) red[t] += red[t + o];
        __syncthreads();
    }
    if (t == 0) partial[blockIdx.x] = red[0];
}

__global__ __launch_bounds__(256) void scan_offsets_kernel(int* __restrict__ partial, int nb,
                                                           int* __restrict__ row_ptr, int n) {
    __shared__ int sc[256];
    int t = threadIdx.x;
    sc[t] = (t < nb) ? partial[t] : 0;
    __syncthreads();
    for (int o = 1; o < 256; o <<= 1) {
        int v = sc[t];
        int u = (t >= o) ? sc[t - o] : 0;
        __syncthreads();
        sc[t] = v + u;
        __syncthreads();
    }
    if (t < nb) partial[t] = (t > 0) ? sc[t - 1] : 0;  // exclusive
    if (t == 0) row_ptr[n] = sc[255];
}

__global__ __launch_bounds__(256) void scan_write_kernel(const int* __restrict__ count, int n,
                                                         const int* __restrict__ partial,
                                                         int* __restrict__ row_ptr,
                                                         float* __restrict__ dinv) {
    __shared__ int sc[256];
    int t = threadIdx.x;
    int base = blockIdx.x * 1024 + t * 4;
    int c[4];
    int s = 0;
#pragma unroll
    for (int i = 0; i < 4; ++i) {
        int idx = base + i;
        c[i] = (idx < n) ? count[idx] : 0;
        s += pad8(c[i]);
    }
    sc[t] = s;
    __syncthreads();
    for (int o = 1; o < 256; o <<= 1) {
        int v = sc[t];
        int u = (t >= o) ? sc[t - o] : 0;
        __syncthreads();
        sc[t] = v + u;
        __syncthreads();
    }
    int run = partial[blockIdx.x] + ((t > 0) ? sc[t - 1] : 0);
#pragma unroll
    for (int i = 0; i < 4; ++i) {
        int idx = base + i;
        if (idx < n) {
            row_ptr[idx] = run;
            dinv[idx] = rsqrtf((float)c[i] + 1.0f);
            run += pad8(c[i]);
        }
    }
}

// ---------------- radix partition: edges -> buckets -> CSR ----------------
__global__ __launch_bounds__(256) void part_hist_kernel(const int* __restrict__ dst, int E,
                                                        int B, int NB, int* __restrict__ histG) {
    __shared__ int h[MAXNB];
    int t = threadIdx.x, blk = blockIdx.x;
    for (int i = t; i < NB; i += 256) h[i] = 0;
    __syncthreads();
    int lo = blk * ECH, hi = min(lo + ECH, E);
    for (int i = lo + t; i < hi; i += 256) atomicAdd(&h[dst[i] >> SHIFT], 1);
    __syncthreads();
    for (int k = t; k < NB; k += 256) histG[(size_t)k * B + blk] = h[k];
}

__global__ __launch_bounds__(256) void part_scan_kernel(int* __restrict__ histG, int B,
                                                        int* __restrict__ bucketTotal) {
    __shared__ int sc[1024];   // supports B <= 1024
    int k = blockIdx.x, t = threadIdx.x;
    for (int i = t; i < 1024; i += 256) sc[i] = (i < B) ? histG[(size_t)k * B + i] : 0;
    __syncthreads();
    for (int o = 1; o < 1024; o <<= 1) {
        int v[4];
#pragma unroll
        for (int j = 0; j < 4; ++j) { int i = t + j * 256; v[j] = (i >= o) ? sc[i - o] : 0; }
        __syncthreads();
#pragma unroll
        for (int j = 0; j < 4; ++j) sc[t + j * 256] += v[j];
        __syncthreads();
    }
    for (int i = t; i < B; i += 256) histG[(size_t)k * B + i] = (i > 0) ? sc[i - 1] : 0;
    if (t == 0) bucketTotal[k] = sc[B - 1];
}

__global__ __launch_bounds__(256) void bucket_base_kernel(const int* __restrict__ bucketTotal,
                                                          int NB, int* __restrict__ bucketBase) {
    __shared__ int sc[MAXNB];
    int t = threadIdx.x;
    for (int i = t; i < MAXNB; i += 256) sc[i] = (i < NB) ? bucketTotal[i] : 0;
    __syncthreads();
    for (int o = 1; o < MAXNB; o <<= 1) {
        int v[MAXNB / 256];
#pragma unroll
        for (int j = 0; j < MAXNB / 256; ++j) { int i = t + j * 256; v[j] = (i >= o) ? sc[i - o] : 0; }
        __syncthreads();
#pragma unroll
        for (int j = 0; j < MAXNB / 256; ++j) sc[t + j * 256] += v[j];
        __syncthreads();
    }
    for (int i = t; i < NB; i += 256) bucketBase[i] = (i > 0) ? sc[i - 1] : 0;
}

__global__ __launch_bounds__(256) void part_scatter_kernel(
    const int* __restrict__ src, const int* __restrict__ dst, int E, int B, int NB,
    const int* __restrict__ histG, const int* __restrict__ bucketBase,
    int2* __restrict__ bedges) {
    __shared__ int cur[MAXNB];
    int t = threadIdx.x, blk = blockIdx.x;
    for (int k = t; k < NB; k += 256) cur[k] = bucketBase[k] + histG[(size_t)k * B + blk];
    __syncthreads();
    int lo = blk * ECH, hi = min(lo + ECH, E);
    for (int i = lo + t; i < hi; i += 256) {
        int s = src[i], d = dst[i];
        int p = atomicAdd(&cur[d >> SHIFT], 1);
        bedges[p] = make_int2(s, d);
    }
}

// Fill CSR (padded layout): real edges via LDS cursors, then pad each dst's
// tail [cur, row_ptr[d+1]) with (d, w=0) no-op entries.
__global__ __launch_bounds__(256) void csr_fill_kernel(
    const int2* __restrict__ bedges, const int* __restrict__ bucketBase,
    const int* __restrict__ bucketTotal, const int* __restrict__ row_ptr,
    const float* __restrict__ dinv, int n, int2* __restrict__ colw) {
    __shared__ int cur[1 << SHIFT];
    int k = blockIdx.x, t = threadIdx.x;
    int d0 = k << SHIFT;
    for (int i = t; i < (1 << SHIFT); i += 256) {
        int d = d0 + i;
        cur[i] = (d < n) ? row_ptr[d] : 0;
    }
    __syncthreads();
    int base = bucketBase[k], cnt = bucketTotal[k];
    for (int i = t; i < cnt; i += 256) {
        int2 e = bedges[base + i];
        float w = dinv[e.x];
        int p = atomicAdd(&cur[e.y - d0], 1);
        colw[p] = make_int2(e.x, __float_as_int(w));
    }
    __syncthreads();
    for (int i = t; i < (1 << SHIFT); i += 256) {
        int d = d0 + i;
        if (d < n) {
            int pend = row_ptr[d + 1];
            for (int p = cur[i]; p < pend; ++p) colw[p] = make_int2(d, 0);
        }
    }
}

// ---------------- GEMMs (4x4 register tile, K-chunked LDS) ----------------
#define FMA16(a, b, acc)                                                     \
    acc[0][0] = fmaf(a.x, b.x, acc[0][0]); acc[0][1] = fmaf(a.x, b.y, acc[0][1]); \
    acc[0][2] = fmaf(a.x, b.z, acc[0][2]); acc[0][3] = fmaf(a.x, b.w, acc[0][3]); \
    acc[1][0] = fmaf(a.y, b.x, acc[1][0]); acc[1][1] = fmaf(a.y, b.y, acc[1][1]); \
    acc[1][2] = fmaf(a.y, b.z, acc[1][2]); acc[1][3] = fmaf(a.y, b.w, acc[1][3]); \
    acc[2][0] = fmaf(a.z, b.x, acc[2][0]); acc[2][1] = fmaf(a.z, b.y, acc[2][1]); \
    acc[2][2] = fmaf(a.z, b.z, acc[2][2]); acc[2][3] = fmaf(a.z, b.w, acc[2][3]); \
    acc[3][0] = fmaf(a.w, b.x, acc[3][0]); acc[3][1] = fmaf(a.w, b.y, acc[3][1]); \
    acc[3][2] = fmaf(a.w, b.z, acc[3][2]); acc[3][3] = fmaf(a.w, b.w, acc[3][3]);

__global__ __launch_bounds__(256) void gemm1_kernel(const float* __restrict__ In,
                                                    const float* __restrict__ W,
                                                    __hip_bfloat16* __restrict__ Out, int n) {
    __shared__ float sInT[32][32];   // [k][row]
    __shared__ float sW[32][128];
    int t = threadIdx.x;
    int tr = t >> 5, tc = t & 31;
    int rbase = blockIdx.x * 32;
    float acc[4][4] = {};
    for (int kt = 0; kt < 128; kt += 32) {
        {
            int r = t >> 3, k4 = (t & 7) << 2;
            int gr = rbase + r;
            float4 v = make_float4(0.f, 0.f, 0.f, 0.f);
            if (gr < n) v = *(const float4*)&In[(size_t)gr * 128 + kt + k4];
            sInT[k4 + 0][r] = v.x; sInT[k4 + 1][r] = v.y;
            sInT[k4 + 2][r] = v.z; sInT[k4 + 3][r] = v.w;
        }
        {
            const float4* Wv = (const float4*)&W[(size_t)kt * 128];
            float4* sWv = (float4*)&sW[0][0];
            for (int i = t; i < 1024; i += 256) sWv[i] = Wv[i];
        }
        __syncthreads();
#pragma unroll
        for (int k = 0; k < 32; ++k) {
            float4 a = *(const float4*)&sInT[k][tr << 2];
            float4 b = *(const float4*)&sW[k][tc << 2];
            FMA16(a, b, acc)
        }
        __syncthreads();
    }
#pragma unroll
    for (int i = 0; i < 4; ++i) {
        int gr = rbase + (tr << 2) + i;
        if (gr < n) {
            uint2 pk;
            pk.x = pk2(acc[i][0], acc[i][1]);
            pk.y = pk2(acc[i][2], acc[i][3]);
            *(uint2*)((uint32_t*)Out + (size_t)gr * 64 + (tc << 1)) = pk;
        }
    }
}

__global__ __launch_bounds__(256) void gemmA_kernel(const __hip_bfloat16* __restrict__ In,
                                                    const float* __restrict__ W,
                                                    __hip_bfloat16* __restrict__ Out, int n) {
    __shared__ float sInT[32][64];
    __shared__ float sW[32][64];
    int t = threadIdx.x;
    int tr = t >> 4, tc = t & 15;
    int rbase = blockIdx.x * 64;
    float acc[4][4] = {};
    const uint32_t* Inu = (const uint32_t*)In;
    for (int kt = 0; kt < 128; kt += 32) {
        for (int i = t; i < 1024; i += 256) {
            int r = i >> 4, ku = i & 15;
            int gr = rbase + r;
            uint32_t u = (gr < n) ? Inu[(size_t)gr * 64 + (kt >> 1) + ku] : 0u;
            sInT[2 * ku][r] = lo16f(u);
            sInT[2 * ku + 1][r] = hi16f(u);
        }
        {
            const float4* Wv = (const float4*)&W[(size_t)kt * 64];
            float4* sWv = (float4*)&sW[0][0];
            for (int i = t; i < 512; i += 256) sWv[i] = Wv[i];
        }
        __syncthreads();
#pragma unroll
        for (int k = 0; k < 32; ++k) {
            float4 a = *(const float4*)&sInT[k][tr << 2];
            float4 b = *(const float4*)&sW[k][tc << 2];
            FMA16(a, b, acc)
        }
        __syncthreads();
    }
#pragma unroll
    for (int i = 0; i < 4; ++i) {
        int gr = rbase + (tr << 2) + i;
        if (gr < n) {
            uint2 pk;
            pk.x = pk2(acc[i][0], acc[i][1]);
            pk.y = pk2(acc[i][2], acc[i][3]);
            *(uint2*)((uint32_t*)Out + (size_t)gr * 32 + (tc << 1)) = pk;
        }
    }
}

__global__ __launch_bounds__(256) void gemmB_kernel(const float* __restrict__ In,
                                                    const float* __restrict__ W,
                                                    __hip_bfloat16* __restrict__ Out, int n) {
    __shared__ float sInT[32][64];
    __shared__ float sW[32][64];
    int t = threadIdx.x;
    int tr = t >> 4, tc = t & 15;
    int rbase = blockIdx.x * 64;
    float acc[4][4] = {};
    for (int kt = 0; kt < 64; kt += 32) {
        for (int i = t; i < 512; i += 256) {
            int r = i >> 3, k4 = (i & 7) << 2;
            int gr = rbase + r;
            float4 v = make_float4(0.f, 0.f, 0.f, 0.f);
            if (gr < n) v = *(const float4*)&In[(size_t)gr * 64 + kt + k4];
            sInT[k4 + 0][r] = v.x; sInT[k4 + 1][r] = v.y;
            sInT[k4 + 2][r] = v.z; sInT[k4 + 3][r] = v.w;
        }
        {
            const float4* Wv = (const float4*)&W[(size_t)kt * 64];
            float4* sWv = (float4*)&sW[0][0];
            for (int i = t; i < 512; i += 256) sWv[i] = Wv[i];
        }
        __syncthreads();
#pragma unroll
        for (int k = 0; k < 32; ++k) {
            float4 a = *(const float4*)&sInT[k][tr << 2];
            float4 b = *(const float4*)&sW[k][tc << 2];
            FMA16(a, b, acc)
        }
        __syncthreads();
    }
#pragma unroll
    for (int i = 0; i < 4; ++i) {
        int gr = rbase + (tr << 2) + i;
        if (gr < n) {
            uint2 pk;
            pk.x = pk2(acc[i][0], acc[i][1]);
            pk.y = pk2(acc[i][2], acc[i][3]);
            *(uint2*)((uint32_t*)Out + (size_t)gr * 32 + (tc << 1)) = pk;
        }
    }
}

// ---- Gathers: branch-free unroll-8, dual accumulators, SCALAR edge lists ----
// p0/p1 forced to SGPR via readfirstlane -> colw[e..e+7] become s_load,
// row addresses become saddr-form (scalar base + lane offset).
__global__ __launch_bounds__(256) void gather128_kernel(
    const __hip_bfloat16* __restrict__ xw, const int* __restrict__ row_ptr,
    const int2* __restrict__ colw, const float* __restrict__ dinv,
    const float* __restrict__ b1, __hip_bfloat16* __restrict__ h1, int n) {
    int w = threadIdx.x >> 6, l = threadIdx.x & 63;
    int d = blockIdx.x * 4 + w;
    if (d >= n) return;
    float dd = dinv[d];
    int p0 = __builtin_amdgcn_readfirstlane(row_ptr[d]);
    int p1 = __builtin_amdgcn_readfirstlane(row_ptr[d + 1]);
    const uint32_t* X = (const uint32_t*)xw;
    uint32_t v = X[(size_t)d * 64 + l];
    float a0 = dd * lo16f(v), a1 = dd * hi16f(v);
    float c0a = 0.f, c1a = 0.f;   // second accumulator pair (chain break)
    for (int e = p0; e < p1; e += 8) {
        int s0 = __builtin_amdgcn_readfirstlane(colw[e].x);
        int s1 = __builtin_amdgcn_readfirstlane(colw[e + 1].x);
        int s2 = __builtin_amdgcn_readfirstlane(colw[e + 2].x);
        int s3 = __builtin_amdgcn_readfirstlane(colw[e + 3].x);
        int s4 = __builtin_amdgcn_readfirstlane(colw[e + 4].x);
        int s5 = __builtin_amdgcn_readfirstlane(colw[e + 5].x);
        int s6 = __builtin_amdgcn_readfirstlane(colw[e + 6].x);
        int s7 = __builtin_amdgcn_readfirstlane(colw[e + 7].x);
        float w0 = __int_as_float(__builtin_amdgcn_readfirstlane(colw[e].y));
        float w1 = __int_as_float(__builtin_amdgcn_readfirstlane(colw[e + 1].y));
        float w2 = __int_as_float(__builtin_amdgcn_readfirstlane(colw[e + 2].y));
        float w3 = __int_as_float(__builtin_amdgcn_readfirstlane(colw[e + 3].y));
        float w4 = __int_as_float(__builtin_amdgcn_readfirstlane(colw[e + 4].y));
        float w5 = __int_as_float(__builtin_amdgcn_readfirstlane(colw[e + 5].y));
        float w6 = __int_as_float(__builtin_amdgcn_readfirstlane(colw[e + 6].y));
        float w7 = __int_as_float(__builtin_amdgcn_readfirstlane(colw[e + 7].y));
        uint32_t v0 = X[(size_t)s0 * 64 + l];
        uint32_t v1 = X[(size_t)s1 * 64 + l];
        uint32_t v2 = X[(size_t)s2 * 64 + l];
        uint32_t v3 = X[(size_t)s3 * 64 + l];
        uint32_t v4 = X[(size_t)s4 * 64 + l];
        uint32_t v5 = X[(size_t)s5 * 64 + l];
        uint32_t v6 = X[(size_t)s6 * 64 + l];
        uint32_t v7 = X[(size_t)s7 * 64 + l];
        a0 = fmaf(w0, lo16f(v0), a0);  a1 = fmaf(w0, hi16f(v0), a1);
        c0a = fmaf(w1, lo16f(v1), c0a); c1a = fmaf(w1, hi16f(v1), c1a);
        a0 = fmaf(w2, lo16f(v2), a0);  a1 = fmaf(w2, hi16f(v2), a1);
        c0a = fmaf(w3, lo16f(v3), c0a); c1a = fmaf(w3, hi16f(v3), c1a);
        a0 = fmaf(w4, lo16f(v4), a0);  a1 = fmaf(w4, hi16f(v4), a1);
        c0a = fmaf(w5, lo16f(v5), c0a); c1a = fmaf(w5, hi16f(v5), c1a);
        a0 = fmaf(w6, lo16f(v6), a0);  a1 = fmaf(w6, hi16f(v6), a1);
        c0a = fmaf(w7, lo16f(v7), c0a); c1a = fmaf(w7, hi16f(v7), c1a);
    }
    a0 += c0a; a1 += c1a;
    a0 = fmaxf(fmaf(dd, a0, b1[2 * l]), 0.0f);
    a1 = fmaxf(fmaf(dd, a1, b1[2 * l + 1]), 0.0f);
    ((uint32_t*)h1)[(size_t)d * 64 + l] = pk2(a0, a1);
}

// OUT=0: fp32 out; OUT=1: bf16 out.
template<bool RELU, int OUT>
__global__ __launch_bounds__(256) void gather64b_kernel(
    const __hip_bfloat16* __restrict__ xw, const int* __restrict__ row_ptr,
    const int2* __restrict__ colw, const float* __restrict__ dinv,
    const float* __restrict__ b, void* __restrict__ out, int n) {
    int w = threadIdx.x >> 6, l = threadIdx.x & 63;
    int d = blockIdx.x * 4 + w;
    if (d >= n) return;
    float dd = dinv[d];
    int p0 = __builtin_amdgcn_readfirstlane(row_ptr[d]);
    int p1 = __builtin_amdgcn_readfirstlane(row_ptr[d + 1]);
    const unsigned short* X = (const unsigned short*)xw;
    float a = dd * u16f(X[(size_t)d * 64 + l]);
    float c = 0.f;   // second accumulator (chain break)
    for (int e = p0; e < p1; e += 8) {
        int s0 = __builtin_amdgcn_readfirstlane(colw[e].x);
        int s1 = __builtin_amdgcn_readfirstlane(colw[e + 1].x);
        int s2 = __builtin_amdgcn_readfirstlane(colw[e + 2].x);
        int s3 = __builtin_amdgcn_readfirstlane(colw[e + 3].x);
        int s4 = __builtin_amdgcn_readfirstlane(colw[e + 4].x);
        int s5 = __builtin_amdgcn_readfirstlane(colw[e + 5].x);
        int s6 = __builtin_amdgcn_readfirstlane(colw[e + 6].x);
        int s7 = __builtin_amdgcn_readfirstlane(colw[e + 7].x);
        float w0 = __int_as_float(__builtin_amdgcn_readfirstlane(colw[e].y));
        float w1 = __int_as_float(__builtin_amdgcn_readfirstlane(colw[e + 1].y));
        float w2 = __int_as_float(__builtin_amdgcn_readfirstlane(colw[e + 2].y));
        float w3 = __int_as_float(__builtin_amdgcn_readfirstlane(colw[e + 3].y));
        float w4 = __int_as_float(__builtin_amdgcn_readfirstlane(colw[e + 4].y));
        float w5 = __int_as_float(__builtin_amdgcn_readfirstlane(colw[e + 5].y));
        float w6 = __int_as_float(__builtin_amdgcn_readfirstlane(colw[e + 6].y));
        float w7 = __int_as_float(__builtin_amdgcn_readfirstlane(colw[e + 7].y));
        unsigned short v0 = X[(size_t)s0 * 64 + l];
        unsigned short v1 = X[(size_t)s1 * 64 + l];
        unsigned short v2 = X[(size_t)s2 * 64 + l];
        unsigned short v3 = X[(size_t)s3 * 64 + l];
        unsigned short v4 = X[(size_t)s4 * 64 + l];
        unsigned short v5 = X[(size_t)s5 * 64 + l];
        unsigned short v6 = X[(size_t)s6 * 64 + l];
        unsigned short v7 = X[(size_t)s7 * 64 + l];
        a = fmaf(w0, u16f(v0), a);
        c = fmaf(w1, u16f(v1), c);
        a = fmaf(w2, u16f(v2), a);
        c = fmaf(w3, u16f(v3), c);
        a = fmaf(w4, u16f(v4), a);
        c = fmaf(w5, u16f(v5), c);
        a = fmaf(w6, u16f(v6), a);
        c = fmaf(w7, u16f(v7), c);
    }
    a += c;
    float r = fmaf(dd, a, b[l]);
    if (RELU) r = fmaxf(r, 0.0f);
    if (OUT == 0) ((float*)out)[(size_t)d * 64 + l] = r;
    else ((unsigned short*)out)[(size_t)d * 64 + l] = bf16bits(r);
}

// ---------------- Score: 8 edges per wave, 8-lane groups, uint4 row loads ----------
__global__ void score_kernel(const __hip_bfloat16* __restrict__ h, const int* __restrict__ pos,
                             const int* __restrict__ neg, int Ep, int En,
                             float* __restrict__ out) {
    int wid = (int)(((size_t)blockIdx.x * blockDim.x + threadIdx.x) >> 6);
    int lane = threadIdx.x & 63;
    int g = lane >> 3, sl = lane & 7;
    int ed = wid * 8 + g;
    int tot = Ep + En;
    if (ed >= tot) return;
    int j, i;
    if (ed < Ep) { j = pos[ed]; i = pos[Ep + ed]; }
    else { int e = ed - Ep; j = neg[e]; i = neg[En + e]; }
    const uint4* X = (const uint4*)h;  // 8 uint4 per 64-feat bf16 row
    uint4 vi = X[(size_t)i * 8 + sl];
    uint4 vj = X[(size_t)j * 8 + sl];
    float v;
    v = lo16f(vi.x) * lo16f(vj.x);
    v = fmaf(hi16f(vi.x), hi16f(vj.x), v);
    v = fmaf(lo16f(vi.y), lo16f(vj.y), v);
    v = fmaf(hi16f(vi.y), hi16f(vj.y), v);
    v = fmaf(lo16f(vi.z), lo16f(vj.z), v);
    v = fmaf(hi16f(vi.z), hi16f(vj.z), v);
    v = fmaf(lo16f(vi.w), lo16f(vj.w), v);
    v = fmaf(hi16f(vi.w), hi16f(vj.w), v);
#pragma unroll
    for (int o = 4; o > 0; o >>= 1) v += __shfl_xor(v, o);
    if (sl == 0) out[ed] = v;
}

extern "C" void kernel_launch(void* const* d_in, const int* in_sizes, int n_in,
                              void* d_out, int out_size, void* d_ws, size_t ws_size,
                              hipStream_t stream) {
    const float* x   = (const float*)d_in[0];
    const int* train = (const int*)d_in[1];
    const int* pos   = (const int*)d_in[2];
    const int* neg   = (const int*)d_in[3];
    const float* W1  = (const float*)d_in[4];
    const float* b1  = (const float*)d_in[5];
    const float* W2  = (const float*)d_in[6];
    const float* b2  = (const float*)d_in[7];
    const float* W3  = (const float*)d_in[8];
    const float* b3  = (const float*)d_in[9];

    const int n  = in_sizes[0] / 128;
    const int E  = in_sizes[1] / 2;
    const int Ep = in_sizes[2] / 2;
    const int En = in_sizes[3] / 2;

    const int B  = (E + ECH - 1) / ECH;         // partition chunks (391 for E=1.6M)
    const int NB = ((n - 1) >> SHIFT) + 1;      // buckets (391 for n=100K)

    // Workspace (~85 MB; padded colw needs E + 8n entries)
    char* wp = (char*)d_ws;
    auto alloc = [&](size_t bytes) { char* r = wp; wp += (bytes + 255) & ~(size_t)255; return r; };
    int*   count    = (int*)alloc((size_t)n * 4);
    int*   row_ptr  = (int*)alloc(((size_t)n + 1) * 4);
    int*   partial  = (int*)alloc(256 * 4);
    int*   bucketTotal = (int*)alloc(MAXNB * 4);
    int*   bucketBase  = (int*)alloc(MAXNB * 4);
    int2*  colw     = (int2*)alloc(((size_t)E + 8 * (size_t)n) * 8);
    float* dinv     = (float*)alloc((size_t)n * 4);
    __hip_bfloat16* xw1 = (__hip_bfloat16*)alloc((size_t)n * 128 * 2);  // reused as h3(bf16 n*64)
    __hip_bfloat16* h1  = (__hip_bfloat16*)alloc((size_t)n * 128 * 2);
    __hip_bfloat16* P   = (__hip_bfloat16*)alloc((size_t)n * 64 * 2);   // xw2, later xw3
    __hip_bfloat16* h3  = xw1;
    __hip_bfloat16* xw3 = P;
    int2* bedges = (int2*)h1;       // alias: consumed before h1 is written
    int*  histG  = (int*)P;         // alias: NB*B*4 ~ 612KB, consumed before P is written

    float* out_scores = (float*)d_out;
    float* out_embed  = out_scores + (Ep + En);  // h2 lives here directly

    const int eb256 = (E + 255) / 256;
    const int nbs = (n + 1023) / 1024;

    // degrees -> padded row_ptr, dinv
    hipMemsetAsync(count, 0, (size_t)n * sizeof(int), stream);
    count_kernel<<<eb256, 256, 0, stream>>>(train + E, E, count);
    scan_partial_kernel<<<nbs, 256, 0, stream>>>(count, n, partial);
    scan_offsets_kernel<<<1, 256, 0, stream>>>(partial, nbs, row_ptr, n);
    scan_write_kernel<<<nbs, 256, 0, stream>>>(count, n, partial, row_ptr, dinv);

    // radix-partitioned CSR build (no global atomics, block-local writes)
    part_hist_kernel<<<B, 256, 0, stream>>>(train + E, E, B, NB, histG);
    part_scan_kernel<<<NB, 256, 0, stream>>>(histG, B, bucketTotal);
    bucket_base_kernel<<<1, 256, 0, stream>>>(bucketTotal, NB, bucketBase);
    part_scatter_kernel<<<B, 256, 0, stream>>>(train, train + E, E, B, NB, histG, bucketBase, bedges);
    csr_fill_kernel<<<NB, 256, 0, stream>>>(bedges, bucketBase, bucketTotal, row_ptr, dinv, n, colw);

    // Layer 1
    gemm1_kernel<<<(n + 31) / 32, 256, 0, stream>>>(x, W1, xw1, n);
    gather128_kernel<<<(n + 3) / 4, 256, 0, stream>>>(xw1, row_ptr, colw, dinv, b1, h1, n);
    gemmA_kernel<<<(n + 63) / 64, 256, 0, stream>>>(h1, W2, P, n);

    // Layer 2 (h2 written straight into out_embed, fp32)
    gather64b_kernel<true, 0><<<(n + 3) / 4, 256, 0, stream>>>(
        P, row_ptr, colw, dinv, b2, out_embed, n);

    // Layer 3 (h3 emitted bf16 for the score stage)
    gemmB_kernel<<<(n + 63) / 64, 256, 0, stream>>>(out_embed, W3, xw3, n);
    gather64b_kernel<false, 1><<<(n + 3) / 4, 256, 0, stream>>>(
        xw3, row_ptr, colw, dinv, b3, h3, n);

    // Scores: 8 edges per wave
    {
        int waves = (Ep + En + 7) / 8;
        score_kernel<<<(int)(((size_t)waves * 64 + 255) / 256), 256, 0, stream>>>(
            h3, pos, neg, Ep, En, out_scores);
    }
}

// Round 16
// 343.241 us; speedup vs baseline: 1.2996x; 1.1933x over previous
//
#include <hip/hip_runtime.h>
#include <hip/hip_bf16.h>

// GCN link prediction. Inputs fp32+int32; OUTPUT fp32 (scores[1M] ++ embed[n*64]).
// CSR gather + bf16 feature tables (fp32 math), register-tiled 4x4 GEMMs
// (LDS pad 33/65: was 8-16-way bank conflict), radix-partitioned CSR build,
// bucket-LDS degree count (was 1.6M global atomics = 50MB scatter writes),
// padded unroll-8 scalarized gathers, 8-edge/wave uint4 score.

#define ECH 4096      // edges per partition chunk
#define SHIFT 8       // dsts per bucket = 256
#define MAXNB 512     // max buckets (n <= 131072)

__device__ __forceinline__ float lo16f(uint32_t u) { uint32_t x = u << 16; float f; __builtin_memcpy(&f, &x, 4); return f; }
__device__ __forceinline__ float hi16f(uint32_t u) { uint32_t x = u & 0xffff0000u; float f; __builtin_memcpy(&f, &x, 4); return f; }
__device__ __forceinline__ float u16f(unsigned short u) { uint32_t x = (uint32_t)u << 16; float f; __builtin_memcpy(&f, &x, 4); return f; }
__device__ __forceinline__ uint32_t pk2(float a, float b) {
    union { __hip_bfloat162 h; uint32_t u; } cv;
    cv.h = __hip_bfloat162(__float2bfloat16(a), __float2bfloat16(b));
    return cv.u;
}
__device__ __forceinline__ unsigned short bf16bits(float a) {
    union { __hip_bfloat16 b; unsigned short u; } cv;
    cv.b = __float2bfloat16(a);
    return cv.u;
}
__device__ __forceinline__ int pad8(int c) { return (c + 7) & ~7; }

// ---------------- radix partition: edges -> buckets ----------------
__global__ __launch_bounds__(256) void part_hist_kernel(const int* __restrict__ dst, int E,
                                                        int B, int NB, int* __restrict__ histG) {
    __shared__ int h[MAXNB];
    int t = threadIdx.x, blk = blockIdx.x;
    for (int i = t; i < NB; i += 256) h[i] = 0;
    __syncthreads();
    int lo = blk * ECH, hi = min(lo + ECH, E);
    for (int i = lo + t; i < hi; i += 256) atomicAdd(&h[dst[i] >> SHIFT], 1);
    __syncthreads();
    for (int k = t; k < NB; k += 256) histG[(size_t)k * B + blk] = h[k];
}

__global__ __launch_bounds__(256) void part_scan_kernel(int* __restrict__ histG, int B,
                                                        int* __restrict__ bucketTotal) {
    __shared__ int sc[1024];   // supports B <= 1024
    int k = blockIdx.x, t = threadIdx.x;
    for (int i = t; i < 1024; i += 256) sc[i] = (i < B) ? histG[(size_t)k * B + i] : 0;
    __syncthreads();
    for (int o = 1; o < 1024; o <<= 1) {
        int v[4];
#pragma unroll
        for (int j = 0; j < 4; ++j) { int i = t + j * 256; v[j] = (i >= o) ? sc[i - o] : 0; }
        __syncthreads();
#pragma unroll
        for (int j = 0; j < 4; ++j) sc[t + j * 256] += v[j];
        __syncthreads();
    }
    for (int i = t; i < B; i += 256) histG[(size_t)k * B + i] = (i > 0) ? sc[i - 1] : 0;
    if (t == 0) bucketTotal[k] = sc[B - 1];
}

__global__ __launch_bounds__(256) void bucket_base_kernel(const int* __restrict__ bucketTotal,
                                                          int NB, int* __restrict__ bucketBase) {
    __shared__ int sc[MAXNB];
    int t = threadIdx.x;
    for (int i = t; i < MAXNB; i += 256) sc[i] = (i < NB) ? bucketTotal[i] : 0;
    __syncthreads();
    for (int o = 1; o < MAXNB; o <<= 1) {
        int v[MAXNB / 256];
#pragma unroll
        for (int j = 0; j < MAXNB / 256; ++j) { int i = t + j * 256; v[j] = (i >= o) ? sc[i - o] : 0; }
        __syncthreads();
#pragma unroll
        for (int j = 0; j < MAXNB / 256; ++j) sc[t + j * 256] += v[j];
        __syncthreads();
    }
    for (int i = t; i < NB; i += 256) bucketBase[i] = (i > 0) ? sc[i - 1] : 0;
}

__global__ __launch_bounds__(256) void part_scatter_kernel(
    const int* __restrict__ src, const int* __restrict__ dst, int E, int B, int NB,
    const int* __restrict__ histG, const int* __restrict__ bucketBase,
    int2* __restrict__ bedges) {
    __shared__ int cur[MAXNB];
    int t = threadIdx.x, blk = blockIdx.x;
    for (int k = t; k < NB; k += 256) cur[k] = bucketBase[k] + histG[(size_t)k * B + blk];
    __syncthreads();
    int lo = blk * ECH, hi = min(lo + ECH, E);
    for (int i = lo + t; i < hi; i += 256) {
        int s = src[i], d = dst[i];
        int p = atomicAdd(&cur[d >> SHIFT], 1);
        bedges[p] = make_int2(s, d);
    }
}

// Per-bucket degree count from partitioned edges (replaces global-atomic count).
__global__ __launch_bounds__(256) void count_bucket_kernel(
    const int2* __restrict__ bedges, const int* __restrict__ bucketBase,
    const int* __restrict__ bucketTotal, int n, int* __restrict__ count) {
    __shared__ int hist[1 << SHIFT];
    int k = blockIdx.x, t = threadIdx.x;
    hist[t] = 0;
    __syncthreads();
    int base = bucketBase[k], cnt = bucketTotal[k];
    int d0 = k << SHIFT;
    for (int i = t; i < cnt; i += 256) atomicAdd(&hist[bedges[base + i].y - d0], 1);
    __syncthreads();
    int d = d0 + t;
    if (d < n) count[d] = hist[t];
}

// ---------------- (padded) row_ptr scan + dinv ----------------
__global__ __launch_bounds__(256) void scan_partial_kernel(const int* __restrict__ count, int n,
                                                           int* __restrict__ partial) {
    __shared__ int red[256];
    int t = threadIdx.x;
    int base = blockIdx.x * 1024 + t * 4;
    int s = 0;
#pragma unroll
    for (int i = 0; i < 4; ++i) {
        int idx = base + i;
        if (idx < n) s += pad8(count[idx]);
    }
    red[t] = s;
    __syncthreads();
    for (int o = 128; o > 0; o >>= 1) {
        if (t < o) red[t] += red[t + o];
        __syncthreads();
    }
    if (t == 0) partial[blockIdx.x] = red[0];
}

__global__ __launch_bounds__(256) void scan_offsets_kernel(int* __restrict__ partial, int nb,
                                                           int* __restrict__ row_ptr, int n) {
    __shared__ int sc[256];
    int t = threadIdx.x;
    sc[t] = (t < nb) ? partial[t] : 0;
    __syncthreads();
    for (int o = 1; o < 256; o <<= 1) {
        int v = sc[t];
        int u = (t >= o) ? sc[t - o] : 0;
        __syncthreads();
        sc[t] = v + u;
        __syncthreads();
    }
    if (t < nb) partial[t] = (t > 0) ? sc[t - 1] : 0;  // exclusive
    if (t == 0) row_ptr[n] = sc[255];
}

__global__ __launch_bounds__(256) void scan_write_kernel(const int* __restrict__ count, int n,
                                                         const int* __restrict__ partial,
                                                         int* __restrict__ row_ptr,
                                                         float* __restrict__ dinv) {
    __shared__ int sc[256];
    int t = threadIdx.x;
    int base = blockIdx.x * 1024 + t * 4;
    int c[4];
    int s = 0;
#pragma unroll
    for (int i = 0; i < 4; ++i) {
        int idx = base + i;
        c[i] = (idx < n) ? count[idx] : 0;
        s += pad8(c[i]);
    }
    sc[t] = s;
    __syncthreads();
    for (int o = 1; o < 256; o <<= 1) {
        int v = sc[t];
        int u = (t >= o) ? sc[t - o] : 0;
        __syncthreads();
        sc[t] = v + u;
        __syncthreads();
    }
    int run = partial[blockIdx.x] + ((t > 0) ? sc[t - 1] : 0);
#pragma unroll
    for (int i = 0; i < 4; ++i) {
        int idx = base + i;
        if (idx < n) {
            row_ptr[idx] = run;
            dinv[idx] = rsqrtf((float)c[i] + 1.0f);
            run += pad8(c[i]);
        }
    }
}

// Fill CSR (padded layout): real edges via LDS cursors, then pad each dst's
// tail [cur, row_ptr[d+1]) with (d, w=0) no-op entries.
__global__ __launch_bounds__(256) void csr_fill_kernel(
    const int2* __restrict__ bedges, const int* __restrict__ bucketBase,
    const int* __restrict__ bucketTotal, const int* __restrict__ row_ptr,
    const float* __restrict__ dinv, int n, int2* __restrict__ colw) {
    __shared__ int cur[1 << SHIFT];
    int k = blockIdx.x, t = threadIdx.x;
    int d0 = k << SHIFT;
    for (int i = t; i < (1 << SHIFT); i += 256) {
        int d = d0 + i;
        cur[i] = (d < n) ? row_ptr[d] : 0;
    }
    __syncthreads();
    int base = bucketBase[k], cnt = bucketTotal[k];
    for (int i = t; i < cnt; i += 256) {
        int2 e = bedges[base + i];
        float w = dinv[e.x];
        int p = atomicAdd(&cur[e.y - d0], 1);
        colw[p] = make_int2(e.x, __float_as_int(w));
    }
    __syncthreads();
    for (int i = t; i < (1 << SHIFT); i += 256) {
        int d = d0 + i;
        if (d < n) {
            int pend = row_ptr[d + 1];
            for (int p = cur[i]; p < pend; ++p) colw[p] = make_int2(d, 0);
        }
    }
}

// ---------------- GEMMs (4x4 register tile, K-chunked LDS, pad 33/65) ----------------
#define FMA16(a, b, acc)                                                     \
    acc[0][0] = fmaf(a.x, b.x, acc[0][0]); acc[0][1] = fmaf(a.x, b.y, acc[0][1]); \
    acc[0][2] = fmaf(a.x, b.z, acc[0][2]); acc[0][3] = fmaf(a.x, b.w, acc[0][3]); \
    acc[1][0] = fmaf(a.y, b.x, acc[1][0]); acc[1][1] = fmaf(a.y, b.y, acc[1][1]); \
    acc[1][2] = fmaf(a.y, b.z, acc[1][2]); acc[1][3] = fmaf(a.y, b.w, acc[1][3]); \
    acc[2][0] = fmaf(a.z, b.x, acc[2][0]); acc[2][1] = fmaf(a.z, b.y, acc[2][1]); \
    acc[2][2] = fmaf(a.z, b.z, acc[2][2]); acc[2][3] = fmaf(a.z, b.w, acc[2][3]); \
    acc[3][0] = fmaf(a.w, b.x, acc[3][0]); acc[3][1] = fmaf(a.w, b.y, acc[3][1]); \
    acc[3][2] = fmaf(a.w, b.z, acc[3][2]); acc[3][3] = fmaf(a.w, b.w, acc[3][3]);

__global__ __launch_bounds__(256) void gemm1_kernel(const float* __restrict__ In,
                                                    const float* __restrict__ W,
                                                    __hip_bfloat16* __restrict__ Out, int n) {
    __shared__ float sInT[32][33];   // [k][row], pad -> conflict-free
    __shared__ float sW[32][128];
    int t = threadIdx.x;
    int tr = t >> 5, tc = t & 31;
    int rbase = blockIdx.x * 32;
    float acc[4][4] = {};
    for (int kt = 0; kt < 128; kt += 32) {
        {
            int r = t >> 3, k4 = (t & 7) << 2;
            int gr = rbase + r;
            float4 v = make_float4(0.f, 0.f, 0.f, 0.f);
            if (gr < n) v = *(const float4*)&In[(size_t)gr * 128 + kt + k4];
            sInT[k4 + 0][r] = v.x; sInT[k4 + 1][r] = v.y;
            sInT[k4 + 2][r] = v.z; sInT[k4 + 3][r] = v.w;
        }
        {
            const float4* Wv = (const float4*)&W[(size_t)kt * 128];
            float4* sWv = (float4*)&sW[0][0];
            for (int i = t; i < 1024; i += 256) sWv[i] = Wv[i];
        }
        __syncthreads();
#pragma unroll
        for (int k = 0; k < 32; ++k) {
            float4 a;
            a.x = sInT[k][(tr << 2) + 0]; a.y = sInT[k][(tr << 2) + 1];
            a.z = sInT[k][(tr << 2) + 2]; a.w = sInT[k][(tr << 2) + 3];
            float4 b = *(const float4*)&sW[k][tc << 2];
            FMA16(a, b, acc)
        }
        __syncthreads();
    }
#pragma unroll
    for (int i = 0; i < 4; ++i) {
        int gr = rbase + (tr << 2) + i;
        if (gr < n) {
            uint2 pk;
            pk.x = pk2(acc[i][0], acc[i][1]);
            pk.y = pk2(acc[i][2], acc[i][3]);
            *(uint2*)((uint32_t*)Out + (size_t)gr * 64 + (tc << 1)) = pk;
        }
    }
}

__global__ __launch_bounds__(256) void gemmA_kernel(const __hip_bfloat16* __restrict__ In,
                                                    const float* __restrict__ W,
                                                    __hip_bfloat16* __restrict__ Out, int n) {
    __shared__ float sInT[32][65];   // pad
    __shared__ float sW[32][64];
    int t = threadIdx.x;
    int tr = t >> 4, tc = t & 15;
    int rbase = blockIdx.x * 64;
    float acc[4][4] = {};
    const uint32_t* Inu = (const uint32_t*)In;
    for (int kt = 0; kt < 128; kt += 32) {
        for (int i = t; i < 1024; i += 256) {
            int r = i >> 4, ku = i & 15;
            int gr = rbase + r;
            uint32_t u = (gr < n) ? Inu[(size_t)gr * 64 + (kt >> 1) + ku] : 0u;
            sInT[2 * ku][r] = lo16f(u);
            sInT[2 * ku + 1][r] = hi16f(u);
        }
        {
            const float4* Wv = (const float4*)&W[(size_t)kt * 64];
            float4* sWv = (float4*)&sW[0][0];
            for (int i = t; i < 512; i += 256) sWv[i] = Wv[i];
        }
        __syncthreads();
#pragma unroll
        for (int k = 0; k < 32; ++k) {
            float4 a;
            a.x = sInT[k][(tr << 2) + 0]; a.y = sInT[k][(tr << 2) + 1];
            a.z = sInT[k][(tr << 2) + 2]; a.w = sInT[k][(tr << 2) + 3];
            float4 b = *(const float4*)&sW[k][tc << 2];
            FMA16(a, b, acc)
        }
        __syncthreads();
    }
#pragma unroll
    for (int i = 0; i < 4; ++i) {
        int gr = rbase + (tr << 2) + i;
        if (gr < n) {
            uint2 pk;
            pk.x = pk2(acc[i][0], acc[i][1]);
            pk.y = pk2(acc[i][2], acc[i][3]);
            *(uint2*)((uint32_t*)Out + (size_t)gr * 32 + (tc << 1)) = pk;
        }
    }
}

__global__ __launch_bounds__(256) void gemmB_kernel(const float* __restrict__ In,
                                                    const float* __restrict__ W,
                                                    __hip_bfloat16* __restrict__ Out, int n) {
    __shared__ float sInT[32][65];   // pad
    __shared__ float sW[32][64];
    int t = threadIdx.x;
    int tr = t >> 4, tc = t & 15;
    int rbase = blockIdx.x * 64;
    float acc[4][4] = {};
    for (int kt = 0; kt < 64; kt += 32) {
        for (int i = t; i < 512; i += 256) {
            int r = i >> 3, k4 = (i & 7) << 2;
            int gr = rbase + r;
            float4 v = make_float4(0.f, 0.f, 0.f, 0.f);
            if (gr < n) v = *(const float4*)&In[(size_t)gr * 64 + kt + k4];
            sInT[k4 + 0][r] = v.x; sInT[k4 + 1][r] = v.y;
            sInT[k4 + 2][r] = v.z; sInT[k4 + 3][r] = v.w;
        }
        {
            const float4* Wv = (const float4*)&W[(size_t)kt * 64];
            float4* sWv = (float4*)&sW[0][0];
            for (int i = t; i < 512; i += 256) sWv[i] = Wv[i];
        }
        __syncthreads();
#pragma unroll
        for (int k = 0; k < 32; ++k) {
            float4 a;
            a.x = sInT[k][(tr << 2) + 0]; a.y = sInT[k][(tr << 2) + 1];
            a.z = sInT[k][(tr << 2) + 2]; a.w = sInT[k][(tr << 2) + 3];
            float4 b = *(const float4*)&sW[k][tc << 2];
            FMA16(a, b, acc)
        }
        __syncthreads();
    }
#pragma unroll
    for (int i = 0; i < 4; ++i) {
        int gr = rbase + (tr << 2) + i;
        if (gr < n) {
            uint2 pk;
            pk.x = pk2(acc[i][0], acc[i][1]);
            pk.y = pk2(acc[i][2], acc[i][3]);
            *(uint2*)((uint32_t*)Out + (size_t)gr * 32 + (tc << 1)) = pk;
        }
    }
}

// ---- Gathers: branch-free unroll-8, dual accumulators, SCALAR edge lists ----
__global__ __launch_bounds__(256) void gather128_kernel(
    const __hip_bfloat16* __restrict__ xw, const int* __restrict__ row_ptr,
    const int2* __restrict__ colw, const float* __restrict__ dinv,
    const float* __restrict__ b1, __hip_bfloat16* __restrict__ h1, int n) {
    int w = threadIdx.x >> 6, l = threadIdx.x & 63;
    int d = blockIdx.x * 4 + w;
    if (d >= n) return;
    float dd = dinv[d];
    int p0 = __builtin_amdgcn_readfirstlane(row_ptr[d]);
    int p1 = __builtin_amdgcn_readfirstlane(row_ptr[d + 1]);
    const uint32_t* X = (const uint32_t*)xw;
    uint32_t v = X[(size_t)d * 64 + l];
    float a0 = dd * lo16f(v), a1 = dd * hi16f(v);
    float c0a = 0.f, c1a = 0.f;
    for (int e = p0; e < p1; e += 8) {
        int s0 = __builtin_amdgcn_readfirstlane(colw[e].x);
        int s1 = __builtin_amdgcn_readfirstlane(colw[e + 1].x);
        int s2 = __builtin_amdgcn_readfirstlane(colw[e + 2].x);
        int s3 = __builtin_amdgcn_readfirstlane(colw[e + 3].x);
        int s4 = __builtin_amdgcn_readfirstlane(colw[e + 4].x);
        int s5 = __builtin_amdgcn_readfirstlane(colw[e + 5].x);
        int s6 = __builtin_amdgcn_readfirstlane(colw[e + 6].x);
        int s7 = __builtin_amdgcn_readfirstlane(colw[e + 7].x);
        float w0 = __int_as_float(__builtin_amdgcn_readfirstlane(colw[e].y));
        float w1 = __int_as_float(__builtin_amdgcn_readfirstlane(colw[e + 1].y));
        float w2 = __int_as_float(__builtin_amdgcn_readfirstlane(colw[e + 2].y));
        float w3 = __int_as_float(__builtin_amdgcn_readfirstlane(colw[e + 3].y));
        float w4 = __int_as_float(__builtin_amdgcn_readfirstlane(colw[e + 4].y));
        float w5 = __int_as_float(__builtin_amdgcn_readfirstlane(colw[e + 5].y));
        float w6 = __int_as_float(__builtin_amdgcn_readfirstlane(colw[e + 6].y));
        float w7 = __int_as_float(__builtin_amdgcn_readfirstlane(colw[e + 7].y));
        uint32_t v0 = X[(size_t)s0 * 64 + l];
        uint32_t v1 = X[(size_t)s1 * 64 + l];
        uint32_t v2 = X[(size_t)s2 * 64 + l];
        uint32_t v3 = X[(size_t)s3 * 64 + l];
        uint32_t v4 = X[(size_t)s4 * 64 + l];
        uint32_t v5 = X[(size_t)s5 * 64 + l];
        uint32_t v6 = X[(size_t)s6 * 64 + l];
        uint32_t v7 = X[(size_t)s7 * 64 + l];
        a0 = fmaf(w0, lo16f(v0), a0);  a1 = fmaf(w0, hi16f(v0), a1);
        c0a = fmaf(w1, lo16f(v1), c0a); c1a = fmaf(w1, hi16f(v1), c1a);
        a0 = fmaf(w2, lo16f(v2), a0);  a1 = fmaf(w2, hi16f(v2), a1);
        c0a = fmaf(w3, lo16f(v3), c0a); c1a = fmaf(w3, hi16f(v3), c1a);
        a0 = fmaf(w4, lo16f(v4), a0);  a1 = fmaf(w4, hi16f(v4), a1);
        c0a = fmaf(w5, lo16f(v5), c0a); c1a = fmaf(w5, hi16f(v5), c1a);
        a0 = fmaf(w6, lo16f(v6), a0);  a1 = fmaf(w6, hi16f(v6), a1);
        c0a = fmaf(w7, lo16f(v7), c0a); c1a = fmaf(w7, hi16f(v7), c1a);
    }
    a0 += c0a; a1 += c1a;
    a0 = fmaxf(fmaf(dd, a0, b1[2 * l]), 0.0f);
    a1 = fmaxf(fmaf(dd, a1, b1[2 * l + 1]), 0.0f);
    ((uint32_t*)h1)[(size_t)d * 64 + l] = pk2(a0, a1);
}

// OUT=0: fp32 out; OUT=1: bf16 out.
template<bool RELU, int OUT>
__global__ __launch_bounds__(256) void gather64b_kernel(
    const __hip_bfloat16* __restrict__ xw, const int* __restrict__ row_ptr,
    const int2* __restrict__ colw, const float* __restrict__ dinv,
    const float* __restrict__ b, void* __restrict__ out, int n) {
    int w = threadIdx.x >> 6, l = threadIdx.x & 63;
    int d = blockIdx.x * 4 + w;
    if (d >= n) return;
    float dd = dinv[d];
    int p0 = __builtin_amdgcn_readfirstlane(row_ptr[d]);
    int p1 = __builtin_amdgcn_readfirstlane(row_ptr[d + 1]);
    const unsigned short* X = (const unsigned short*)xw;
    float a = dd * u16f(X[(size_t)d * 64 + l]);
    float c = 0.f;
    for (int e = p0; e < p1; e += 8) {
        int s0 = __builtin_amdgcn_readfirstlane(colw[e].x);
        int s1 = __builtin_amdgcn_readfirstlane(colw[e + 1].x);
        int s2 = __builtin_amdgcn_readfirstlane(colw[e + 2].x);
        int s3 = __builtin_amdgcn_readfirstlane(colw[e + 3].x);
        int s4 = __builtin_amdgcn_readfirstlane(colw[e + 4].x);
        int s5 = __builtin_amdgcn_readfirstlane(colw[e + 5].x);
        int s6 = __builtin_amdgcn_readfirstlane(colw[e + 6].x);
        int s7 = __builtin_amdgcn_readfirstlane(colw[e + 7].x);
        float w0 = __int_as_float(__builtin_amdgcn_readfirstlane(colw[e].y));
        float w1 = __int_as_float(__builtin_amdgcn_readfirstlane(colw[e + 1].y));
        float w2 = __int_as_float(__builtin_amdgcn_readfirstlane(colw[e + 2].y));
        float w3 = __int_as_float(__builtin_amdgcn_readfirstlane(colw[e + 3].y));
        float w4 = __int_as_float(__builtin_amdgcn_readfirstlane(colw[e + 4].y));
        float w5 = __int_as_float(__builtin_amdgcn_readfirstlane(colw[e + 5].y));
        float w6 = __int_as_float(__builtin_amdgcn_readfirstlane(colw[e + 6].y));
        float w7 = __int_as_float(__builtin_amdgcn_readfirstlane(colw[e + 7].y));
        unsigned short v0 = X[(size_t)s0 * 64 + l];
        unsigned short v1 = X[(size_t)s1 * 64 + l];
        unsigned short v2 = X[(size_t)s2 * 64 + l];
        unsigned short v3 = X[(size_t)s3 * 64 + l];
        unsigned short v4 = X[(size_t)s4 * 64 + l];
        unsigned short v5 = X[(size_t)s5 * 64 + l];
        unsigned short v6 = X[(size_t)s6 * 64 + l];
        unsigned short v7 = X[(size_t)s7 * 64 + l];
        a = fmaf(w0, u16f(v0), a);
        c = fmaf(w1, u16f(v1), c);
        a = fmaf(w2, u16f(v2), a);
        c = fmaf(w3, u16f(v3), c);
        a = fmaf(w4, u16f(v4), a);
        c = fmaf(w5, u16f(v5), c);
        a = fmaf(w6, u16f(v6), a);
        c = fmaf(w7, u16f(v7), c);
    }
    a += c;
    float r = fmaf(dd, a, b[l]);
    if (RELU) r = fmaxf(r, 0.0f);
    if (OUT == 0) ((float*)out)[(size_t)d * 64 + l] = r;
    else ((unsigned short*)out)[(size_t)d * 64 + l] = bf16bits(r);
}

// ---------------- Score: 8 edges per wave, 8-lane groups, uint4 row loads ----------
__global__ void score_kernel(const __hip_bfloat16* __restrict__ h, const int* __restrict__ pos,
                             const int* __restrict__ neg, int Ep, int En,
                             float* __restrict__ out) {
    int wid = (int)(((size_t)blockIdx.x * blockDim.x + threadIdx.x) >> 6);
    int lane = threadIdx.x & 63;
    int g = lane >> 3, sl = lane & 7;
    int ed = wid * 8 + g;
    int tot = Ep + En;
    if (ed >= tot) return;
    int j, i;
    if (ed < Ep) { j = pos[ed]; i = pos[Ep + ed]; }
    else { int e = ed - Ep; j = neg[e]; i = neg[En + e]; }
    const uint4* X = (const uint4*)h;  // 8 uint4 per 64-feat bf16 row
    uint4 vi = X[(size_t)i * 8 + sl];
    uint4 vj = X[(size_t)j * 8 + sl];
    float v;
    v = lo16f(vi.x) * lo16f(vj.x);
    v = fmaf(hi16f(vi.x), hi16f(vj.x), v);
    v = fmaf(lo16f(vi.y), lo16f(vj.y), v);
    v = fmaf(hi16f(vi.y), hi16f(vj.y), v);
    v = fmaf(lo16f(vi.z), lo16f(vj.z), v);
    v = fmaf(hi16f(vi.z), hi16f(vj.z), v);
    v = fmaf(lo16f(vi.w), lo16f(vj.w), v);
    v = fmaf(hi16f(vi.w), hi16f(vj.w), v);
#pragma unroll
    for (int o = 4; o > 0; o >>= 1) v += __shfl_xor(v, o);
    if (sl == 0) out[ed] = v;
}

extern "C" void kernel_launch(void* const* d_in, const int* in_sizes, int n_in,
                              void* d_out, int out_size, void* d_ws, size_t ws_size,
                              hipStream_t stream) {
    const float* x   = (const float*)d_in[0];
    const int* train = (const int*)d_in[1];
    const int* pos   = (const int*)d_in[2];
    const int* neg   = (const int*)d_in[3];
    const float* W1  = (const float*)d_in[4];
    const float* b1  = (const float*)d_in[5];
    const float* W2  = (const float*)d_in[6];
    const float* b2  = (const float*)d_in[7];
    const float* W3  = (const float*)d_in[8];
    const float* b3  = (const float*)d_in[9];

    const int n  = in_sizes[0] / 128;
    const int E  = in_sizes[1] / 2;
    const int Ep = in_sizes[2] / 2;
    const int En = in_sizes[3] / 2;

    const int B  = (E + ECH - 1) / ECH;         // partition chunks (391 for E=1.6M)
    const int NB = ((n - 1) >> SHIFT) + 1;      // buckets (391 for n=100K)

    // Workspace (~85 MB; padded colw needs E + 8n entries)
    char* wp = (char*)d_ws;
    auto alloc = [&](size_t bytes) { char* r = wp; wp += (bytes + 255) & ~(size_t)255; return r; };
    int*   count    = (int*)alloc((size_t)n * 4);
    int*   row_ptr  = (int*)alloc(((size_t)n + 1) * 4);
    int*   partial  = (int*)alloc(256 * 4);
    int*   bucketTotal = (int*)alloc(MAXNB * 4);
    int*   bucketBase  = (int*)alloc(MAXNB * 4);
    int2*  colw     = (int2*)alloc(((size_t)E + 8 * (size_t)n) * 8);
    float* dinv     = (float*)alloc((size_t)n * 4);
    __hip_bfloat16* xw1 = (__hip_bfloat16*)alloc((size_t)n * 128 * 2);  // reused as h3(bf16 n*64)
    __hip_bfloat16* h1  = (__hip_bfloat16*)alloc((size_t)n * 128 * 2);
    __hip_bfloat16* P   = (__hip_bfloat16*)alloc((size_t)n * 64 * 2);   // xw2, later xw3
    __hip_bfloat16* h3  = xw1;
    __hip_bfloat16* xw3 = P;
    int2* bedges = (int2*)h1;       // alias: consumed before h1 is written
    int*  histG  = (int*)P;         // alias: NB*B*4 ~ 612KB, consumed before P is written

    float* out_scores = (float*)d_out;
    float* out_embed  = out_scores + (Ep + En);  // h2 lives here directly

    const int nbs = (n + 1023) / 1024;

    // radix partition (dst-bucketed edges) -> per-bucket degree count -> row_ptr/dinv -> CSR
    part_hist_kernel<<<B, 256, 0, stream>>>(train + E, E, B, NB, histG);
    part_scan_kernel<<<NB, 256, 0, stream>>>(histG, B, bucketTotal);
    bucket_base_kernel<<<1, 256, 0, stream>>>(bucketTotal, NB, bucketBase);
    part_scatter_kernel<<<B, 256, 0, stream>>>(train, train + E, E, B, NB, histG, bucketBase, bedges);
    count_bucket_kernel<<<NB, 256, 0, stream>>>(bedges, bucketBase, bucketTotal, n, count);
    scan_partial_kernel<<<nbs, 256, 0, stream>>>(count, n, partial);
    scan_offsets_kernel<<<1, 256, 0, stream>>>(partial, nbs, row_ptr, n);
    scan_write_kernel<<<nbs, 256, 0, stream>>>(count, n, partial, row_ptr, dinv);
    csr_fill_kernel<<<NB, 256, 0, stream>>>(bedges, bucketBase, bucketTotal, row_ptr, dinv, n, colw);

    // Layer 1
    gemm1_kernel<<<(n + 31) / 32, 256, 0, stream>>>(x, W1, xw1, n);
    gather128_kernel<<<(n + 3) / 4, 256, 0, stream>>>(xw1, row_ptr, colw, dinv, b1, h1, n);
    gemmA_kernel<<<(n + 63) / 64, 256, 0, stream>>>(h1, W2, P, n);

    // Layer 2 (h2 written straight into out_embed, fp32)
    gather64b_kernel<true, 0><<<(n + 3) / 4, 256, 0, stream>>>(
        P, row_ptr, colw, dinv, b2, out_embed, n);

    // Layer 3 (h3 emitted bf16 for the score stage)
    gemmB_kernel<<<(n + 63) / 64, 256, 0, stream>>>(out_embed, W3, xw3, n);
    gather64b_kernel<false, 1><<<(n + 3) / 4, 256, 0, stream>>>(
        xw3, row_ptr, colw, dinv, b3, h3, n);

    // Scores: 8 edges per wave
    {
        int waves = (Ep + En + 7) / 8;
        score_kernel<<<(int)(((size_t)waves * 64 + 255) / 256), 256, 0, stream>>>(
            h3, pos, neg, Ep, En, out_scores);
    }
}

// Round 17
// 317.535 us; speedup vs baseline: 1.4048x; 1.0810x over previous
//
#include <hip/hip_runtime.h>
#include <hip/hip_bf16.h>

// GCN link prediction. Inputs fp32+int32; OUTPUT fp32 (scores[1M] ++ embed[n*64]).
// CSR gather + bf16 feature tables (fp32 math), MFMA gemm1 (bf16 16x16x32),
// VALU-tiled gemmA/B, radix-partitioned CSR build, bucket-LDS degree count,
// padded unroll-8 scalarized gathers, 8-edge/wave uint4 score.

#define ECH 4096      // edges per partition chunk
#define SHIFT 8       // dsts per bucket = 256
#define MAXNB 512     // max buckets (n <= 131072)

typedef __attribute__((ext_vector_type(8))) short bf16x8;
typedef __attribute__((ext_vector_type(4))) float f32x4;

__device__ __forceinline__ float lo16f(uint32_t u) { uint32_t x = u << 16; float f; __builtin_memcpy(&f, &x, 4); return f; }
__device__ __forceinline__ float hi16f(uint32_t u) { uint32_t x = u & 0xffff0000u; float f; __builtin_memcpy(&f, &x, 4); return f; }
__device__ __forceinline__ float u16f(unsigned short u) { uint32_t x = (uint32_t)u << 16; float f; __builtin_memcpy(&f, &x, 4); return f; }
__device__ __forceinline__ uint32_t pk2(float a, float b) {
    union { __hip_bfloat162 h; uint32_t u; } cv;
    cv.h = __hip_bfloat162(__float2bfloat16(a), __float2bfloat16(b));
    return cv.u;
}
__device__ __forceinline__ unsigned short bf16bits(float a) {
    union { __hip_bfloat16 b; unsigned short u; } cv;
    cv.b = __float2bfloat16(a);
    return cv.u;
}
__device__ __forceinline__ int pad8(int c) { return (c + 7) & ~7; }

// ---------------- radix partition: edges -> buckets ----------------
__global__ __launch_bounds__(256) void part_hist_kernel(const int* __restrict__ dst, int E,
                                                        int B, int NB, int* __restrict__ histG) {
    __shared__ int h[MAXNB];
    int t = threadIdx.x, blk = blockIdx.x;
    for (int i = t; i < NB; i += 256) h[i] = 0;
    __syncthreads();
    int lo = blk * ECH, hi = min(lo + ECH, E);
    for (int i = lo + t; i < hi; i += 256) atomicAdd(&h[dst[i] >> SHIFT], 1);
    __syncthreads();
    for (int k = t; k < NB; k += 256) histG[(size_t)k * B + blk] = h[k];
}

__global__ __launch_bounds__(256) void part_scan_kernel(int* __restrict__ histG, int B,
                                                        int* __restrict__ bucketTotal) {
    __shared__ int sc[1024];   // supports B <= 1024
    int k = blockIdx.x, t = threadIdx.x;
    for (int i = t; i < 1024; i += 256) sc[i] = (i < B) ? histG[(size_t)k * B + i] : 0;
    __syncthreads();
    for (int o = 1; o < 1024; o <<= 1) {
        int v[4];
#pragma unroll
        for (int j = 0; j < 4; ++j) { int i = t + j * 256; v[j] = (i >= o) ? sc[i - o] : 0; }
        __syncthreads();
#pragma unroll
        for (int j = 0; j < 4; ++j) sc[t + j * 256] += v[j];
        __syncthreads();
    }
    for (int i = t; i < B; i += 256) histG[(size_t)k * B + i] = (i > 0) ? sc[i - 1] : 0;
    if (t == 0) bucketTotal[k] = sc[B - 1];
}

__global__ __launch_bounds__(256) void bucket_base_kernel(const int* __restrict__ bucketTotal,
                                                          int NB, int* __restrict__ bucketBase) {
    __shared__ int sc[MAXNB];
    int t = threadIdx.x;
    for (int i = t; i < MAXNB; i += 256) sc[i] = (i < NB) ? bucketTotal[i] : 0;
    __syncthreads();
    for (int o = 1; o < MAXNB; o <<= 1) {
        int v[MAXNB / 256];
#pragma unroll
        for (int j = 0; j < MAXNB / 256; ++j) { int i = t + j * 256; v[j] = (i >= o) ? sc[i - o] : 0; }
        __syncthreads();
#pragma unroll
        for (int j = 0; j < MAXNB / 256; ++j) sc[t + j * 256] += v[j];
        __syncthreads();
    }
    for (int i = t; i < NB; i += 256) bucketBase[i] = (i > 0) ? sc[i - 1] : 0;
}

__global__ __launch_bounds__(256) void part_scatter_kernel(
    const int* __restrict__ src, const int* __restrict__ dst, int E, int B, int NB,
    const int* __restrict__ histG, const int* __restrict__ bucketBase,
    int2* __restrict__ bedges) {
    __shared__ int cur[MAXNB];
    int t = threadIdx.x, blk = blockIdx.x;
    for (int k = t; k < NB; k += 256) cur[k] = bucketBase[k] + histG[(size_t)k * B + blk];
    __syncthreads();
    int lo = blk * ECH, hi = min(lo + ECH, E);
    for (int i = lo + t; i < hi; i += 256) {
        int s = src[i], d = dst[i];
        int p = atomicAdd(&cur[d >> SHIFT], 1);
        bedges[p] = make_int2(s, d);
    }
}

// Per-bucket degree count from partitioned edges.
__global__ __launch_bounds__(256) void count_bucket_kernel(
    const int2* __restrict__ bedges, const int* __restrict__ bucketBase,
    const int* __restrict__ bucketTotal, int n, int* __restrict__ count) {
    __shared__ int hist[1 << SHIFT];
    int k = blockIdx.x, t = threadIdx.x;
    hist[t] = 0;
    __syncthreads();
    int base = bucketBase[k], cnt = bucketTotal[k];
    int d0 = k << SHIFT;
    for (int i = t; i < cnt; i += 256) atomicAdd(&hist[bedges[base + i].y - d0], 1);
    __syncthreads();
    int d = d0 + t;
    if (d < n) count[d] = hist[t];
}

// ---------------- (padded) row_ptr scan + dinv ----------------
__global__ __launch_bounds__(256) void scan_partial_kernel(const int* __restrict__ count, int n,
                                                           int* __restrict__ partial) {
    __shared__ int red[256];
    int t = threadIdx.x;
    int base = blockIdx.x * 1024 + t * 4;
    int s = 0;
#pragma unroll
    for (int i = 0; i < 4; ++i) {
        int idx = base + i;
        if (idx < n) s += pad8(count[idx]);
    }
    red[t] = s;
    __syncthreads();
    for (int o = 128; o > 0; o >>= 1) {
        if (t < o) red[t] += red[t + o];
        __syncthreads();
    }
    if (t == 0) partial[blockIdx.x] = red[0];
}

__global__ __launch_bounds__(256) void scan_offsets_kernel(int* __restrict__ partial, int nb,
                                                           int* __restrict__ row_ptr, int n) {
    __shared__ int sc[256];
    int t = threadIdx.x;
    sc[t] = (t < nb) ? partial[t] : 0;
    __syncthreads();
    for (int o = 1; o < 256; o <<= 1) {
        int v = sc[t];
        int u = (t >= o) ? sc[t - o] : 0;
        __syncthreads();
        sc[t] = v + u;
        __syncthreads();
    }
    if (t < nb) partial[t] = (t > 0) ? sc[t - 1] : 0;  // exclusive
    if (t == 0) row_ptr[n] = sc[255];
}

__global__ __launch_bounds__(256) void scan_write_kernel(const int* __restrict__ count, int n,
                                                         const int* __restrict__ partial,
                                                         int* __restrict__ row_ptr,
                                                         float* __restrict__ dinv) {
    __shared__ int sc[256];
    int t = threadIdx.x;
    int base = blockIdx.x * 1024 + t * 4;
    int c[4];
    int s = 0;
#pragma unroll
    for (int i = 0; i < 4; ++i) {
        int idx = base + i;
        c[i] = (idx < n) ? count[idx] : 0;
        s += pad8(c[i]);
    }
    sc[t] = s;
    __syncthreads();
    for (int o = 1; o < 256; o <<= 1) {
        int v = sc[t];
        int u = (t >= o) ? sc[t - o] : 0;
        __syncthreads();
        sc[t] = v + u;
        __syncthreads();
    }
    int run = partial[blockIdx.x] + ((t > 0) ? sc[t - 1] : 0);
#pragma unroll
    for (int i = 0; i < 4; ++i) {
        int idx = base + i;
        if (idx < n) {
            row_ptr[idx] = run;
            dinv[idx] = rsqrtf((float)c[i] + 1.0f);
            run += pad8(c[i]);
        }
    }
}

// Fill CSR (padded layout): real edges via LDS cursors, then pad tails with (d, 0).
__global__ __launch_bounds__(256) void csr_fill_kernel(
    const int2* __restrict__ bedges, const int* __restrict__ bucketBase,
    const int* __restrict__ bucketTotal, const int* __restrict__ row_ptr,
    const float* __restrict__ dinv, int n, int2* __restrict__ colw) {
    __shared__ int cur[1 << SHIFT];
    int k = blockIdx.x, t = threadIdx.x;
    int d0 = k << SHIFT;
    for (int i = t; i < (1 << SHIFT); i += 256) {
        int d = d0 + i;
        cur[i] = (d < n) ? row_ptr[d] : 0;
    }
    __syncthreads();
    int base = bucketBase[k], cnt = bucketTotal[k];
    for (int i = t; i < cnt; i += 256) {
        int2 e = bedges[base + i];
        float w = dinv[e.x];
        int p = atomicAdd(&cur[e.y - d0], 1);
        colw[p] = make_int2(e.x, __float_as_int(w));
    }
    __syncthreads();
    for (int i = t; i < (1 << SHIFT); i += 256) {
        int d = d0 + i;
        if (d < n) {
            int pend = row_ptr[d + 1];
            for (int p = cur[i]; p < pend; ++p) colw[p] = make_int2(d, 0);
        }
    }
}

// ---------------- MFMA gemm1: xw1 = x @ W1 (bf16 compute) ----------------
// Pack W1 (row-major [k][col], f32) into B-fragment order: [kc(4)][ct(8)][lane(64)][j(8)] bf16.
// Lane l, elem j of fragment (kc,ct): B[k = kc*32 + (l>>4)*8 + j][col = ct*16 + (l&15)].
__global__ __launch_bounds__(256) void packW1_kernel(const float* __restrict__ W,
                                                     __hip_bfloat16* __restrict__ Wp) {
    int idx = blockIdx.x * 256 + threadIdx.x;   // 2048 total
    int lane = idx & 63;
    int ct = (idx >> 6) & 7;
    int kc = idx >> 9;
    int col = ct * 16 + (lane & 15);
    int k0 = kc * 32 + (lane >> 4) * 8;
    unsigned short tmp[8];
#pragma unroll
    for (int j = 0; j < 8; ++j) tmp[j] = bf16bits(W[(size_t)(k0 + j) * 128 + col]);
    ((uint4*)Wp)[idx] = *(const uint4*)tmp;
}

// 64 rows/block, 4 waves x 16 rows; per wave: 8 col-tiles, K in 4 chunks of 32.
// A staged in LDS fragment-ready: sA[row][40] bf16 (80B rows).
__global__ __launch_bounds__(256) void gemm1_mfma_kernel(
    const float* __restrict__ In, const __hip_bfloat16* __restrict__ Wp,
    __hip_bfloat16* __restrict__ Out, int n) {
    __shared__ unsigned short sA[64 * 40];
    int t = threadIdx.x;
    int wv = t >> 6, lane = t & 63;
    int rbase = blockIdx.x * 64;
    f32x4 acc[8] = {};
    int srow = t >> 2;            // staging: row 0..63
    int kseg = (t & 3) * 8;       // staging: k-segment {0,8,16,24}
    int arow = wv * 16 + (lane & 15);
    int aoff = (lane >> 4) * 8;
    for (int kc = 0; kc < 4; ++kc) {
        {   // stage 64x32 fp32 -> bf16
            int gr = rbase + srow;
            unsigned short tmp[8];
            if (gr < n) {
                const float* src = &In[(size_t)gr * 128 + kc * 32 + kseg];
                float4 v0 = *(const float4*)src;
                float4 v1 = *(const float4*)(src + 4);
                tmp[0] = bf16bits(v0.x); tmp[1] = bf16bits(v0.y);
                tmp[2] = bf16bits(v0.z); tmp[3] = bf16bits(v0.w);
                tmp[4] = bf16bits(v1.x); tmp[5] = bf16bits(v1.y);
                tmp[6] = bf16bits(v1.z); tmp[7] = bf16bits(v1.w);
            } else {
#pragma unroll
                for (int j = 0; j < 8; ++j) tmp[j] = 0;
            }
            *(uint4*)&sA[srow * 40 + kseg] = *(const uint4*)tmp;
        }
        __syncthreads();
        bf16x8 afrag = *(const bf16x8*)&sA[arow * 40 + aoff];
        const uint4* wp = (const uint4*)Wp + (size_t)kc * 512 + lane;
#pragma unroll
        for (int ct = 0; ct < 8; ++ct) {
            uint4 braw = wp[ct * 64];
            bf16x8 bfrag;
            __builtin_memcpy(&bfrag, &braw, 16);
            acc[ct] = __builtin_amdgcn_mfma_f32_16x16x32_bf16(afrag, bfrag, acc[ct], 0, 0, 0);
        }
        __syncthreads();
    }
    // C: row = wv*16 + (lane>>4)*4 + r, col = ct*16 + (lane&15)
    int orow0 = rbase + wv * 16 + (lane >> 4) * 4;
    int ocol = lane & 15;
#pragma unroll
    for (int ct = 0; ct < 8; ++ct) {
#pragma unroll
        for (int r = 0; r < 4; ++r) {
            int gr = orow0 + r;
            if (gr < n)
                ((unsigned short*)Out)[(size_t)gr * 128 + ct * 16 + ocol] = bf16bits(acc[ct][r]);
        }
    }
}

// ---------------- VALU GEMMs A/B (4x4 register tile, pad 65) ----------------
#define FMA16(a, b, acc)                                                     \
    acc[0][0] = fmaf(a.x, b.x, acc[0][0]); acc[0][1] = fmaf(a.x, b.y, acc[0][1]); \
    acc[0][2] = fmaf(a.x, b.z, acc[0][2]); acc[0][3] = fmaf(a.x, b.w, acc[0][3]); \
    acc[1][0] = fmaf(a.y, b.x, acc[1][0]); acc[1][1] = fmaf(a.y, b.y, acc[1][1]); \
    acc[1][2] = fmaf(a.y, b.z, acc[1][2]); acc[1][3] = fmaf(a.y, b.w, acc[1][3]); \
    acc[2][0] = fmaf(a.z, b.x, acc[2][0]); acc[2][1] = fmaf(a.z, b.y, acc[2][1]); \
    acc[2][2] = fmaf(a.z, b.z, acc[2][2]); acc[2][3] = fmaf(a.z, b.w, acc[2][3]); \
    acc[3][0] = fmaf(a.w, b.x, acc[3][0]); acc[3][1] = fmaf(a.w, b.y, acc[3][1]); \
    acc[3][2] = fmaf(a.w, b.z, acc[3][2]); acc[3][3] = fmaf(a.w, b.w, acc[3][3]);

__global__ __launch_bounds__(256) void gemmA_kernel(const __hip_bfloat16* __restrict__ In,
                                                    const float* __restrict__ W,
                                                    __hip_bfloat16* __restrict__ Out, int n) {
    __shared__ float sInT[32][65];   // pad
    __shared__ float sW[32][64];
    int t = threadIdx.x;
    int tr = t >> 4, tc = t & 15;
    int rbase = blockIdx.x * 64;
    float acc[4][4] = {};
    const uint32_t* Inu = (const uint32_t*)In;
    for (int kt = 0; kt < 128; kt += 32) {
        for (int i = t; i < 1024; i += 256) {
            int r = i >> 4, ku = i & 15;
            int gr = rbase + r;
            uint32_t u = (gr < n) ? Inu[(size_t)gr * 64 + (kt >> 1) + ku] : 0u;
            sInT[2 * ku][r] = lo16f(u);
            sInT[2 * ku + 1][r] = hi16f(u);
        }
        {
            const float4* Wv = (const float4*)&W[(size_t)kt * 64];
            float4* sWv = (float4*)&sW[0][0];
            for (int i = t; i < 512; i += 256) sWv[i] = Wv[i];
        }
        __syncthreads();
#pragma unroll
        for (int k = 0; k < 32; ++k) {
            float4 a;
            a.x = sInT[k][(tr << 2) + 0]; a.y = sInT[k][(tr << 2) + 1];
            a.z = sInT[k][(tr << 2) + 2]; a.w = sInT[k][(tr << 2) + 3];
            float4 b = *(const float4*)&sW[k][tc << 2];
            FMA16(a, b, acc)
        }
        __syncthreads();
    }
#pragma unroll
    for (int i = 0; i < 4; ++i) {
        int gr = rbase + (tr << 2) + i;
        if (gr < n) {
            uint2 pk;
            pk.x = pk2(acc[i][0], acc[i][1]);
            pk.y = pk2(acc[i][2], acc[i][3]);
            *(uint2*)((uint32_t*)Out + (size_t)gr * 32 + (tc << 1)) = pk;
        }
    }
}

__global__ __launch_bounds__(256) void gemmB_kernel(const float* __restrict__ In,
                                                    const float* __restrict__ W,
                                                    __hip_bfloat16* __restrict__ Out, int n) {
    __shared__ float sInT[32][65];   // pad
    __shared__ float sW[32][64];
    int t = threadIdx.x;
    int tr = t >> 4, tc = t & 15;
    int rbase = blockIdx.x * 64;
    float acc[4][4] = {};
    for (int kt = 0; kt < 64; kt += 32) {
        for (int i = t; i < 512; i += 256) {
            int r = i >> 3, k4 = (i & 7) << 2;
            int gr = rbase + r;
            float4 v = make_float4(0.f, 0.f, 0.f, 0.f);
            if (gr < n) v = *(const float4*)&In[(size_t)gr * 64 + kt + k4];
            sInT[k4 + 0][r] = v.x; sInT[k4 + 1][r] = v.y;
            sInT[k4 + 2][r] = v.z; sInT[k4 + 3][r] = v.w;
        }
        {
            const float4* Wv = (const float4*)&W[(size_t)kt * 64];
            float4* sWv = (float4*)&sW[0][0];
            for (int i = t; i < 512; i += 256) sWv[i] = Wv[i];
        }
        __syncthreads();
#pragma unroll
        for (int k = 0; k < 32; ++k) {
            float4 a;
            a.x = sInT[k][(tr << 2) + 0]; a.y = sInT[k][(tr << 2) + 1];
            a.z = sInT[k][(tr << 2) + 2]; a.w = sInT[k][(tr << 2) + 3];
            float4 b = *(const float4*)&sW[k][tc << 2];
            FMA16(a, b, acc)
        }
        __syncthreads();
    }
#pragma unroll
    for (int i = 0; i < 4; ++i) {
        int gr = rbase + (tr << 2) + i;
        if (gr < n) {
            uint2 pk;
            pk.x = pk2(acc[i][0], acc[i][1]);
            pk.y = pk2(acc[i][2], acc[i][3]);
            *(uint2*)((uint32_t*)Out + (size_t)gr * 32 + (tc << 1)) = pk;
        }
    }
}

// ---- Gathers: branch-free unroll-8, dual accumulators, SCALAR edge lists ----
__global__ __launch_bounds__(256) void gather128_kernel(
    const __hip_bfloat16* __restrict__ xw, const int* __restrict__ row_ptr,
    const int2* __restrict__ colw, const float* __restrict__ dinv,
    const float* __restrict__ b1, __hip_bfloat16* __restrict__ h1, int n) {
    int w = threadIdx.x >> 6, l = threadIdx.x & 63;
    int d = blockIdx.x * 4 + w;
    if (d >= n) return;
    float dd = dinv[d];
    int p0 = __builtin_amdgcn_readfirstlane(row_ptr[d]);
    int p1 = __builtin_amdgcn_readfirstlane(row_ptr[d + 1]);
    const uint32_t* X = (const uint32_t*)xw;
    uint32_t v = X[(size_t)d * 64 + l];
    float a0 = dd * lo16f(v), a1 = dd * hi16f(v);
    float c0a = 0.f, c1a = 0.f;
    for (int e = p0; e < p1; e += 8) {
        int s0 = __builtin_amdgcn_readfirstlane(colw[e].x);
        int s1 = __builtin_amdgcn_readfirstlane(colw[e + 1].x);
        int s2 = __builtin_amdgcn_readfirstlane(colw[e + 2].x);
        int s3 = __builtin_amdgcn_readfirstlane(colw[e + 3].x);
        int s4 = __builtin_amdgcn_readfirstlane(colw[e + 4].x);
        int s5 = __builtin_amdgcn_readfirstlane(colw[e + 5].x);
        int s6 = __builtin_amdgcn_readfirstlane(colw[e + 6].x);
        int s7 = __builtin_amdgcn_readfirstlane(colw[e + 7].x);
        float w0 = __int_as_float(__builtin_amdgcn_readfirstlane(colw[e].y));
        float w1 = __int_as_float(__builtin_amdgcn_readfirstlane(colw[e + 1].y));
        float w2 = __int_as_float(__builtin_amdgcn_readfirstlane(colw[e + 2].y));
        float w3 = __int_as_float(__builtin_amdgcn_readfirstlane(colw[e + 3].y));
        float w4 = __int_as_float(__builtin_amdgcn_readfirstlane(colw[e + 4].y));
        float w5 = __int_as_float(__builtin_amdgcn_readfirstlane(colw[e + 5].y));
        float w6 = __int_as_float(__builtin_amdgcn_readfirstlane(colw[e + 6].y));
        float w7 = __int_as_float(__builtin_amdgcn_readfirstlane(colw[e + 7].y));
        uint32_t v0 = X[(size_t)s0 * 64 + l];
        uint32_t v1 = X[(size_t)s1 * 64 + l];
        uint32_t v2 = X[(size_t)s2 * 64 + l];
        uint32_t v3 = X[(size_t)s3 * 64 + l];
        uint32_t v4 = X[(size_t)s4 * 64 + l];
        uint32_t v5 = X[(size_t)s5 * 64 + l];
        uint32_t v6 = X[(size_t)s6 * 64 + l];
        uint32_t v7 = X[(size_t)s7 * 64 + l];
        a0 = fmaf(w0, lo16f(v0), a0);  a1 = fmaf(w0, hi16f(v0), a1);
        c0a = fmaf(w1, lo16f(v1), c0a); c1a = fmaf(w1, hi16f(v1), c1a);
        a0 = fmaf(w2, lo16f(v2), a0);  a1 = fmaf(w2, hi16f(v2), a1);
        c0a = fmaf(w3, lo16f(v3), c0a); c1a = fmaf(w3, hi16f(v3), c1a);
        a0 = fmaf(w4, lo16f(v4), a0);  a1 = fmaf(w4, hi16f(v4), a1);
        c0a = fmaf(w5, lo16f(v5), c0a); c1a = fmaf(w5, hi16f(v5), c1a);
        a0 = fmaf(w6, lo16f(v6), a0);  a1 = fmaf(w6, hi16f(v6), a1);
        c0a = fmaf(w7, lo16f(v7), c0a); c1a = fmaf(w7, hi16f(v7), c1a);
    }
    a0 += c0a; a1 += c1a;
    a0 = fmaxf(fmaf(dd, a0, b1[2 * l]), 0.0f);
    a1 = fmaxf(fmaf(dd, a1, b1[2 * l + 1]), 0.0f);
    ((uint32_t*)h1)[(size_t)d * 64 + l] = pk2(a0, a1);
}

// OUT=0: fp32 out; OUT=1: bf16 out.
template<bool RELU, int OUT>
__global__ __launch_bounds__(256) void gather64b_kernel(
    const __hip_bfloat16* __restrict__ xw, const int* __restrict__ row_ptr,
    const int2* __restrict__ colw, const float* __restrict__ dinv,
    const float* __restrict__ b, void* __restrict__ out, int n) {
    int w = threadIdx.x >> 6, l = threadIdx.x & 63;
    int d = blockIdx.x * 4 + w;
    if (d >= n) return;
    float dd = dinv[d];
    int p0 = __builtin_amdgcn_readfirstlane(row_ptr[d]);
    int p1 = __builtin_amdgcn_readfirstlane(row_ptr[d + 1]);
    const unsigned short* X = (const unsigned short*)xw;
    float a = dd * u16f(X[(size_t)d * 64 + l]);
    float c = 0.f;
    for (int e = p0; e < p1; e += 8) {
        int s0 = __builtin_amdgcn_readfirstlane(colw[e].x);
        int s1 = __builtin_amdgcn_readfirstlane(colw[e + 1].x);
        int s2 = __builtin_amdgcn_readfirstlane(colw[e + 2].x);
        int s3 = __builtin_amdgcn_readfirstlane(colw[e + 3].x);
        int s4 = __builtin_amdgcn_readfirstlane(colw[e + 4].x);
        int s5 = __builtin_amdgcn_readfirstlane(colw[e + 5].x);
        int s6 = __builtin_amdgcn_readfirstlane(colw[e + 6].x);
        int s7 = __builtin_amdgcn_readfirstlane(colw[e + 7].x);
        float w0 = __int_as_float(__builtin_amdgcn_readfirstlane(colw[e].y));
        float w1 = __int_as_float(__builtin_amdgcn_readfirstlane(colw[e + 1].y));
        float w2 = __int_as_float(__builtin_amdgcn_readfirstlane(colw[e + 2].y));
        float w3 = __int_as_float(__builtin_amdgcn_readfirstlane(colw[e + 3].y));
        float w4 = __int_as_float(__builtin_amdgcn_readfirstlane(colw[e + 4].y));
        float w5 = __int_as_float(__builtin_amdgcn_readfirstlane(colw[e + 5].y));
        float w6 = __int_as_float(__builtin_amdgcn_readfirstlane(colw[e + 6].y));
        float w7 = __int_as_float(__builtin_amdgcn_readfirstlane(colw[e + 7].y));
        unsigned short v0 = X[(size_t)s0 * 64 + l];
        unsigned short v1 = X[(size_t)s1 * 64 + l];
        unsigned short v2 = X[(size_t)s2 * 64 + l];
        unsigned short v3 = X[(size_t)s3 * 64 + l];
        unsigned short v4 = X[(size_t)s4 * 64 + l];
        unsigned short v5 = X[(size_t)s5 * 64 + l];
        unsigned short v6 = X[(size_t)s6 * 64 + l];
        unsigned short v7 = X[(size_t)s7 * 64 + l];
        a = fmaf(w0, u16f(v0), a);
        c = fmaf(w1, u16f(v1), c);
        a = fmaf(w2, u16f(v2), a);
        c = fmaf(w3, u16f(v3), c);
        a = fmaf(w4, u16f(v4), a);
        c = fmaf(w5, u16f(v5), c);
        a = fmaf(w6, u16f(v6), a);
        c = fmaf(w7, u16f(v7), c);
    }
    a += c;
    float r = fmaf(dd, a, b[l]);
    if (RELU) r = fmaxf(r, 0.0f);
    if (OUT == 0) ((float*)out)[(size_t)d * 64 + l] = r;
    else ((unsigned short*)out)[(size_t)d * 64 + l] = bf16bits(r);
}

// ---------------- Score: 8 edges per wave, 8-lane groups, uint4 row loads ----------
__global__ void score_kernel(const __hip_bfloat16* __restrict__ h, const int* __restrict__ pos,
                             const int* __restrict__ neg, int Ep, int En,
                             float* __restrict__ out) {
    int wid = (int)(((size_t)blockIdx.x * blockDim.x + threadIdx.x) >> 6);
    int lane = threadIdx.x & 63;
    int g = lane >> 3, sl = lane & 7;
    int ed = wid * 8 + g;
    int tot = Ep + En;
    if (ed >= tot) return;
    int j, i;
    if (ed < Ep) { j = pos[ed]; i = pos[Ep + ed]; }
    else { int e = ed - Ep; j = neg[e]; i = neg[En + e]; }
    const uint4* X = (const uint4*)h;  // 8 uint4 per 64-feat bf16 row
    uint4 vi = X[(size_t)i * 8 + sl];
    uint4 vj = X[(size_t)j * 8 + sl];
    float v;
    v = lo16f(vi.x) * lo16f(vj.x);
    v = fmaf(hi16f(vi.x), hi16f(vj.x), v);
    v = fmaf(lo16f(vi.y), lo16f(vj.y), v);
    v = fmaf(hi16f(vi.y), hi16f(vj.y), v);
    v = fmaf(lo16f(vi.z), lo16f(vj.z), v);
    v = fmaf(hi16f(vi.z), hi16f(vj.z), v);
    v = fmaf(lo16f(vi.w), lo16f(vj.w), v);
    v = fmaf(hi16f(vi.w), hi16f(vj.w), v);
#pragma unroll
    for (int o = 4; o > 0; o >>= 1) v += __shfl_xor(v, o);
    if (sl == 0) out[ed] = v;
}

extern "C" void kernel_launch(void* const* d_in, const int* in_sizes, int n_in,
                              void* d_out, int out_size, void* d_ws, size_t ws_size,
                              hipStream_t stream) {
    const float* x   = (const float*)d_in[0];
    const int* train = (const int*)d_in[1];
    const int* pos   = (const int*)d_in[2];
    const int* neg   = (const int*)d_in[3];
    const float* W1  = (const float*)d_in[4];
    const float* b1  = (const float*)d_in[5];
    const float* W2  = (const float*)d_in[6];
    const float* b2  = (const float*)d_in[7];
    const float* W3  = (const float*)d_in[8];
    const float* b3  = (const float*)d_in[9];

    const int n  = in_sizes[0] / 128;
    const int E  = in_sizes[1] / 2;
    const int Ep = in_sizes[2] / 2;
    const int En = in_sizes[3] / 2;

    const int B  = (E + ECH - 1) / ECH;         // partition chunks (391 for E=1.6M)
    const int NB = ((n - 1) >> SHIFT) + 1;      // buckets (391 for n=100K)

    // Workspace (~85 MB)
    char* wp = (char*)d_ws;
    auto alloc = [&](size_t bytes) { char* r = wp; wp += (bytes + 255) & ~(size_t)255; return r; };
    int*   count    = (int*)alloc((size_t)n * 4);
    int*   row_ptr  = (int*)alloc(((size_t)n + 1) * 4);
    int*   partial  = (int*)alloc(256 * 4);
    int*   bucketTotal = (int*)alloc(MAXNB * 4);
    int*   bucketBase  = (int*)alloc(MAXNB * 4);
    __hip_bfloat16* Wp = (__hip_bfloat16*)alloc(4 * 8 * 64 * 8 * 2);   // packed W1 (32KB)
    int2*  colw     = (int2*)alloc(((size_t)E + 8 * (size_t)n) * 8);
    float* dinv     = (float*)alloc((size_t)n * 4);
    __hip_bfloat16* xw1 = (__hip_bfloat16*)alloc((size_t)n * 128 * 2);  // reused as h3(bf16 n*64)
    __hip_bfloat16* h1  = (__hip_bfloat16*)alloc((size_t)n * 128 * 2);
    __hip_bfloat16* P   = (__hip_bfloat16*)alloc((size_t)n * 64 * 2);   // xw2, later xw3
    __hip_bfloat16* h3  = xw1;
    __hip_bfloat16* xw3 = P;
    int2* bedges = (int2*)h1;       // alias: consumed before h1 is written
    int*  histG  = (int*)P;         // alias: NB*B*4 ~ 612KB, consumed before P is written

    float* out_scores = (float*)d_out;
    float* out_embed  = out_scores + (Ep + En);  // h2 lives here directly

    const int nbs = (n + 1023) / 1024;

    // radix partition -> per-bucket count -> row_ptr/dinv -> CSR
    part_hist_kernel<<<B, 256, 0, stream>>>(train + E, E, B, NB, histG);
    part_scan_kernel<<<NB, 256, 0, stream>>>(histG, B, bucketTotal);
    bucket_base_kernel<<<1, 256, 0, stream>>>(bucketTotal, NB, bucketBase);
    part_scatter_kernel<<<B, 256, 0, stream>>>(train, train + E, E, B, NB, histG, bucketBase, bedges);
    count_bucket_kernel<<<NB, 256, 0, stream>>>(bedges, bucketBase, bucketTotal, n, count);
    scan_partial_kernel<<<nbs, 256, 0, stream>>>(count, n, partial);
    scan_offsets_kernel<<<1, 256, 0, stream>>>(partial, nbs, row_ptr, n);
    scan_write_kernel<<<nbs, 256, 0, stream>>>(count, n, partial, row_ptr, dinv);
    csr_fill_kernel<<<NB, 256, 0, stream>>>(bedges, bucketBase, bucketTotal, row_ptr, dinv, n, colw);

    // Layer 1 (MFMA)
    packW1_kernel<<<8, 256, 0, stream>>>(W1, Wp);
    gemm1_mfma_kernel<<<(n + 63) / 64, 256, 0, stream>>>(x, Wp, xw1, n);
    gather128_kernel<<<(n + 3) / 4, 256, 0, stream>>>(xw1, row_ptr, colw, dinv, b1, h1, n);
    gemmA_kernel<<<(n + 63) / 64, 256, 0, stream>>>(h1, W2, P, n);

    // Layer 2 (h2 written straight into out_embed, fp32)
    gather64b_kernel<true, 0><<<(n + 3) / 4, 256, 0, stream>>>(
        P, row_ptr, colw, dinv, b2, out_embed, n);

    // Layer 3 (h3 emitted bf16 for the score stage)
    gemmB_kernel<<<(n + 63) / 64, 256, 0, stream>>>(out_embed, W3, xw3, n);
    gather64b_kernel<false, 1><<<(n + 3) / 4, 256, 0, stream>>>(
        xw3, row_ptr, colw, dinv, b3, h3, n);

    // Scores: 8 edges per wave
    {
        int waves = (Ep + En + 7) / 8;
        score_kernel<<<(int)(((size_t)waves * 64 + 255) / 256), 256, 0, stream>>>(
            h3, pos, neg, Ep, En, out_scores);
    }
}

// Round 18
// 293.458 us; speedup vs baseline: 1.5200x; 1.0820x over previous
//
#include <hip/hip_runtime.h>
#include <hip/hip_bf16.h>

// GCN link prediction. Inputs fp32+int32; OUTPUT fp32 (scores[1M] ++ embed[n*64]).
// CSR gather + bf16 feature tables (fp32 math), MFMA for ALL three GEMMs
// (bf16 16x16x32, fragment-packed weights), radix-partitioned CSR build,
// bucket-LDS degree count, padded unroll-8 scalarized gathers, 8-edge/wave score.

#define ECH 4096      // edges per partition chunk
#define SHIFT 8       // dsts per bucket = 256
#define MAXNB 512     // max buckets (n <= 131072)

typedef __attribute__((ext_vector_type(8))) short bf16x8;
typedef __attribute__((ext_vector_type(4))) float f32x4;

__device__ __forceinline__ float lo16f(uint32_t u) { uint32_t x = u << 16; float f; __builtin_memcpy(&f, &x, 4); return f; }
__device__ __forceinline__ float hi16f(uint32_t u) { uint32_t x = u & 0xffff0000u; float f; __builtin_memcpy(&f, &x, 4); return f; }
__device__ __forceinline__ float u16f(unsigned short u) { uint32_t x = (uint32_t)u << 16; float f; __builtin_memcpy(&f, &x, 4); return f; }
__device__ __forceinline__ uint32_t pk2(float a, float b) {
    union { __hip_bfloat162 h; uint32_t u; } cv;
    cv.h = __hip_bfloat162(__float2bfloat16(a), __float2bfloat16(b));
    return cv.u;
}
__device__ __forceinline__ unsigned short bf16bits(float a) {
    union { __hip_bfloat16 b; unsigned short u; } cv;
    cv.b = __float2bfloat16(a);
    return cv.u;
}
__device__ __forceinline__ int pad8(int c) { return (c + 7) & ~7; }

// ---------------- radix partition: edges -> buckets ----------------
__global__ __launch_bounds__(256) void part_hist_kernel(const int* __restrict__ dst, int E,
                                                        int B, int NB, int* __restrict__ histG) {
    __shared__ int h[MAXNB];
    int t = threadIdx.x, blk = blockIdx.x;
    for (int i = t; i < NB; i += 256) h[i] = 0;
    __syncthreads();
    int lo = blk * ECH, hi = min(lo + ECH, E);
    for (int i = lo + t; i < hi; i += 256) atomicAdd(&h[dst[i] >> SHIFT], 1);
    __syncthreads();
    for (int k = t; k < NB; k += 256) histG[(size_t)k * B + blk] = h[k];
}

__global__ __launch_bounds__(256) void part_scan_kernel(int* __restrict__ histG, int B,
                                                        int* __restrict__ bucketTotal) {
    __shared__ int sc[1024];   // supports B <= 1024
    int k = blockIdx.x, t = threadIdx.x;
    for (int i = t; i < 1024; i += 256) sc[i] = (i < B) ? histG[(size_t)k * B + i] : 0;
    __syncthreads();
    for (int o = 1; o < 1024; o <<= 1) {
        int v[4];
#pragma unroll
        for (int j = 0; j < 4; ++j) { int i = t + j * 256; v[j] = (i >= o) ? sc[i - o] : 0; }
        __syncthreads();
#pragma unroll
        for (int j = 0; j < 4; ++j) sc[t + j * 256] += v[j];
        __syncthreads();
    }
    for (int i = t; i < B; i += 256) histG[(size_t)k * B + i] = (i > 0) ? sc[i - 1] : 0;
    if (t == 0) bucketTotal[k] = sc[B - 1];
}

__global__ __launch_bounds__(256) void bucket_base_kernel(const int* __restrict__ bucketTotal,
                                                          int NB, int* __restrict__ bucketBase) {
    __shared__ int sc[MAXNB];
    int t = threadIdx.x;
    for (int i = t; i < MAXNB; i += 256) sc[i] = (i < NB) ? bucketTotal[i] : 0;
    __syncthreads();
    for (int o = 1; o < MAXNB; o <<= 1) {
        int v[MAXNB / 256];
#pragma unroll
        for (int j = 0; j < MAXNB / 256; ++j) { int i = t + j * 256; v[j] = (i >= o) ? sc[i - o] : 0; }
        __syncthreads();
#pragma unroll
        for (int j = 0; j < MAXNB / 256; ++j) sc[t + j * 256] += v[j];
        __syncthreads();
    }
    for (int i = t; i < NB; i += 256) bucketBase[i] = (i > 0) ? sc[i - 1] : 0;
}

__global__ __launch_bounds__(256) void part_scatter_kernel(
    const int* __restrict__ src, const int* __restrict__ dst, int E, int B, int NB,
    const int* __restrict__ histG, const int* __restrict__ bucketBase,
    int2* __restrict__ bedges) {
    __shared__ int cur[MAXNB];
    int t = threadIdx.x, blk = blockIdx.x;
    for (int k = t; k < NB; k += 256) cur[k] = bucketBase[k] + histG[(size_t)k * B + blk];
    __syncthreads();
    int lo = blk * ECH, hi = min(lo + ECH, E);
    for (int i = lo + t; i < hi; i += 256) {
        int s = src[i], d = dst[i];
        int p = atomicAdd(&cur[d >> SHIFT], 1);
        bedges[p] = make_int2(s, d);
    }
}

// Per-bucket degree count from partitioned edges.
__global__ __launch_bounds__(256) void count_bucket_kernel(
    const int2* __restrict__ bedges, const int* __restrict__ bucketBase,
    const int* __restrict__ bucketTotal, int n, int* __restrict__ count) {
    __shared__ int hist[1 << SHIFT];
    int k = blockIdx.x, t = threadIdx.x;
    hist[t] = 0;
    __syncthreads();
    int base = bucketBase[k], cnt = bucketTotal[k];
    int d0 = k << SHIFT;
    for (int i = t; i < cnt; i += 256) atomicAdd(&hist[bedges[base + i].y - d0], 1);
    __syncthreads();
    int d = d0 + t;
    if (d < n) count[d] = hist[t];
}

// ---------------- (padded) row_ptr scan + dinv ----------------
__global__ __launch_bounds__(256) void scan_partial_kernel(const int* __restrict__ count, int n,
                                                           int* __restrict__ partial) {
    __shared__ int red[256];
    int t = threadIdx.x;
    int base = blockIdx.x * 1024 + t * 4;
    int s = 0;
#pragma unroll
    for (int i = 0; i < 4; ++i) {
        int idx = base + i;
        if (idx < n) s += pad8(count[idx]);
    }
    red[t] = s;
    __syncthreads();
    for (int o = 128; o > 0; o >>= 1) {
        if (t < o) red[t] += red[t + o];
        __syncthreads();
    }
    if (t == 0) partial[blockIdx.x] = red[0];
}

__global__ __launch_bounds__(256) void scan_offsets_kernel(int* __restrict__ partial, int nb,
                                                           int* __restrict__ row_ptr, int n) {
    __shared__ int sc[256];
    int t = threadIdx.x;
    sc[t] = (t < nb) ? partial[t] : 0;
    __syncthreads();
    for (int o = 1; o < 256; o <<= 1) {
        int v = sc[t];
        int u = (t >= o) ? sc[t - o] : 0;
        __syncthreads();
        sc[t] = v + u;
        __syncthreads();
    }
    if (t < nb) partial[t] = (t > 0) ? sc[t - 1] : 0;  // exclusive
    if (t == 0) row_ptr[n] = sc[255];
}

__global__ __launch_bounds__(256) void scan_write_kernel(const int* __restrict__ count, int n,
                                                         const int* __restrict__ partial,
                                                         int* __restrict__ row_ptr,
                                                         float* __restrict__ dinv) {
    __shared__ int sc[256];
    int t = threadIdx.x;
    int base = blockIdx.x * 1024 + t * 4;
    int c[4];
    int s = 0;
#pragma unroll
    for (int i = 0; i < 4; ++i) {
        int idx = base + i;
        c[i] = (idx < n) ? count[idx] : 0;
        s += pad8(c[i]);
    }
    sc[t] = s;
    __syncthreads();
    for (int o = 1; o < 256; o <<= 1) {
        int v = sc[t];
        int u = (t >= o) ? sc[t - o] : 0;
        __syncthreads();
        sc[t] = v + u;
        __syncthreads();
    }
    int run = partial[blockIdx.x] + ((t > 0) ? sc[t - 1] : 0);
#pragma unroll
    for (int i = 0; i < 4; ++i) {
        int idx = base + i;
        if (idx < n) {
            row_ptr[idx] = run;
            dinv[idx] = rsqrtf((float)c[i] + 1.0f);
            run += pad8(c[i]);
        }
    }
}

// Fill CSR (padded layout): real edges via LDS cursors, then pad tails with (d, 0).
__global__ __launch_bounds__(256) void csr_fill_kernel(
    const int2* __restrict__ bedges, const int* __restrict__ bucketBase,
    const int* __restrict__ bucketTotal, const int* __restrict__ row_ptr,
    const float* __restrict__ dinv, int n, int2* __restrict__ colw) {
    __shared__ int cur[1 << SHIFT];
    int k = blockIdx.x, t = threadIdx.x;
    int d0 = k << SHIFT;
    for (int i = t; i < (1 << SHIFT); i += 256) {
        int d = d0 + i;
        cur[i] = (d < n) ? row_ptr[d] : 0;
    }
    __syncthreads();
    int base = bucketBase[k], cnt = bucketTotal[k];
    for (int i = t; i < cnt; i += 256) {
        int2 e = bedges[base + i];
        float w = dinv[e.x];
        int p = atomicAdd(&cur[e.y - d0], 1);
        colw[p] = make_int2(e.x, __float_as_int(w));
    }
    __syncthreads();
    for (int i = t; i < (1 << SHIFT); i += 256) {
        int d = d0 + i;
        if (d < n) {
            int pend = row_ptr[d + 1];
            for (int p = cur[i]; p < pend; ++p) colw[p] = make_int2(d, 0);
        }
    }
}

// ---------------- MFMA GEMMs (bf16 16x16x32) ----------------
// Pack W[K][N] (row-major f32) into B-fragment order [kc][ct][lane][8] bf16:
// lane l, elem j of (kc,ct): B[k = kc*32 + (l>>4)*8 + j][col = ct*16 + (l&15)].
template<int K, int N>
__global__ __launch_bounds__(256) void packW_kernel(const float* __restrict__ W,
                                                    __hip_bfloat16* __restrict__ Wp) {
    constexpr int NT = N / 16;
    int idx = blockIdx.x * 256 + threadIdx.x;
    if (idx >= (K / 32) * NT * 64) return;
    int lane = idx & 63;
    int ct = (idx >> 6) % NT;
    int kc = idx / (64 * NT);
    int col = ct * 16 + (lane & 15);
    int k0 = kc * 32 + (lane >> 4) * 8;
    unsigned short tmp[8];
#pragma unroll
    for (int j = 0; j < 8; ++j) tmp[j] = bf16bits(W[(size_t)(k0 + j) * N + col]);
    ((uint4*)Wp)[idx] = *(const uint4*)tmp;
}

// gemm1: xw1[n][128] = x(f32)[n][128] @ W1. 64 rows/block (4 waves x 16), LDS-staged A.
__global__ __launch_bounds__(256) void gemm1_mfma_kernel(
    const float* __restrict__ In, const __hip_bfloat16* __restrict__ Wp,
    __hip_bfloat16* __restrict__ Out, int n) {
    __shared__ unsigned short sA[64 * 40];
    int t = threadIdx.x;
    int wv = t >> 6, lane = t & 63;
    int rbase = blockIdx.x * 64;
    f32x4 acc[8] = {};
    int srow = t >> 2;
    int kseg = (t & 3) * 8;
    int arow = wv * 16 + (lane & 15);
    int aoff = (lane >> 4) * 8;
    for (int kc = 0; kc < 4; ++kc) {
        {
            int gr = rbase + srow;
            unsigned short tmp[8];
            if (gr < n) {
                const float* src = &In[(size_t)gr * 128 + kc * 32 + kseg];
                float4 v0 = *(const float4*)src;
                float4 v1 = *(const float4*)(src + 4);
                tmp[0] = bf16bits(v0.x); tmp[1] = bf16bits(v0.y);
                tmp[2] = bf16bits(v0.z); tmp[3] = bf16bits(v0.w);
                tmp[4] = bf16bits(v1.x); tmp[5] = bf16bits(v1.y);
                tmp[6] = bf16bits(v1.z); tmp[7] = bf16bits(v1.w);
            } else {
#pragma unroll
                for (int j = 0; j < 8; ++j) tmp[j] = 0;
            }
            *(uint4*)&sA[srow * 40 + kseg] = *(const uint4*)tmp;
        }
        __syncthreads();
        bf16x8 afrag = *(const bf16x8*)&sA[arow * 40 + aoff];
        const uint4* wp = (const uint4*)Wp + (size_t)kc * 512 + lane;
#pragma unroll
        for (int ct = 0; ct < 8; ++ct) {
            uint4 braw = wp[ct * 64];
            bf16x8 bfrag;
            __builtin_memcpy(&bfrag, &braw, 16);
            acc[ct] = __builtin_amdgcn_mfma_f32_16x16x32_bf16(afrag, bfrag, acc[ct], 0, 0, 0);
        }
        __syncthreads();
    }
    int orow0 = rbase + wv * 16 + (lane >> 4) * 4;
    int ocol = lane & 15;
#pragma unroll
    for (int ct = 0; ct < 8; ++ct) {
#pragma unroll
        for (int r = 0; r < 4; ++r) {
            int gr = orow0 + r;
            if (gr < n)
                ((unsigned short*)Out)[(size_t)gr * 128 + ct * 16 + ocol] = bf16bits(acc[ct][r]);
        }
    }
}

// gemmA: P[n][64] = h1(bf16)[n][128] @ W2. A-frags direct from global (16B contiguous).
__global__ __launch_bounds__(256) void gemmA_mfma_kernel(
    const __hip_bfloat16* __restrict__ In, const __hip_bfloat16* __restrict__ Wp,
    __hip_bfloat16* __restrict__ Out, int n) {
    int t = threadIdx.x;
    int wv = t >> 6, lane = t & 63;
    int rbase = blockIdx.x * 64 + wv * 16;
    int arow = rbase + (lane & 15);
    bool rowok = (arow < n);
    f32x4 acc[4] = {};
    const unsigned short* a_base = (const unsigned short*)In + (size_t)(rowok ? arow : 0) * 128 + (lane >> 4) * 8;
#pragma unroll
    for (int kc = 0; kc < 4; ++kc) {
        bf16x8 afrag = {};
        if (rowok) {
            uint4 araw = *(const uint4*)(a_base + kc * 32);
            __builtin_memcpy(&afrag, &araw, 16);
        }
        const uint4* wp = (const uint4*)Wp + (size_t)kc * 256 + lane;
#pragma unroll
        for (int ct = 0; ct < 4; ++ct) {
            uint4 braw = wp[ct * 64];
            bf16x8 bfrag;
            __builtin_memcpy(&bfrag, &braw, 16);
            acc[ct] = __builtin_amdgcn_mfma_f32_16x16x32_bf16(afrag, bfrag, acc[ct], 0, 0, 0);
        }
    }
    int orow0 = rbase + (lane >> 4) * 4;
    int ocol = lane & 15;
#pragma unroll
    for (int ct = 0; ct < 4; ++ct) {
#pragma unroll
        for (int r = 0; r < 4; ++r) {
            int gr = orow0 + r;
            if (gr < n)
                ((unsigned short*)Out)[(size_t)gr * 64 + ct * 16 + ocol] = bf16bits(acc[ct][r]);
        }
    }
}

// gemmB: xw3[n][64] = h2(f32)[n][64] @ W3. A-frags direct from global w/ cvt.
__global__ __launch_bounds__(256) void gemmB_mfma_kernel(
    const float* __restrict__ In, const __hip_bfloat16* __restrict__ Wp,
    __hip_bfloat16* __restrict__ Out, int n) {
    int t = threadIdx.x;
    int wv = t >> 6, lane = t & 63;
    int rbase = blockIdx.x * 64 + wv * 16;
    int arow = rbase + (lane & 15);
    bool rowok = (arow < n);
    f32x4 acc[4] = {};
    const float* a_base = In + (size_t)(rowok ? arow : 0) * 64 + (lane >> 4) * 8;
#pragma unroll
    for (int kc = 0; kc < 2; ++kc) {
        bf16x8 afrag = {};
        if (rowok) {
            float4 v0 = *(const float4*)(a_base + kc * 32);
            float4 v1 = *(const float4*)(a_base + kc * 32 + 4);
            unsigned short tmp[8];
            tmp[0] = bf16bits(v0.x); tmp[1] = bf16bits(v0.y);
            tmp[2] = bf16bits(v0.z); tmp[3] = bf16bits(v0.w);
            tmp[4] = bf16bits(v1.x); tmp[5] = bf16bits(v1.y);
            tmp[6] = bf16bits(v1.z); tmp[7] = bf16bits(v1.w);
            __builtin_memcpy(&afrag, tmp, 16);
        }
        const uint4* wp = (const uint4*)Wp + (size_t)kc * 256 + lane;
#pragma unroll
        for (int ct = 0; ct < 4; ++ct) {
            uint4 braw = wp[ct * 64];
            bf16x8 bfrag;
            __builtin_memcpy(&bfrag, &braw, 16);
            acc[ct] = __builtin_amdgcn_mfma_f32_16x16x32_bf16(afrag, bfrag, acc[ct], 0, 0, 0);
        }
    }
    int orow0 = rbase + (lane >> 4) * 4;
    int ocol = lane & 15;
#pragma unroll
    for (int ct = 0; ct < 4; ++ct) {
#pragma unroll
        for (int r = 0; r < 4; ++r) {
            int gr = orow0 + r;
            if (gr < n)
                ((unsigned short*)Out)[(size_t)gr * 64 + ct * 16 + ocol] = bf16bits(acc[ct][r]);
        }
    }
}

// ---- Gathers: branch-free unroll-8, dual accumulators, SCALAR edge lists ----
__global__ __launch_bounds__(256) void gather128_kernel(
    const __hip_bfloat16* __restrict__ xw, const int* __restrict__ row_ptr,
    const int2* __restrict__ colw, const float* __restrict__ dinv,
    const float* __restrict__ b1, __hip_bfloat16* __restrict__ h1, int n) {
    int w = threadIdx.x >> 6, l = threadIdx.x & 63;
    int d = blockIdx.x * 4 + w;
    if (d >= n) return;
    float dd = dinv[d];
    int p0 = __builtin_amdgcn_readfirstlane(row_ptr[d]);
    int p1 = __builtin_amdgcn_readfirstlane(row_ptr[d + 1]);
    const uint32_t* X = (const uint32_t*)xw;
    uint32_t v = X[(size_t)d * 64 + l];
    float a0 = dd * lo16f(v), a1 = dd * hi16f(v);
    float c0a = 0.f, c1a = 0.f;
    for (int e = p0; e < p1; e += 8) {
        int s0 = __builtin_amdgcn_readfirstlane(colw[e].x);
        int s1 = __builtin_amdgcn_readfirstlane(colw[e + 1].x);
        int s2 = __builtin_amdgcn_readfirstlane(colw[e + 2].x);
        int s3 = __builtin_amdgcn_readfirstlane(colw[e + 3].x);
        int s4 = __builtin_amdgcn_readfirstlane(colw[e + 4].x);
        int s5 = __builtin_amdgcn_readfirstlane(colw[e + 5].x);
        int s6 = __builtin_amdgcn_readfirstlane(colw[e + 6].x);
        int s7 = __builtin_amdgcn_readfirstlane(colw[e + 7].x);
        float w0 = __int_as_float(__builtin_amdgcn_readfirstlane(colw[e].y));
        float w1 = __int_as_float(__builtin_amdgcn_readfirstlane(colw[e + 1].y));
        float w2 = __int_as_float(__builtin_amdgcn_readfirstlane(colw[e + 2].y));
        float w3 = __int_as_float(__builtin_amdgcn_readfirstlane(colw[e + 3].y));
        float w4 = __int_as_float(__builtin_amdgcn_readfirstlane(colw[e + 4].y));
        float w5 = __int_as_float(__builtin_amdgcn_readfirstlane(colw[e + 5].y));
        float w6 = __int_as_float(__builtin_amdgcn_readfirstlane(colw[e + 6].y));
        float w7 = __int_as_float(__builtin_amdgcn_readfirstlane(colw[e + 7].y));
        uint32_t v0 = X[(size_t)s0 * 64 + l];
        uint32_t v1 = X[(size_t)s1 * 64 + l];
        uint32_t v2 = X[(size_t)s2 * 64 + l];
        uint32_t v3 = X[(size_t)s3 * 64 + l];
        uint32_t v4 = X[(size_t)s4 * 64 + l];
        uint32_t v5 = X[(size_t)s5 * 64 + l];
        uint32_t v6 = X[(size_t)s6 * 64 + l];
        uint32_t v7 = X[(size_t)s7 * 64 + l];
        a0 = fmaf(w0, lo16f(v0), a0);  a1 = fmaf(w0, hi16f(v0), a1);
        c0a = fmaf(w1, lo16f(v1), c0a); c1a = fmaf(w1, hi16f(v1), c1a);
        a0 = fmaf(w2, lo16f(v2), a0);  a1 = fmaf(w2, hi16f(v2), a1);
        c0a = fmaf(w3, lo16f(v3), c0a); c1a = fmaf(w3, hi16f(v3), c1a);
        a0 = fmaf(w4, lo16f(v4), a0);  a1 = fmaf(w4, hi16f(v4), a1);
        c0a = fmaf(w5, lo16f(v5), c0a); c1a = fmaf(w5, hi16f(v5), c1a);
        a0 = fmaf(w6, lo16f(v6), a0);  a1 = fmaf(w6, hi16f(v6), a1);
        c0a = fmaf(w7, lo16f(v7), c0a); c1a = fmaf(w7, hi16f(v7), c1a);
    }
    a0 += c0a; a1 += c1a;
    a0 = fmaxf(fmaf(dd, a0, b1[2 * l]), 0.0f);
    a1 = fmaxf(fmaf(dd, a1, b1[2 * l + 1]), 0.0f);
    ((uint32_t*)h1)[(size_t)d * 64 + l] = pk2(a0, a1);
}

// OUT=0: fp32 out; OUT=1: bf16 out.
template<bool RELU, int OUT>
__global__ __launch_bounds__(256) void gather64b_kernel(
    const __hip_bfloat16* __restrict__ xw, const int* __restrict__ row_ptr,
    const int2* __restrict__ colw, const float* __restrict__ dinv,
    const float* __restrict__ b, void* __restrict__ out, int n) {
    int w = threadIdx.x >> 6, l = threadIdx.x & 63;
    int d = blockIdx.x * 4 + w;
    if (d >= n) return;
    float dd = dinv[d];
    int p0 = __builtin_amdgcn_readfirstlane(row_ptr[d]);
    int p1 = __builtin_amdgcn_readfirstlane(row_ptr[d + 1]);
    const unsigned short* X = (const unsigned short*)xw;
    float a = dd * u16f(X[(size_t)d * 64 + l]);
    float c = 0.f;
    for (int e = p0; e < p1; e += 8) {
        int s0 = __builtin_amdgcn_readfirstlane(colw[e].x);
        int s1 = __builtin_amdgcn_readfirstlane(colw[e + 1].x);
        int s2 = __builtin_amdgcn_readfirstlane(colw[e + 2].x);
        int s3 = __builtin_amdgcn_readfirstlane(colw[e + 3].x);
        int s4 = __builtin_amdgcn_readfirstlane(colw[e + 4].x);
        int s5 = __builtin_amdgcn_readfirstlane(colw[e + 5].x);
        int s6 = __builtin_amdgcn_readfirstlane(colw[e + 6].x);
        int s7 = __builtin_amdgcn_readfirstlane(colw[e + 7].x);
        float w0 = __int_as_float(__builtin_amdgcn_readfirstlane(colw[e].y));
        float w1 = __int_as_float(__builtin_amdgcn_readfirstlane(colw[e + 1].y));
        float w2 = __int_as_float(__builtin_amdgcn_readfirstlane(colw[e + 2].y));
        float w3 = __int_as_float(__builtin_amdgcn_readfirstlane(colw[e + 3].y));
        float w4 = __int_as_float(__builtin_amdgcn_readfirstlane(colw[e + 4].y));
        float w5 = __int_as_float(__builtin_amdgcn_readfirstlane(colw[e + 5].y));
        float w6 = __int_as_float(__builtin_amdgcn_readfirstlane(colw[e + 6].y));
        float w7 = __int_as_float(__builtin_amdgcn_readfirstlane(colw[e + 7].y));
        unsigned short v0 = X[(size_t)s0 * 64 + l];
        unsigned short v1 = X[(size_t)s1 * 64 + l];
        unsigned short v2 = X[(size_t)s2 * 64 + l];
        unsigned short v3 = X[(size_t)s3 * 64 + l];
        unsigned short v4 = X[(size_t)s4 * 64 + l];
        unsigned short v5 = X[(size_t)s5 * 64 + l];
        unsigned short v6 = X[(size_t)s6 * 64 + l];
        unsigned short v7 = X[(size_t)s7 * 64 + l];
        a = fmaf(w0, u16f(v0), a);
        c = fmaf(w1, u16f(v1), c);
        a = fmaf(w2, u16f(v2), a);
        c = fmaf(w3, u16f(v3), c);
        a = fmaf(w4, u16f(v4), a);
        c = fmaf(w5, u16f(v5), c);
        a = fmaf(w6, u16f(v6), a);
        c = fmaf(w7, u16f(v7), c);
    }
    a += c;
    float r = fmaf(dd, a, b[l]);
    if (RELU) r = fmaxf(r, 0.0f);
    if (OUT == 0) ((float*)out)[(size_t)d * 64 + l] = r;
    else ((unsigned short*)out)[(size_t)d * 64 + l] = bf16bits(r);
}

// ---------------- Score: 8 edges per wave, 8-lane groups, uint4 row loads ----------
__global__ void score_kernel(const __hip_bfloat16* __restrict__ h, const int* __restrict__ pos,
                             const int* __restrict__ neg, int Ep, int En,
                             float* __restrict__ out) {
    int wid = (int)(((size_t)blockIdx.x * blockDim.x + threadIdx.x) >> 6);
    int lane = threadIdx.x & 63;
    int g = lane >> 3, sl = lane & 7;
    int ed = wid * 8 + g;
    int tot = Ep + En;
    if (ed >= tot) return;
    int j, i;
    if (ed < Ep) { j = pos[ed]; i = pos[Ep + ed]; }
    else { int e = ed - Ep; j = neg[e]; i = neg[En + e]; }
    const uint4* X = (const uint4*)h;  // 8 uint4 per 64-feat bf16 row
    uint4 vi = X[(size_t)i * 8 + sl];
    uint4 vj = X[(size_t)j * 8 + sl];
    float v;
    v = lo16f(vi.x) * lo16f(vj.x);
    v = fmaf(hi16f(vi.x), hi16f(vj.x), v);
    v = fmaf(lo16f(vi.y), lo16f(vj.y), v);
    v = fmaf(hi16f(vi.y), hi16f(vj.y), v);
    v = fmaf(lo16f(vi.z), lo16f(vj.z), v);
    v = fmaf(hi16f(vi.z), hi16f(vj.z), v);
    v = fmaf(lo16f(vi.w), lo16f(vj.w), v);
    v = fmaf(hi16f(vi.w), hi16f(vj.w), v);
#pragma unroll
    for (int o = 4; o > 0; o >>= 1) v += __shfl_xor(v, o);
    if (sl == 0) out[ed] = v;
}

extern "C" void kernel_launch(void* const* d_in, const int* in_sizes, int n_in,
                              void* d_out, int out_size, void* d_ws, size_t ws_size,
                              hipStream_t stream) {
    const float* x   = (const float*)d_in[0];
    const int* train = (const int*)d_in[1];
    const int* pos   = (const int*)d_in[2];
    const int* neg   = (const int*)d_in[3];
    const float* W1  = (const float*)d_in[4];
    const float* b1  = (const float*)d_in[5];
    const float* W2  = (const float*)d_in[6];
    const float* b2  = (const float*)d_in[7];
    const float* W3  = (const float*)d_in[8];
    const float* b3  = (const float*)d_in[9];

    const int n  = in_sizes[0] / 128;
    const int E  = in_sizes[1] / 2;
    const int Ep = in_sizes[2] / 2;
    const int En = in_sizes[3] / 2;

    const int B  = (E + ECH - 1) / ECH;         // partition chunks (391 for E=1.6M)
    const int NB = ((n - 1) >> SHIFT) + 1;      // buckets (391 for n=100K)

    // Workspace (~85 MB)
    char* wp = (char*)d_ws;
    auto alloc = [&](size_t bytes) { char* r = wp; wp += (bytes + 255) & ~(size_t)255; return r; };
    int*   count    = (int*)alloc((size_t)n * 4);
    int*   row_ptr  = (int*)alloc(((size_t)n + 1) * 4);
    int*   partial  = (int*)alloc(256 * 4);
    int*   bucketTotal = (int*)alloc(MAXNB * 4);
    int*   bucketBase  = (int*)alloc(MAXNB * 4);
    __hip_bfloat16* Wp1 = (__hip_bfloat16*)alloc(4 * 8 * 64 * 8 * 2);   // 32KB
    __hip_bfloat16* Wp2 = (__hip_bfloat16*)alloc(4 * 4 * 64 * 8 * 2);   // 16KB
    __hip_bfloat16* Wp3 = (__hip_bfloat16*)alloc(2 * 4 * 64 * 8 * 2);   // 8KB
    int2*  colw     = (int2*)alloc(((size_t)E + 8 * (size_t)n) * 8);
    float* dinv     = (float*)alloc((size_t)n * 4);
    __hip_bfloat16* xw1 = (__hip_bfloat16*)alloc((size_t)n * 128 * 2);  // reused as h3(bf16 n*64)
    __hip_bfloat16* h1  = (__hip_bfloat16*)alloc((size_t)n * 128 * 2);
    __hip_bfloat16* P   = (__hip_bfloat16*)alloc((size_t)n * 64 * 2);   // xw2, later xw3
    __hip_bfloat16* h3  = xw1;
    __hip_bfloat16* xw3 = P;
    int2* bedges = (int2*)h1;       // alias: consumed before h1 is written
    int*  histG  = (int*)P;         // alias: NB*B*4 ~ 612KB, consumed before P is written

    float* out_scores = (float*)d_out;
    float* out_embed  = out_scores + (Ep + En);  // h2 lives here directly

    const int nbs = (n + 1023) / 1024;

    // radix partition -> per-bucket count -> row_ptr/dinv -> CSR
    part_hist_kernel<<<B, 256, 0, stream>>>(train + E, E, B, NB, histG);
    part_scan_kernel<<<NB, 256, 0, stream>>>(histG, B, bucketTotal);
    bucket_base_kernel<<<1, 256, 0, stream>>>(bucketTotal, NB, bucketBase);
    part_scatter_kernel<<<B, 256, 0, stream>>>(train, train + E, E, B, NB, histG, bucketBase, bedges);
    count_bucket_kernel<<<NB, 256, 0, stream>>>(bedges, bucketBase, bucketTotal, n, count);
    scan_partial_kernel<<<nbs, 256, 0, stream>>>(count, n, partial);
    scan_offsets_kernel<<<1, 256, 0, stream>>>(partial, nbs, row_ptr, n);
    scan_write_kernel<<<nbs, 256, 0, stream>>>(count, n, partial, row_ptr, dinv);
    csr_fill_kernel<<<NB, 256, 0, stream>>>(bedges, bucketBase, bucketTotal, row_ptr, dinv, n, colw);

    // Weight packs (one-time, tiny)
    packW_kernel<128, 128><<<8, 256, 0, stream>>>(W1, Wp1);
    packW_kernel<128, 64><<<4, 256, 0, stream>>>(W2, Wp2);
    packW_kernel<64, 64><<<2, 256, 0, stream>>>(W3, Wp3);

    // Layer 1 (MFMA)
    gemm1_mfma_kernel<<<(n + 63) / 64, 256, 0, stream>>>(x, Wp1, xw1, n);
    gather128_kernel<<<(n + 3) / 4, 256, 0, stream>>>(xw1, row_ptr, colw, dinv, b1, h1, n);
    gemmA_mfma_kernel<<<(n + 63) / 64, 256, 0, stream>>>(h1, Wp2, P, n);

    // Layer 2 (h2 written straight into out_embed, fp32)
    gather64b_kernel<true, 0><<<(n + 3) / 4, 256, 0, stream>>>(
        P, row_ptr, colw, dinv, b2, out_embed, n);

    // Layer 3 (h3 emitted bf16 for the score stage)
    gemmB_mfma_kernel<<<(n + 63) / 64, 256, 0, stream>>>(out_embed, Wp3, xw3, n);
    gather64b_kernel<false, 1><<<(n + 3) / 4, 256, 0, stream>>>(
        xw3, row_ptr, colw, dinv, b3, h3, n);

    // Scores: 8 edges per wave
    {
        int waves = (Ep + En + 7) / 8;
        score_kernel<<<(int)(((size_t)waves * 64 + 255) / 256), 256, 0, stream>>>(
            h3, pos, neg, Ep, En, out_scores);
    }
}

// Round 19
// 280.072 us; speedup vs baseline: 1.5927x; 1.0478x over previous
//
#include <hip/hip_runtime.h>
#include <hip/hip_bf16.h>

// GCN link prediction. Inputs fp32+int32; OUTPUT fp32 (scores[1M] ++ embed[n*64]).
// CSR gather + bf16 feature tables (fp32 math), MFMA for all three GEMMs,
// radix-partitioned CSR build with COMPRESSED u32 edge records:
//   bedges: (src<<8)|(dst&255)      colw: (src<<15)|q15(dinv[src])
// bucket-LDS degree count, padded unroll-8 scalarized gathers, 8-edge/wave score.

#define ECH 4096      // edges per partition chunk
#define SHIFT 8       // dsts per bucket = 256
#define MAXNB 512     // max buckets (n <= 131072)

typedef __attribute__((ext_vector_type(8))) short bf16x8;
typedef __attribute__((ext_vector_type(4))) float f32x4;

__device__ __forceinline__ float lo16f(uint32_t u) { uint32_t x = u << 16; float f; __builtin_memcpy(&f, &x, 4); return f; }
__device__ __forceinline__ float hi16f(uint32_t u) { uint32_t x = u & 0xffff0000u; float f; __builtin_memcpy(&f, &x, 4); return f; }
__device__ __forceinline__ float u16f(unsigned short u) { uint32_t x = (uint32_t)u << 16; float f; __builtin_memcpy(&f, &x, 4); return f; }
__device__ __forceinline__ uint32_t pk2(float a, float b) {
    union { __hip_bfloat162 h; uint32_t u; } cv;
    cv.h = __hip_bfloat162(__float2bfloat16(a), __float2bfloat16(b));
    return cv.u;
}
__device__ __forceinline__ unsigned short bf16bits(float a) {
    union { __hip_bfloat16 b; unsigned short u; } cv;
    cv.b = __float2bfloat16(a);
    return cv.u;
}
__device__ __forceinline__ int pad8(int c) { return (c + 7) & ~7; }
#define WDEC (1.0f / 32767.0f)

// ---------------- radix partition: edges -> buckets ----------------
__global__ __launch_bounds__(256) void part_hist_kernel(const int* __restrict__ dst, int E,
                                                        int B, int NB, int* __restrict__ histG) {
    __shared__ int h[MAXNB];
    int t = threadIdx.x, blk = blockIdx.x;
    for (int i = t; i < NB; i += 256) h[i] = 0;
    __syncthreads();
    int lo = blk * ECH, hi = min(lo + ECH, E);
    for (int i = lo + t; i < hi; i += 256) atomicAdd(&h[dst[i] >> SHIFT], 1);
    __syncthreads();
    for (int k = t; k < NB; k += 256) histG[(size_t)k * B + blk] = h[k];
}

__global__ __launch_bounds__(256) void part_scan_kernel(int* __restrict__ histG, int B,
                                                        int* __restrict__ bucketTotal) {
    __shared__ int sc[1024];   // supports B <= 1024
    int k = blockIdx.x, t = threadIdx.x;
    for (int i = t; i < 1024; i += 256) sc[i] = (i < B) ? histG[(size_t)k * B + i] : 0;
    __syncthreads();
    for (int o = 1; o < 1024; o <<= 1) {
        int v[4];
#pragma unroll
        for (int j = 0; j < 4; ++j) { int i = t + j * 256; v[j] = (i >= o) ? sc[i - o] : 0; }
        __syncthreads();
#pragma unroll
        for (int j = 0; j < 4; ++j) sc[t + j * 256] += v[j];
        __syncthreads();
    }
    for (int i = t; i < B; i += 256) histG[(size_t)k * B + i] = (i > 0) ? sc[i - 1] : 0;
    if (t == 0) bucketTotal[k] = sc[B - 1];
}

__global__ __launch_bounds__(256) void bucket_base_kernel(const int* __restrict__ bucketTotal,
                                                          int NB, int* __restrict__ bucketBase) {
    __shared__ int sc[MAXNB];
    int t = threadIdx.x;
    for (int i = t; i < MAXNB; i += 256) sc[i] = (i < NB) ? bucketTotal[i] : 0;
    __syncthreads();
    for (int o = 1; o < MAXNB; o <<= 1) {
        int v[MAXNB / 256];
#pragma unroll
        for (int j = 0; j < MAXNB / 256; ++j) { int i = t + j * 256; v[j] = (i >= o) ? sc[i - o] : 0; }
        __syncthreads();
#pragma unroll
        for (int j = 0; j < MAXNB / 256; ++j) sc[t + j * 256] += v[j];
        __syncthreads();
    }
    for (int i = t; i < NB; i += 256) bucketBase[i] = (i > 0) ? sc[i - 1] : 0;
}

// bedges entry: (src << 8) | (dst & 255); bucket id implied by position.
__global__ __launch_bounds__(256) void part_scatter_kernel(
    const int* __restrict__ src, const int* __restrict__ dst, int E, int B, int NB,
    const int* __restrict__ histG, const int* __restrict__ bucketBase,
    uint32_t* __restrict__ bedges) {
    __shared__ int cur[MAXNB];
    int t = threadIdx.x, blk = blockIdx.x;
    for (int k = t; k < NB; k += 256) cur[k] = bucketBase[k] + histG[(size_t)k * B + blk];
    __syncthreads();
    int lo = blk * ECH, hi = min(lo + ECH, E);
    for (int i = lo + t; i < hi; i += 256) {
        int s = src[i], d = dst[i];
        int p = atomicAdd(&cur[d >> SHIFT], 1);
        bedges[p] = ((uint32_t)s << 8) | (uint32_t)(d & 255);
    }
}

// Per-bucket degree count from partitioned edges.
__global__ __launch_bounds__(256) void count_bucket_kernel(
    const uint32_t* __restrict__ bedges, const int* __restrict__ bucketBase,
    const int* __restrict__ bucketTotal, int n, int* __restrict__ count) {
    __shared__ int hist[1 << SHIFT];
    int k = blockIdx.x, t = threadIdx.x;
    hist[t] = 0;
    __syncthreads();
    int base = bucketBase[k], cnt = bucketTotal[k];
    for (int i = t; i < cnt; i += 256) atomicAdd(&hist[bedges[base + i] & 255u], 1);
    __syncthreads();
    int d = (k << SHIFT) + t;
    if (d < n) count[d] = hist[t];
}

// ---------------- (padded) row_ptr scan + dinv ----------------
__global__ __launch_bounds__(256) void scan_partial_kernel(const int* __restrict__ count, int n,
                                                           int* __restrict__ partial) {
    __shared__ int red[256];
    int t = threadIdx.x;
    int base = blockIdx.x * 1024 + t * 4;
    int s = 0;
#pragma unroll
    for (int i = 0; i < 4; ++i) {
        int idx = base + i;
        if (idx < n) s += pad8(count[idx]);
    }
    red[t] = s;
    __syncthreads();
    for (int o = 128; o > 0; o >>= 1) {
        if (t < o) red[t] += red[t + o];
        __syncthreads();
    }
    if (t == 0) partial[blockIdx.x] = red[0];
}

__global__ __launch_bounds__(256) void scan_offsets_kernel(int* __restrict__ partial, int nb,
                                                           int* __restrict__ row_ptr, int n) {
    __shared__ int sc[256];
    int t = threadIdx.x;
    sc[t] = (t < nb) ? partial[t] : 0;
    __syncthreads();
    for (int o = 1; o < 256; o <<= 1) {
        int v = sc[t];
        int u = (t >= o) ? sc[t - o] : 0;
        __syncthreads();
        sc[t] = v + u;
        __syncthreads();
    }
    if (t < nb) partial[t] = (t > 0) ? sc[t - 1] : 0;  // exclusive
    if (t == 0) row_ptr[n] = sc[255];
}

__global__ __launch_bounds__(256) void scan_write_kernel(const int* __restrict__ count, int n,
                                                         const int* __restrict__ partial,
                                                         int* __restrict__ row_ptr,
                                                         float* __restrict__ dinv) {
    __shared__ int sc[256];
    int t = threadIdx.x;
    int base = blockIdx.x * 1024 + t * 4;
    int c[4];
    int s = 0;
#pragma unroll
    for (int i = 0; i < 4; ++i) {
        int idx = base + i;
        c[i] = (idx < n) ? count[idx] : 0;
        s += pad8(c[i]);
    }
    sc[t] = s;
    __syncthreads();
    for (int o = 1; o < 256; o <<= 1) {
        int v = sc[t];
        int u = (t >= o) ? sc[t - o] : 0;
        __syncthreads();
        sc[t] = v + u;
        __syncthreads();
    }
    int run = partial[blockIdx.x] + ((t > 0) ? sc[t - 1] : 0);
#pragma unroll
    for (int i = 0; i < 4; ++i) {
        int idx = base + i;
        if (idx < n) {
            row_ptr[idx] = run;
            dinv[idx] = rsqrtf((float)c[i] + 1.0f);
            run += pad8(c[i]);
        }
    }
}

// Fill CSR (padded layout, compressed): colw = (src<<15)|q15(dinv[src]); pads = (d<<15).
__global__ __launch_bounds__(256) void csr_fill_kernel(
    const uint32_t* __restrict__ bedges, const int* __restrict__ bucketBase,
    const int* __restrict__ bucketTotal, const int* __restrict__ row_ptr,
    const float* __restrict__ dinv, int n, uint32_t* __restrict__ colw) {
    __shared__ int cur[1 << SHIFT];
    int k = blockIdx.x, t = threadIdx.x;
    int d0 = k << SHIFT;
    for (int i = t; i < (1 << SHIFT); i += 256) {
        int d = d0 + i;
        cur[i] = (d < n) ? row_ptr[d] : 0;
    }
    __syncthreads();
    int base = bucketBase[k], cnt = bucketTotal[k];
    for (int i = t; i < cnt; i += 256) {
        uint32_t e = bedges[base + i];
        int s = (int)(e >> 8);
        uint32_t wq = (uint32_t)(dinv[s] * 32767.0f + 0.5f);
        int p = atomicAdd(&cur[e & 255u], 1);
        colw[p] = ((uint32_t)s << 15) | wq;
    }
    __syncthreads();
    for (int i = t; i < (1 << SHIFT); i += 256) {
        int d = d0 + i;
        if (d < n) {
            int pend = row_ptr[d + 1];
            uint32_t padv = (uint32_t)d << 15;   // w = 0
            for (int p = cur[i]; p < pend; ++p) colw[p] = padv;
        }
    }
}

// ---------------- MFMA GEMMs (bf16 16x16x32) ----------------
template<int K, int N>
__global__ __launch_bounds__(256) void packW_kernel(const float* __restrict__ W,
                                                    __hip_bfloat16* __restrict__ Wp) {
    constexpr int NT = N / 16;
    int idx = blockIdx.x * 256 + threadIdx.x;
    if (idx >= (K / 32) * NT * 64) return;
    int lane = idx & 63;
    int ct = (idx >> 6) % NT;
    int kc = idx / (64 * NT);
    int col = ct * 16 + (lane & 15);
    int k0 = kc * 32 + (lane >> 4) * 8;
    unsigned short tmp[8];
#pragma unroll
    for (int j = 0; j < 8; ++j) tmp[j] = bf16bits(W[(size_t)(k0 + j) * N + col]);
    ((uint4*)Wp)[idx] = *(const uint4*)tmp;
}

__global__ __launch_bounds__(256) void gemm1_mfma_kernel(
    const float* __restrict__ In, const __hip_bfloat16* __restrict__ Wp,
    __hip_bfloat16* __restrict__ Out, int n) {
    __shared__ unsigned short sA[64 * 40];
    int t = threadIdx.x;
    int wv = t >> 6, lane = t & 63;
    int rbase = blockIdx.x * 64;
    f32x4 acc[8] = {};
    int srow = t >> 2;
    int kseg = (t & 3) * 8;
    int arow = wv * 16 + (lane & 15);
    int aoff = (lane >> 4) * 8;
    for (int kc = 0; kc < 4; ++kc) {
        {
            int gr = rbase + srow;
            unsigned short tmp[8];
            if (gr < n) {
                const float* src = &In[(size_t)gr * 128 + kc * 32 + kseg];
                float4 v0 = *(const float4*)src;
                float4 v1 = *(const float4*)(src + 4);
                tmp[0] = bf16bits(v0.x); tmp[1] = bf16bits(v0.y);
                tmp[2] = bf16bits(v0.z); tmp[3] = bf16bits(v0.w);
                tmp[4] = bf16bits(v1.x); tmp[5] = bf16bits(v1.y);
                tmp[6] = bf16bits(v1.z); tmp[7] = bf16bits(v1.w);
            } else {
#pragma unroll
                for (int j = 0; j < 8; ++j) tmp[j] = 0;
            }
            *(uint4*)&sA[srow * 40 + kseg] = *(const uint4*)tmp;
        }
        __syncthreads();
        bf16x8 afrag = *(const bf16x8*)&sA[arow * 40 + aoff];
        const uint4* wpp = (const uint4*)Wp + (size_t)kc * 512 + lane;
#pragma unroll
        for (int ct = 0; ct < 8; ++ct) {
            uint4 braw = wpp[ct * 64];
            bf16x8 bfrag;
            __builtin_memcpy(&bfrag, &braw, 16);
            acc[ct] = __builtin_amdgcn_mfma_f32_16x16x32_bf16(afrag, bfrag, acc[ct], 0, 0, 0);
        }
        __syncthreads();
    }
    int orow0 = rbase + wv * 16 + (lane >> 4) * 4;
    int ocol = lane & 15;
#pragma unroll
    for (int ct = 0; ct < 8; ++ct) {
#pragma unroll
        for (int r = 0; r < 4; ++r) {
            int gr = orow0 + r;
            if (gr < n)
                ((unsigned short*)Out)[(size_t)gr * 128 + ct * 16 + ocol] = bf16bits(acc[ct][r]);
        }
    }
}

__global__ __launch_bounds__(256) void gemmA_mfma_kernel(
    const __hip_bfloat16* __restrict__ In, const __hip_bfloat16* __restrict__ Wp,
    __hip_bfloat16* __restrict__ Out, int n) {
    int t = threadIdx.x;
    int wv = t >> 6, lane = t & 63;
    int rbase = blockIdx.x * 64 + wv * 16;
    int arow = rbase + (lane & 15);
    bool rowok = (arow < n);
    f32x4 acc[4] = {};
    const unsigned short* a_base = (const unsigned short*)In + (size_t)(rowok ? arow : 0) * 128 + (lane >> 4) * 8;
#pragma unroll
    for (int kc = 0; kc < 4; ++kc) {
        bf16x8 afrag = {};
        if (rowok) {
            uint4 araw = *(const uint4*)(a_base + kc * 32);
            __builtin_memcpy(&afrag, &araw, 16);
        }
        const uint4* wpp = (const uint4*)Wp + (size_t)kc * 256 + lane;
#pragma unroll
        for (int ct = 0; ct < 4; ++ct) {
            uint4 braw = wpp[ct * 64];
            bf16x8 bfrag;
            __builtin_memcpy(&bfrag, &braw, 16);
            acc[ct] = __builtin_amdgcn_mfma_f32_16x16x32_bf16(afrag, bfrag, acc[ct], 0, 0, 0);
        }
    }
    int orow0 = rbase + (lane >> 4) * 4;
    int ocol = lane & 15;
#pragma unroll
    for (int ct = 0; ct < 4; ++ct) {
#pragma unroll
        for (int r = 0; r < 4; ++r) {
            int gr = orow0 + r;
            if (gr < n)
                ((unsigned short*)Out)[(size_t)gr * 64 + ct * 16 + ocol] = bf16bits(acc[ct][r]);
        }
    }
}

__global__ __launch_bounds__(256) void gemmB_mfma_kernel(
    const float* __restrict__ In, const __hip_bfloat16* __restrict__ Wp,
    __hip_bfloat16* __restrict__ Out, int n) {
    int t = threadIdx.x;
    int wv = t >> 6, lane = t & 63;
    int rbase = blockIdx.x * 64 + wv * 16;
    int arow = rbase + (lane & 15);
    bool rowok = (arow < n);
    f32x4 acc[4] = {};
    const float* a_base = In + (size_t)(rowok ? arow : 0) * 64 + (lane >> 4) * 8;
#pragma unroll
    for (int kc = 0; kc < 2; ++kc) {
        bf16x8 afrag = {};
        if (rowok) {
            float4 v0 = *(const float4*)(a_base + kc * 32);
            float4 v1 = *(const float4*)(a_base + kc * 32 + 4);
            unsigned short tmp[8];
            tmp[0] = bf16bits(v0.x); tmp[1] = bf16bits(v0.y);
            tmp[2] = bf16bits(v0.z); tmp[3] = bf16bits(v0.w);
            tmp[4] = bf16bits(v1.x); tmp[5] = bf16bits(v1.y);
            tmp[6] = bf16bits(v1.z); tmp[7] = bf16bits(v1.w);
            __builtin_memcpy(&afrag, tmp, 16);
        }
        const uint4* wpp = (const uint4*)Wp + (size_t)kc * 256 + lane;
#pragma unroll
        for (int ct = 0; ct < 4; ++ct) {
            uint4 braw = wpp[ct * 64];
            bf16x8 bfrag;
            __builtin_memcpy(&bfrag, &braw, 16);
            acc[ct] = __builtin_amdgcn_mfma_f32_16x16x32_bf16(afrag, bfrag, acc[ct], 0, 0, 0);
        }
    }
    int orow0 = rbase + (lane >> 4) * 4;
    int ocol = lane & 15;
#pragma unroll
    for (int ct = 0; ct < 4; ++ct) {
#pragma unroll
        for (int r = 0; r < 4; ++r) {
            int gr = orow0 + r;
            if (gr < n)
                ((unsigned short*)Out)[(size_t)gr * 64 + ct * 16 + ocol] = bf16bits(acc[ct][r]);
        }
    }
}

// ---- Gathers: branch-free unroll-8, dual accumulators, compressed scalar edges ----
#define DECODE(q, s, w) int s = (int)((q) >> 15); float w = (float)((q) & 0x7fffu) * WDEC;

__global__ __launch_bounds__(256) void gather128_kernel(
    const __hip_bfloat16* __restrict__ xw, const int* __restrict__ row_ptr,
    const uint32_t* __restrict__ colw, const float* __restrict__ dinv,
    const float* __restrict__ b1, __hip_bfloat16* __restrict__ h1, int n) {
    int w = threadIdx.x >> 6, l = threadIdx.x & 63;
    int d = blockIdx.x * 4 + w;
    if (d >= n) return;
    float dd = dinv[d];
    int p0 = __builtin_amdgcn_readfirstlane(row_ptr[d]);
    int p1 = __builtin_amdgcn_readfirstlane(row_ptr[d + 1]);
    const uint32_t* X = (const uint32_t*)xw;
    uint32_t v = X[(size_t)d * 64 + l];
    float a0 = dd * lo16f(v), a1 = dd * hi16f(v);
    float c0a = 0.f, c1a = 0.f;
    for (int e = p0; e < p1; e += 8) {
        uint32_t q0 = __builtin_amdgcn_readfirstlane(colw[e]);
        uint32_t q1 = __builtin_amdgcn_readfirstlane(colw[e + 1]);
        uint32_t q2 = __builtin_amdgcn_readfirstlane(colw[e + 2]);
        uint32_t q3 = __builtin_amdgcn_readfirstlane(colw[e + 3]);
        uint32_t q4 = __builtin_amdgcn_readfirstlane(colw[e + 4]);
        uint32_t q5 = __builtin_amdgcn_readfirstlane(colw[e + 5]);
        uint32_t q6 = __builtin_amdgcn_readfirstlane(colw[e + 6]);
        uint32_t q7 = __builtin_amdgcn_readfirstlane(colw[e + 7]);
        DECODE(q0, s0, w0) DECODE(q1, s1, w1) DECODE(q2, s2, w2) DECODE(q3, s3, w3)
        DECODE(q4, s4, w4) DECODE(q5, s5, w5) DECODE(q6, s6, w6) DECODE(q7, s7, w7)
        uint32_t v0 = X[(size_t)s0 * 64 + l];
        uint32_t v1 = X[(size_t)s1 * 64 + l];
        uint32_t v2 = X[(size_t)s2 * 64 + l];
        uint32_t v3 = X[(size_t)s3 * 64 + l];
        uint32_t v4 = X[(size_t)s4 * 64 + l];
        uint32_t v5 = X[(size_t)s5 * 64 + l];
        uint32_t v6 = X[(size_t)s6 * 64 + l];
        uint32_t v7 = X[(size_t)s7 * 64 + l];
        a0 = fmaf(w0, lo16f(v0), a0);  a1 = fmaf(w0, hi16f(v0), a1);
        c0a = fmaf(w1, lo16f(v1), c0a); c1a = fmaf(w1, hi16f(v1), c1a);
        a0 = fmaf(w2, lo16f(v2), a0);  a1 = fmaf(w2, hi16f(v2), a1);
        c0a = fmaf(w3, lo16f(v3), c0a); c1a = fmaf(w3, hi16f(v3), c1a);
        a0 = fmaf(w4, lo16f(v4), a0);  a1 = fmaf(w4, hi16f(v4), a1);
        c0a = fmaf(w5, lo16f(v5), c0a); c1a = fmaf(w5, hi16f(v5), c1a);
        a0 = fmaf(w6, lo16f(v6), a0);  a1 = fmaf(w6, hi16f(v6), a1);
        c0a = fmaf(w7, lo16f(v7), c0a); c1a = fmaf(w7, hi16f(v7), c1a);
    }
    a0 += c0a; a1 += c1a;
    a0 = fmaxf(fmaf(dd, a0, b1[2 * l]), 0.0f);
    a1 = fmaxf(fmaf(dd, a1, b1[2 * l + 1]), 0.0f);
    ((uint32_t*)h1)[(size_t)d * 64 + l] = pk2(a0, a1);
}

// OUT=0: fp32 out; OUT=1: bf16 out.
template<bool RELU, int OUT>
__global__ __launch_bounds__(256) void gather64b_kernel(
    const __hip_bfloat16* __restrict__ xw, const int* __restrict__ row_ptr,
    const uint32_t* __restrict__ colw, const float* __restrict__ dinv,
    const float* __restrict__ b, void* __restrict__ out, int n) {
    int w = threadIdx.x >> 6, l = threadIdx.x & 63;
    int d = blockIdx.x * 4 + w;
    if (d >= n) return;
    float dd = dinv[d];
    int p0 = __builtin_amdgcn_readfirstlane(row_ptr[d]);
    int p1 = __builtin_amdgcn_readfirstlane(row_ptr[d + 1]);
    const unsigned short* X = (const unsigned short*)xw;
    float a = dd * u16f(X[(size_t)d * 64 + l]);
    float c = 0.f;
    for (int e = p0; e < p1; e += 8) {
        uint32_t q0 = __builtin_amdgcn_readfirstlane(colw[e]);
        uint32_t q1 = __builtin_amdgcn_readfirstlane(colw[e + 1]);
        uint32_t q2 = __builtin_amdgcn_readfirstlane(colw[e + 2]);
        uint32_t q3 = __builtin_amdgcn_readfirstlane(colw[e + 3]);
        uint32_t q4 = __builtin_amdgcn_readfirstlane(colw[e + 4]);
        uint32_t q5 = __builtin_amdgcn_readfirstlane(colw[e + 5]);
        uint32_t q6 = __builtin_amdgcn_readfirstlane(colw[e + 6]);
        uint32_t q7 = __builtin_amdgcn_readfirstlane(colw[e + 7]);
        DECODE(q0, s0, w0) DECODE(q1, s1, w1) DECODE(q2, s2, w2) DECODE(q3, s3, w3)
        DECODE(q4, s4, w4) DECODE(q5, s5, w5) DECODE(q6, s6, w6) DECODE(q7, s7, w7)
        unsigned short v0 = X[(size_t)s0 * 64 + l];
        unsigned short v1 = X[(size_t)s1 * 64 + l];
        unsigned short v2 = X[(size_t)s2 * 64 + l];
        unsigned short v3 = X[(size_t)s3 * 64 + l];
        unsigned short v4 = X[(size_t)s4 * 64 + l];
        unsigned short v5 = X[(size_t)s5 * 64 + l];
        unsigned short v6 = X[(size_t)s6 * 64 + l];
        unsigned short v7 = X[(size_t)s7 * 64 + l];
        a = fmaf(w0, u16f(v0), a);
        c = fmaf(w1, u16f(v1), c);
        a = fmaf(w2, u16f(v2), a);
        c = fmaf(w3, u16f(v3), c);
        a = fmaf(w4, u16f(v4), a);
        c = fmaf(w5, u16f(v5), c);
        a = fmaf(w6, u16f(v6), a);
        c = fmaf(w7, u16f(v7), c);
    }
    a += c;
    float r = fmaf(dd, a, b[l]);
    if (RELU) r = fmaxf(r, 0.0f);
    if (OUT == 0) ((float*)out)[(size_t)d * 64 + l] = r;
    else ((unsigned short*)out)[(size_t)d * 64 + l] = bf16bits(r);
}

// ---------------- Score: 8 edges per wave, 8-lane groups, uint4 row loads ----------
__global__ void score_kernel(const __hip_bfloat16* __restrict__ h, const int* __restrict__ pos,
                             const int* __restrict__ neg, int Ep, int En,
                             float* __restrict__ out) {
    int wid = (int)(((size_t)blockIdx.x * blockDim.x + threadIdx.x) >> 6);
    int lane = threadIdx.x & 63;
    int g = lane >> 3, sl = lane & 7;
    int ed = wid * 8 + g;
    int tot = Ep + En;
    if (ed >= tot) return;
    int j, i;
    if (ed < Ep) { j = pos[ed]; i = pos[Ep + ed]; }
    else { int e = ed - Ep; j = neg[e]; i = neg[En + e]; }
    const uint4* X = (const uint4*)h;
    uint4 vi = X[(size_t)i * 8 + sl];
    uint4 vj = X[(size_t)j * 8 + sl];
    float v;
    v = lo16f(vi.x) * lo16f(vj.x);
    v = fmaf(hi16f(vi.x), hi16f(vj.x), v);
    v = fmaf(lo16f(vi.y), lo16f(vj.y), v);
    v = fmaf(hi16f(vi.y), hi16f(vj.y), v);
    v = fmaf(lo16f(vi.z), lo16f(vj.z), v);
    v = fmaf(hi16f(vi.z), hi16f(vj.z), v);
    v = fmaf(lo16f(vi.w), lo16f(vj.w), v);
    v = fmaf(hi16f(vi.w), hi16f(vj.w), v);
#pragma unroll
    for (int o = 4; o > 0; o >>= 1) v += __shfl_xor(v, o);
    if (sl == 0) out[ed] = v;
}

extern "C" void kernel_launch(void* const* d_in, const int* in_sizes, int n_in,
                              void* d_out, int out_size, void* d_ws, size_t ws_size,
                              hipStream_t stream) {
    const float* x   = (const float*)d_in[0];
    const int* train = (const int*)d_in[1];
    const int* pos   = (const int*)d_in[2];
    const int* neg   = (const int*)d_in[3];
    const float* W1  = (const float*)d_in[4];
    const float* b1  = (const float*)d_in[5];
    const float* W2  = (const float*)d_in[6];
    const float* b2  = (const float*)d_in[7];
    const float* W3  = (const float*)d_in[8];
    const float* b3  = (const float*)d_in[9];

    const int n  = in_sizes[0] / 128;
    const int E  = in_sizes[1] / 2;
    const int Ep = in_sizes[2] / 2;
    const int En = in_sizes[3] / 2;

    const int B  = (E + ECH - 1) / ECH;
    const int NB = ((n - 1) >> SHIFT) + 1;

    // Workspace (~70 MB with compressed edge records)
    char* wp = (char*)d_ws;
    auto alloc = [&](size_t bytes) { char* r = wp; wp += (bytes + 255) & ~(size_t)255; return r; };
    int*   count    = (int*)alloc((size_t)n * 4);
    int*   row_ptr  = (int*)alloc(((size_t)n + 1) * 4);
    int*   partial  = (int*)alloc(256 * 4);
    int*   bucketTotal = (int*)alloc(MAXNB * 4);
    int*   bucketBase  = (int*)alloc(MAXNB * 4);
    __hip_bfloat16* Wp1 = (__hip_bfloat16*)alloc(4 * 8 * 64 * 8 * 2);
    __hip_bfloat16* Wp2 = (__hip_bfloat16*)alloc(4 * 4 * 64 * 8 * 2);
    __hip_bfloat16* Wp3 = (__hip_bfloat16*)alloc(2 * 4 * 64 * 8 * 2);
    uint32_t* colw  = (uint32_t*)alloc(((size_t)E + 8 * (size_t)n) * 4);
    float* dinv     = (float*)alloc((size_t)n * 4);
    __hip_bfloat16* xw1 = (__hip_bfloat16*)alloc((size_t)n * 128 * 2);  // reused as h3
    __hip_bfloat16* h1  = (__hip_bfloat16*)alloc((size_t)n * 128 * 2);
    __hip_bfloat16* P   = (__hip_bfloat16*)alloc((size_t)n * 64 * 2);   // xw2, later xw3
    __hip_bfloat16* h3  = xw1;
    __hip_bfloat16* xw3 = P;
    uint32_t* bedges = (uint32_t*)h1;   // alias: consumed before h1 written
    int*  histG  = (int*)P;             // alias: consumed before P written

    float* out_scores = (float*)d_out;
    float* out_embed  = out_scores + (Ep + En);

    const int nbs = (n + 1023) / 1024;

    // radix partition -> per-bucket count -> row_ptr/dinv -> CSR
    part_hist_kernel<<<B, 256, 0, stream>>>(train + E, E, B, NB, histG);
    part_scan_kernel<<<NB, 256, 0, stream>>>(histG, B, bucketTotal);
    bucket_base_kernel<<<1, 256, 0, stream>>>(bucketTotal, NB, bucketBase);
    part_scatter_kernel<<<B, 256, 0, stream>>>(train, train + E, E, B, NB, histG, bucketBase, bedges);
    count_bucket_kernel<<<NB, 256, 0, stream>>>(bedges, bucketBase, bucketTotal, n, count);
    scan_partial_kernel<<<nbs, 256, 0, stream>>>(count, n, partial);
    scan_offsets_kernel<<<1, 256, 0, stream>>>(partial, nbs, row_ptr, n);
    scan_write_kernel<<<nbs, 256, 0, stream>>>(count, n, partial, row_ptr, dinv);
    csr_fill_kernel<<<NB, 256, 0, stream>>>(bedges, bucketBase, bucketTotal, row_ptr, dinv, n, colw);

    // Weight packs
    packW_kernel<128, 128><<<8, 256, 0, stream>>>(W1, Wp1);
    packW_kernel<128, 64><<<4, 256, 0, stream>>>(W2, Wp2);
    packW_kernel<64, 64><<<2, 256, 0, stream>>>(W3, Wp3);

    // Layer 1
    gemm1_mfma_kernel<<<(n + 63) / 64, 256, 0, stream>>>(x, Wp1, xw1, n);
    gather128_kernel<<<(n + 3) / 4, 256, 0, stream>>>(xw1, row_ptr, colw, dinv, b1, h1, n);
    gemmA_mfma_kernel<<<(n + 63) / 64, 256, 0, stream>>>(h1, Wp2, P, n);

    // Layer 2 (h2 -> out_embed fp32)
    gather64b_kernel<true, 0><<<(n + 3) / 4, 256, 0, stream>>>(
        P, row_ptr, colw, dinv, b2, out_embed, n);

    // Layer 3
    gemmB_mfma_kernel<<<(n + 63) / 64, 256, 0, stream>>>(out_embed, Wp3, xw3, n);
    gather64b_kernel<false, 1><<<(n + 3) / 4, 256, 0, stream>>>(
        xw3, row_ptr, colw, dinv, b3, h3, n);

    // Scores
    {
        int waves = (Ep + En + 7) / 8;
        score_kernel<<<(int)(((size_t)waves * 64 + 255) / 256), 256, 0, stream>>>(
            h3, pos, neg, Ep, En, out_scores);
    }
}